// Round 1
// baseline (20737.700 us; speedup 1.0000x reference)
//
#include <hip/hip_runtime.h>
#include <math.h>

// ---------------- problem constants ----------------
constexpr int CB = 8, CT = 4096, CP = 4, CD = 512, CV = 256;
constexpr int CN = 1024, CK = 16, CH = 8, CHD = 64;
constexpr int ROWS = CB * CN;     // 8192
constexpr int TROWS = CB * CT;    // 32768
constexpr float CEPS = 1e-5f;

// ---------------- workspace layout (floats) ----------------
// LOCAL (B*N, P, D) persists to the end.
// GI doubles as scores (8*1024*1024 <= 8192*1536) mid-round, and GI..GH
// together (25.1M floats) hold `final` (16.7M floats) at the end.
constexpr size_t OFF_LOCAL = 0;                                   // 16,777,216
constexpr size_t OFF_H     = OFF_LOCAL + (size_t)ROWS * CP * CD;  //  4,194,304
constexpr size_t OFF_GI    = OFF_H     + (size_t)ROWS * CD;       // 12,582,912
constexpr size_t OFF_GH    = OFF_GI    + (size_t)ROWS * 3 * CD;   // 12,582,912
constexpr size_t OFF_Q     = OFF_GH    + (size_t)ROWS * 3 * CD;   //  4,194,304
constexpr size_t OFF_K     = OFF_Q     + (size_t)ROWS * CD;       //  4,194,304
constexpr size_t OFF_V     = OFF_K     + (size_t)ROWS * CD;       //  4,194,304
constexpr size_t OFF_MSGS  = OFF_V     + (size_t)ROWS * CD;       //  4,194,304
constexpr size_t OFF_PROB  = OFF_MSGS  + (size_t)ROWS * CD;       //    131,072
constexpr size_t OFF_IDX   = OFF_PROB  + (size_t)ROWS * CK;       //    131,072
// total = 63,176,704 floats = 241 MiB

// ---------------- device helpers ----------------
__device__ __forceinline__ float sigm(float x) { return 1.f / (1.f + expf(-x)); }
__device__ __forceinline__ float geluf(float x) {
  return 0.5f * x * (1.f + erff(x * 0.7071067811865475f));
}
// 256-thread block reductions (4 waves of 64)
__device__ __forceinline__ float blk_sum(float v, float* red) {
#pragma unroll
  for (int o = 32; o > 0; o >>= 1) v += __shfl_down(v, o, 64);
  const int wv = threadIdx.x >> 6, ln = threadIdx.x & 63;
  __syncthreads();
  if (ln == 0) red[wv] = v;
  __syncthreads();
  return red[0] + red[1] + red[2] + red[3];
}
__device__ __forceinline__ float blk_max(float v, float* red) {
#pragma unroll
  for (int o = 32; o > 0; o >>= 1) v = fmaxf(v, __shfl_down(v, o, 64));
  const int wv = threadIdx.x >> 6, ln = threadIdx.x & 63;
  __syncthreads();
  if (ln == 0) red[wv] = v;
  __syncthreads();
  return fmaxf(fmaxf(red[0], red[1]), fmaxf(red[2], red[3]));
}

// ---------------- GEMM: C[M,N] (+)= A[M,K] @ W[K,N] (+ bias) ----------------
// 64x64 tile, BK=16, 256 threads, 4x4 per thread. All dims multiples of 64/64/16.
__global__ __launch_bounds__(256) void gemm_nn(
    const float* __restrict__ A, const float* __restrict__ W,
    const float* __restrict__ bias, float* __restrict__ C,
    int M, int N, int K, int lda, int ldw, int ldc, int accum)
{
  __shared__ __align__(16) float As[16][64];
  __shared__ __align__(16) float Bs[16][64];
  const int tid = threadIdx.x;
  const int tx = tid & 15, ty = tid >> 4;
  const int bm = blockIdx.y * 64, bn = blockIdx.x * 64;
  const int ar = tid >> 2, akq = (tid & 3) << 2;
  const int bc = tid & 63, bkr = tid >> 6;
  float acc[4][4] = {};
  for (int k0 = 0; k0 < K; k0 += 16) {
    const float4 av = *(const float4*)(A + (size_t)(bm + ar) * lda + (k0 + akq));
    As[akq + 0][ar] = av.x; As[akq + 1][ar] = av.y;
    As[akq + 2][ar] = av.z; As[akq + 3][ar] = av.w;
#pragma unroll
    for (int p = 0; p < 4; ++p) {
      const int kk = p * 4 + bkr;
      Bs[kk][bc] = W[(size_t)(k0 + kk) * ldw + (bn + bc)];
    }
    __syncthreads();
#pragma unroll
    for (int kk = 0; kk < 16; ++kk) {
      const float4 a = *(const float4*)&As[kk][ty << 2];
      const float4 b = *(const float4*)&Bs[kk][tx << 2];
      acc[0][0] += a.x * b.x; acc[0][1] += a.x * b.y; acc[0][2] += a.x * b.z; acc[0][3] += a.x * b.w;
      acc[1][0] += a.y * b.x; acc[1][1] += a.y * b.y; acc[1][2] += a.y * b.z; acc[1][3] += a.y * b.w;
      acc[2][0] += a.z * b.x; acc[2][1] += a.z * b.y; acc[2][2] += a.z * b.z; acc[2][3] += a.z * b.w;
      acc[3][0] += a.w * b.x; acc[3][1] += a.w * b.y; acc[3][2] += a.w * b.z; acc[3][3] += a.w * b.w;
    }
    __syncthreads();
  }
  float4 bv = make_float4(0.f, 0.f, 0.f, 0.f);
  if (bias) bv = *(const float4*)(bias + bn + (tx << 2));
#pragma unroll
  for (int i = 0; i < 4; ++i) {
    float* Cp = C + (size_t)(bm + (ty << 2) + i) * ldc + bn + (tx << 2);
    float4 o = make_float4(acc[i][0] + bv.x, acc[i][1] + bv.y,
                           acc[i][2] + bv.z, acc[i][3] + bv.w);
    if (accum) {
      const float4 c = *(const float4*)Cp;
      o.x += c.x; o.y += c.y; o.z += c.z; o.w += c.w;
    }
    *(float4*)Cp = o;
  }
}

// ---------------- batched GEMM-NT: C[b][n,m] = scale * A[b][n,:] . Bt[b][m,:] ----
__global__ __launch_bounds__(256) void gemm_nt(
    const float* __restrict__ A, const float* __restrict__ Bt, float* __restrict__ C,
    int M, int N, int K, int lda, int ldb, int ldc,
    long long sA, long long sB, long long sC, float scale)
{
  A += (size_t)blockIdx.z * sA; Bt += (size_t)blockIdx.z * sB; C += (size_t)blockIdx.z * sC;
  __shared__ __align__(16) float As[16][64];
  __shared__ __align__(16) float Bs[16][64];
  const int tid = threadIdx.x;
  const int tx = tid & 15, ty = tid >> 4;
  const int bm = blockIdx.y * 64, bn = blockIdx.x * 64;
  const int ar = tid >> 2, akq = (tid & 3) << 2;
  float acc[4][4] = {};
  for (int k0 = 0; k0 < K; k0 += 16) {
    const float4 av = *(const float4*)(A + (size_t)(bm + ar) * lda + (k0 + akq));
    As[akq + 0][ar] = av.x; As[akq + 1][ar] = av.y;
    As[akq + 2][ar] = av.z; As[akq + 3][ar] = av.w;
    const float4 bv4 = *(const float4*)(Bt + (size_t)(bn + ar) * ldb + (k0 + akq));
    Bs[akq + 0][ar] = bv4.x; Bs[akq + 1][ar] = bv4.y;
    Bs[akq + 2][ar] = bv4.z; Bs[akq + 3][ar] = bv4.w;
    __syncthreads();
#pragma unroll
    for (int kk = 0; kk < 16; ++kk) {
      const float4 a = *(const float4*)&As[kk][ty << 2];
      const float4 b = *(const float4*)&Bs[kk][tx << 2];
      acc[0][0] += a.x * b.x; acc[0][1] += a.x * b.y; acc[0][2] += a.x * b.z; acc[0][3] += a.x * b.w;
      acc[1][0] += a.y * b.x; acc[1][1] += a.y * b.y; acc[1][2] += a.y * b.z; acc[1][3] += a.y * b.w;
      acc[2][0] += a.z * b.x; acc[2][1] += a.z * b.y; acc[2][2] += a.z * b.z; acc[2][3] += a.z * b.w;
      acc[3][0] += a.w * b.x; acc[3][1] += a.w * b.y; acc[3][2] += a.w * b.z; acc[3][3] += a.w * b.w;
    }
    __syncthreads();
  }
#pragma unroll
  for (int i = 0; i < 4; ++i) {
    float* Cp = C + (size_t)(bm + (ty << 2) + i) * ldc + bn + (tx << 2);
    *(float4*)Cp = make_float4(acc[i][0] * scale, acc[i][1] * scale,
                               acc[i][2] * scale, acc[i][3] * scale);
  }
}

// ---------------- small kernels ----------------
__global__ void zero_k(float* __restrict__ p) {
  p[(size_t)blockIdx.x * 256 + threadIdx.x] = 0.f;
}

// X_t[r,d] = emb[x[b, n*P+t], d] + pos_emb[t, d]
__global__ void embed_step(const int* __restrict__ x, const float* __restrict__ emb,
                           const float* __restrict__ pos, float* __restrict__ Xt, int t)
{
  const int i = blockIdx.x * 256 + threadIdx.x;   // ROWS*CD
  const int r = i >> 9, d = i & 511;
  const int b = r >> 10, n = r & (CN - 1);
  const int tok = x[b * CT + n * CP + t];
  Xt[i] = emb[(size_t)tok * CD + d] + pos[t * CD + d];
}

// GRU pointwise (initial patch GRU), writes h and hs-slot t
__global__ void gru_point(const float* __restrict__ gi, const float* __restrict__ gh,
                          float* __restrict__ h, float* __restrict__ hs, int t)
{
  const int i = blockIdx.x * 256 + threadIdx.x;   // ROWS*CD
  const int r = i >> 9, d = i & 511;
  const size_t gb = (size_t)r * (3 * CD) + d;
  const float ir = gi[gb], iz = gi[gb + CD], inn = gi[gb + 2 * CD];
  const float hr = gh[gb], hz = gh[gb + CD], hn = gh[gb + 2 * CD];
  const float hp = h[i];
  const float rr = sigm(ir + hr), zz = sigm(iz + hz);
  const float nn = tanhf(inn + rr * hn);
  const float hv = (1.f - zz) * nn + zz * hp;
  h[i] = hv;
  hs[(size_t)r * (CP * CD) + (size_t)t * CD + d] = hv;
}

// generic row LN (width 512)
__global__ __launch_bounds__(256) void ln_rows(const float* __restrict__ in, float* __restrict__ out,
                                               const float* __restrict__ g, const float* __restrict__ b)
{
  const int r = blockIdx.x, t = threadIdx.x;
  __shared__ float red[4];
  const float* ip = in + (size_t)r * CD;
  const float v0 = ip[t], v1 = ip[t + 256];
  const float mu = blk_sum(v0 + v1, red) * (1.f / CD);
  const float d0 = v0 - mu, d1 = v1 - mu;
  const float var = blk_sum(d0 * d0 + d1 * d1, red) * (1.f / CD);
  const float inv = rsqrtf(var + CEPS);
  float* op = out + (size_t)r * CD;
  op[t] = d0 * inv * g[t] + b[t];
  op[t + 256] = d1 * inv * g[t + 256] + b[t + 256];
}

// hm[r,d] = mean_p local[r,p,d]
__global__ void mean_pool(const float* __restrict__ local, float* __restrict__ hm)
{
  const int i = blockIdx.x * 256 + threadIdx.x;   // ROWS*CD
  const int r = i >> 9, d = i & 511;
  const float* p = local + (size_t)r * (CP * CD) + d;
  hm[i] = 0.25f * (p[0] + p[CD] + p[2 * CD] + p[3 * CD]);
}

// G[r,d] = 0.2 * sum_{w=0..4} gelu(pre[r,d] + (n>=w ? nb[r-w,d] : 0))
__global__ void msg_gelu(const float* __restrict__ pre, const float* __restrict__ nb,
                         float* __restrict__ G)
{
  const int i = blockIdx.x * 256 + threadIdx.x;   // ROWS*CD
  const int r = i >> 9;
  const int n = r & (CN - 1);
  const float pv = pre[i];
  float acc = 0.f;
#pragma unroll
  for (int w = 0; w <= 4; ++w) {
    const float xv = pv + ((n >= w) ? nb[(size_t)i - (size_t)w * CD] : 0.f);
    acc += geluf(xv);
  }
  G[i] = acc * 0.2f;
}

// in-place rotary on (ROWS, 512), n = row % N
__global__ void rotary_k(float* __restrict__ t)
{
  const int i = blockIdx.x * 256 + threadIdx.x;   // ROWS*256
  const int r = i >> 8, j = i & 255;
  const int n = r & (CN - 1);
  const float fr = (float)n * expf(-9.210340371976184f * ((float)j * (1.f / 256.f)));
  float s, c;
  sincosf(fr, &s, &c);
  float* p = t + (size_t)r * CD;
  const float t1 = p[j], t2 = p[j + 256];
  p[j] = t1 * c - t2 * s;
  p[j + 256] = t2 * c + t1 * s;
}

// per-row top-16 of causal scores row + softmax -> probs/idx
__global__ void topk_softmax(const float* __restrict__ scores, float* __restrict__ probs,
                             int* __restrict__ idxs)
{
  const int r = blockIdx.x * 256 + threadIdx.x;   // ROWS threads
  if (r >= ROWS) return;
  const int b = r >> 10, n = r & (CN - 1);
  const float* row = scores + ((size_t)b * CN + n) * CN;
  float v[CK]; int id[CK];
#pragma unroll
  for (int q = 0; q < CK; ++q) { v[q] = -INFINITY; id[q] = 0; }
  float mn = -INFINITY; int mnp = 0;
  for (int m = 0; m <= n; ++m) {
    const float s = row[m];
    if (s > mn) {
      v[mnp] = s; id[mnp] = m;
      mn = v[0]; mnp = 0;
#pragma unroll
      for (int q = 1; q < CK; ++q) { if (v[q] < mn) { mn = v[q]; mnp = q; } }
    }
  }
  float mx = -INFINITY;
#pragma unroll
  for (int q = 0; q < CK; ++q) mx = fmaxf(mx, v[q]);
  float p[CK]; float sum = 0.f;
#pragma unroll
  for (int q = 0; q < CK; ++q) {
    const float e = (v[q] == -INFINITY) ? 0.f : expf(v[q] - mx);
    p[q] = e; sum += e;
  }
  const float inv = 1.f / sum;
#pragma unroll
  for (int q = 0; q < CK; ++q) {
    probs[(size_t)r * CK + q] = p[q] * inv;
    idxs[(size_t)r * CK + q] = id[q];
  }
}

// ctx[r,d] = sum_k p_k * v[b, idx_k, d]
__global__ __launch_bounds__(128) void topk_gather(const float* __restrict__ probs,
                                                   const int* __restrict__ idxs,
                                                   const float* __restrict__ v,
                                                   float* __restrict__ ctx)
{
  const int r = blockIdx.x;        // ROWS
  const int b = r >> 10;
  __shared__ float p[CK];
  __shared__ int id[CK];
  if (threadIdx.x < CK) {
    p[threadIdx.x] = probs[(size_t)r * CK + threadIdx.x];
    id[threadIdx.x] = idxs[(size_t)r * CK + threadIdx.x];
  }
  __syncthreads();
  for (int d = threadIdx.x; d < CD; d += 128) {
    float a = 0.f;
#pragma unroll
    for (int q = 0; q < CK; ++q)
      a += p[q] * v[((size_t)(b << 10) + id[q]) * CD + d];
    ctx[(size_t)r * CD + d] = a;
  }
}

// fused GRU-cell + LN (round update), h updated in place
__global__ __launch_bounds__(256) void gru_ln(const float* __restrict__ gi, const float* __restrict__ gh,
                                              float* __restrict__ h, const float* __restrict__ g,
                                              const float* __restrict__ b)
{
  const int r = blockIdx.x, t = threadIdx.x;
  __shared__ float red[4];
  float u[2];
#pragma unroll
  for (int q = 0; q < 2; ++q) {
    const int d = t + q * 256;
    const size_t gb = (size_t)r * (3 * CD) + d;
    const float ir = gi[gb], iz = gi[gb + CD], inn = gi[gb + 2 * CD];
    const float hr = gh[gb], hz = gh[gb + CD], hn = gh[gb + 2 * CD];
    const float hp = h[(size_t)r * CD + d];
    const float rr = sigm(ir + hr), zz = sigm(iz + hz);
    const float nn = tanhf(inn + rr * hn);
    u[q] = (1.f - zz) * nn + zz * hp;
  }
  const float mu = blk_sum(u[0] + u[1], red) * (1.f / CD);
  const float d0 = u[0] - mu, d1 = u[1] - mu;
  const float var = blk_sum(d0 * d0 + d1 * d1, red) * (1.f / CD);
  const float inv = rsqrtf(var + CEPS);
  h[(size_t)r * CD + t] = d0 * inv * g[t] + b[t];
  h[(size_t)r * CD + t + 256] = d1 * inv * g[t + 256] + b[t + 256];
}

// causal MHA: one block per (n, head, b); qkv packed (B,N,3D); out (B,N,D)
__global__ __launch_bounds__(256) void ar_attn(const float* __restrict__ qkv, float* __restrict__ out)
{
  const int n = blockIdx.x, head = blockIdx.y, b = blockIdx.z;
  const int lane = threadIdx.x & 63, wave = threadIdx.x >> 6;
  __shared__ float s[CN];
  __shared__ float part[4][64];
  __shared__ float red[4];
  const size_t base = (size_t)b * CN * (3 * CD);
  const int hoff = head * CHD;
  const float qd = qkv[base + (size_t)n * (3 * CD) + hoff + lane];
  for (int m = wave; m <= n; m += 4) {
    float pr = qd * qkv[base + (size_t)m * (3 * CD) + CD + hoff + lane];
#pragma unroll
    for (int o = 32; o > 0; o >>= 1) pr += __shfl_down(pr, o, 64);
    if (lane == 0) s[m] = pr * 0.125f;   // 1/sqrt(64)
  }
  __syncthreads();
  float mx = -INFINITY;
  for (int m = threadIdx.x; m <= n; m += 256) mx = fmaxf(mx, s[m]);
  mx = blk_max(mx, red);
  float sum = 0.f;
  for (int m = threadIdx.x; m <= n; m += 256) {
    const float e = expf(s[m] - mx);
    s[m] = e; sum += e;
  }
  sum = blk_sum(sum, red);               // syncs also order s[] writes before reads below
  const float inv = 1.f / sum;
  float acc = 0.f;
  for (int m = wave; m <= n; m += 4)
    acc += s[m] * qkv[base + (size_t)m * (3 * CD) + 2 * CD + hoff + lane];
  part[wave][lane] = acc;
  __syncthreads();
  if (wave == 0) {
    const float o4 = (part[0][lane] + part[1][lane] + part[2][lane] + part[3][lane]) * inv;
    out[((size_t)b * CN + n) * CD + hoff + lane] = o4;
  }
}

// final = LN(local[r] + broad[r/4]) -> out
__global__ __launch_bounds__(256) void final_ln(const float* __restrict__ local,
                                                const float* __restrict__ broad,
                                                const float* __restrict__ g, const float* __restrict__ bb,
                                                float* __restrict__ out)
{
  const int r = blockIdx.x, t = threadIdx.x;   // TROWS
  __shared__ float red[4];
  const size_t lb = (size_t)r * CD;
  const size_t br = (size_t)(r >> 2) * CD;
  const float v0 = local[lb + t] + broad[br + t];
  const float v1 = local[lb + 256 + t] + broad[br + 256 + t];
  const float mu = blk_sum(v0 + v1, red) * (1.f / CD);
  const float d0 = v0 - mu, d1 = v1 - mu;
  const float var = blk_sum(d0 * d0 + d1 * d1, red) * (1.f / CD);
  const float inv = rsqrtf(var + CEPS);
  out[lb + t] = d0 * inv * g[t] + bb[t];
  out[lb + 256 + t] = d1 * inv * g[t + 256] + bb[t + 256];
}

// ---------------- launcher ----------------
extern "C" void kernel_launch(void* const* d_in, const int* in_sizes, int n_in,
                              void* d_out, int out_size, void* d_ws, size_t ws_size,
                              hipStream_t stream)
{
  (void)in_sizes; (void)n_in; (void)out_size; (void)ws_size;
  const int*   x         = (const int*)d_in[0];
  const float* emb       = (const float*)d_in[1];
  const float* pos_emb   = (const float*)d_in[2];
  const float* gru_w_ih  = (const float*)d_in[3];
  const float* gru_w_hh  = (const float*)d_in[4];
  const float* gru_b_ih  = (const float*)d_in[5];
  const float* gru_b_hh  = (const float*)d_in[6];
  const float* patch_g   = (const float*)d_in[7];
  const float* patch_b   = (const float*)d_in[8];
  const float* summ_w    = (const float*)d_in[9];
  const float* summ_b    = (const float*)d_in[10];
  const float* msg_w1    = (const float*)d_in[11];
  const float* msg_b1    = (const float*)d_in[12];
  const float* msg_w2    = (const float*)d_in[13];
  const float* msg_b2    = (const float*)d_in[14];
  const float* msg_ln_g  = (const float*)d_in[15];
  const float* msg_ln_b  = (const float*)d_in[16];
  const float* q_w       = (const float*)d_in[17];
  const float* q_b       = (const float*)d_in[18];
  const float* k_w       = (const float*)d_in[19];
  const float* k_b       = (const float*)d_in[20];
  const float* v_w       = (const float*)d_in[21];
  const float* v_b       = (const float*)d_in[22];
  const float* o_w       = (const float*)d_in[23];
  const float* o_b       = (const float*)d_in[24];
  const float* gc_w_ih   = (const float*)d_in[25];
  const float* gc_w_hh   = (const float*)d_in[26];
  const float* gc_b_ih   = (const float*)d_in[27];
  const float* gc_b_hh   = (const float*)d_in[28];
  const float* ar_ln_g   = (const float*)d_in[29];
  const float* ar_ln_b   = (const float*)d_in[30];
  const float* ar_qkv_w  = (const float*)d_in[31];
  const float* ar_qkv_b  = (const float*)d_in[32];
  const float* ar_out_w  = (const float*)d_in[33];
  const float* ar_out_b  = (const float*)d_in[34];
  const float* broad_w   = (const float*)d_in[35];
  const float* broad_b   = (const float*)d_in[36];
  const float* ln_g      = (const float*)d_in[37];
  const float* ln_b      = (const float*)d_in[38];
  const float* head_w    = (const float*)d_in[39];
  float* out = (float*)d_out;

  float* ws = (float*)d_ws;
  float* Wl    = ws + OFF_LOCAL;
  float* Wh    = ws + OFF_H;
  float* Wgi   = ws + OFF_GI;
  float* Wgh   = ws + OFF_GH;
  float* Wq    = ws + OFF_Q;
  float* Wk    = ws + OFF_K;
  float* Wv    = ws + OFF_V;
  float* Wmsgs = ws + OFF_MSGS;
  float* Wprob = ws + OFF_PROB;
  int*   Widx  = (int*)(ws + OFF_IDX);
  float* Wscores = Wgi;   // scores (B,N,N) lives in GI between its GEMM and topk
  float* Wfinal  = Wgi;   // final (B*T, D) spans GI+GH at the end

  const int EW = ROWS * CD / 256;        // 16384 elementwise blocks
  const float inv_sqrt_d = 0.04419417382415922f;   // 1/sqrt(512)

  // ---- patch GRU over P=4 steps ----
  zero_k<<<EW, 256, 0, stream>>>(Wh);
  for (int t = 0; t < CP; ++t) {
    embed_step<<<EW, 256, 0, stream>>>(x, emb, pos_emb, Wq, t);
    gemm_nn<<<dim3(1536 / 64, ROWS / 64), 256, 0, stream>>>(
        Wq, gru_w_ih, gru_b_ih, Wgi, ROWS, 1536, 512, 512, 1536, 1536, 0);
    gemm_nn<<<dim3(1536 / 64, ROWS / 64), 256, 0, stream>>>(
        Wh, gru_w_hh, gru_b_hh, Wgh, ROWS, 1536, 512, 512, 1536, 1536, 0);
    gru_point<<<EW, 256, 0, stream>>>(Wgi, Wgh, Wh, Wl, t);
  }
  ln_rows<<<TROWS, 256, 0, stream>>>(Wl, Wl, patch_g, patch_b);
  mean_pool<<<EW, 256, 0, stream>>>(Wl, Wk);
  gemm_nn<<<dim3(512 / 64, ROWS / 64), 256, 0, stream>>>(
      Wk, summ_w, summ_b, Wh, ROWS, 512, 512, 512, 512, 512, 0);

  // ---- rounds ----
  for (int rnd = 0; rnd < 6; ++rnd) {
    // messages: pre = h@W1_top + b1 ; nb = h@W1_bot ; G = mean_w gelu(...)
    gemm_nn<<<dim3(8, 128), 256, 0, stream>>>(Wh, msg_w1, msg_b1, Wq,
                                              ROWS, 512, 512, 512, 512, 512, 0);
    gemm_nn<<<dim3(8, 128), 256, 0, stream>>>(Wh, msg_w1 + (size_t)512 * 512, nullptr, Wk,
                                              ROWS, 512, 512, 512, 512, 512, 0);
    msg_gelu<<<EW, 256, 0, stream>>>(Wq, Wk, Wv);
    gemm_nn<<<dim3(8, 128), 256, 0, stream>>>(Wv, msg_w2, msg_b2, Wmsgs,
                                              ROWS, 512, 512, 512, 512, 512, 0);
    // q,k,v + rotary
    gemm_nn<<<dim3(8, 128), 256, 0, stream>>>(Wh, q_w, q_b, Wq, ROWS, 512, 512, 512, 512, 512, 0);
    rotary_k<<<ROWS, 256, 0, stream>>>(Wq);
    gemm_nn<<<dim3(8, 128), 256, 0, stream>>>(Wh, k_w, k_b, Wk, ROWS, 512, 512, 512, 512, 512, 0);
    rotary_k<<<ROWS, 256, 0, stream>>>(Wk);
    gemm_nn<<<dim3(8, 128), 256, 0, stream>>>(Wh, v_w, v_b, Wv, ROWS, 512, 512, 512, 512, 512, 0);
    // scores = q @ k^T / sqrt(D)
    gemm_nt<<<dim3(16, 16, CB), 256, 0, stream>>>(
        Wq, Wk, Wscores, CN, CN, 512, 512, 512, CN,
        (long long)CN * CD, (long long)CN * CD, (long long)CN * CN, inv_sqrt_d);
    topk_softmax<<<ROWS / 256, 256, 0, stream>>>(Wscores, Wprob, Widx);
    topk_gather<<<ROWS, 128, 0, stream>>>(Wprob, Widx, Wv, Wq);       // ctx -> Wq
    gemm_nn<<<dim3(8, 128), 256, 0, stream>>>(Wq, o_w, o_b, Wk,       // retrieved -> Wk
                                              ROWS, 512, 512, 512, 512, 512, 0);
    // gi = msgs@Wih_top + b ; gi += retrieved@Wih_bot ; gh = h@Whh + b
    gemm_nn<<<dim3(24, 128), 256, 0, stream>>>(Wmsgs, gc_w_ih, gc_b_ih, Wgi,
                                               ROWS, 1536, 512, 512, 1536, 1536, 0);
    gemm_nn<<<dim3(24, 128), 256, 0, stream>>>(Wk, gc_w_ih + (size_t)512 * 1536, nullptr, Wgi,
                                               ROWS, 1536, 512, 512, 1536, 1536, 1);
    gemm_nn<<<dim3(24, 128), 256, 0, stream>>>(Wh, gc_w_hh, gc_b_hh, Wgh,
                                               ROWS, 1536, 512, 512, 1536, 1536, 0);
    gru_ln<<<ROWS, 256, 0, stream>>>(Wgi, Wgh, Wh, msg_ln_g, msg_ln_b);
    // periodic MHA
    if ((rnd & 1) == 1) {
      ln_rows<<<ROWS, 256, 0, stream>>>(Wh, Wq, ar_ln_g, ar_ln_b);
      gemm_nn<<<dim3(24, 128), 256, 0, stream>>>(Wq, ar_qkv_w, ar_qkv_b, Wgi,
                                                 ROWS, 1536, 512, 512, 1536, 1536, 0);
      ar_attn<<<dim3(CN, CH, CB), 256, 0, stream>>>(Wgi, Wk);
      gemm_nn<<<dim3(8, 128), 256, 0, stream>>>(Wk, ar_out_w, ar_out_b, Wh,
                                                ROWS, 512, 512, 512, 512, 512, 1);
    }
  }

  // ---- head ----
  gemm_nn<<<dim3(8, 128), 256, 0, stream>>>(Wh, broad_w, broad_b, Wq,
                                            ROWS, 512, 512, 512, 512, 512, 0);
  final_ln<<<TROWS, 256, 0, stream>>>(Wl, Wq, ln_g, ln_b, Wfinal);
  gemm_nn<<<dim3(CV / 64, TROWS / 64), 256, 0, stream>>>(
      Wfinal, head_w, nullptr, out, TROWS, CV, 512, 512, CV, CV, 0);
}

// Round 2
// 13286.282 us; speedup vs baseline: 1.5608x; 1.5608x over previous
//
#include <hip/hip_runtime.h>
#include <math.h>

// ---------------- problem constants ----------------
constexpr int CB = 8, CT = 4096, CP = 4, CD = 512, CV = 256;
constexpr int CN = 1024, CK = 16, CH = 8, CHD = 64;
constexpr int ROWS = CB * CN;     // 8192
constexpr int TROWS = CB * CT;    // 32768
constexpr float CEPS = 1e-5f;

// ---------------- workspace layout (floats) ----------------
constexpr size_t OFF_LOCAL = 0;                                   // 16,777,216
constexpr size_t OFF_H     = OFF_LOCAL + (size_t)ROWS * CP * CD;  //  4,194,304
constexpr size_t OFF_GI    = OFF_H     + (size_t)ROWS * CD;       // 12,582,912
constexpr size_t OFF_GH    = OFF_GI    + (size_t)ROWS * 3 * CD;   // 12,582,912
constexpr size_t OFF_Q     = OFF_GH    + (size_t)ROWS * 3 * CD;   //  4,194,304
constexpr size_t OFF_K     = OFF_Q     + (size_t)ROWS * CD;       //  4,194,304
constexpr size_t OFF_V     = OFF_K     + (size_t)ROWS * CD;       //  4,194,304
constexpr size_t OFF_MSGS  = OFF_V     + (size_t)ROWS * CD;       //  4,194,304
constexpr size_t OFF_PROB  = OFF_MSGS  + (size_t)ROWS * CD;       //    131,072
constexpr size_t OFF_IDX   = OFF_PROB  + (size_t)ROWS * CK;       //    131,072

// ---------------- device helpers ----------------
__device__ __forceinline__ float sigm(float x) { return 1.f / (1.f + expf(-x)); }
__device__ __forceinline__ float geluf(float x) {
  return 0.5f * x * (1.f + erff(x * 0.7071067811865475f));
}
__device__ __forceinline__ float blk_sum(float v, float* red) {
#pragma unroll
  for (int o = 32; o > 0; o >>= 1) v += __shfl_down(v, o, 64);
  const int wv = threadIdx.x >> 6, ln = threadIdx.x & 63;
  __syncthreads();
  if (ln == 0) red[wv] = v;
  __syncthreads();
  return red[0] + red[1] + red[2] + red[3];
}

// ---------------- GEMM: C[M,N] (+)= A[M,K] @ W[K,N] (+ bias) ----------------
__global__ __launch_bounds__(256) void gemm_nn(
    const float* __restrict__ A, const float* __restrict__ W,
    const float* __restrict__ bias, float* __restrict__ C,
    int M, int N, int K, int lda, int ldw, int ldc, int accum)
{
  __shared__ __align__(16) float As[16][64];
  __shared__ __align__(16) float Bs[16][64];
  const int tid = threadIdx.x;
  const int tx = tid & 15, ty = tid >> 4;
  const int bm = blockIdx.y * 64, bn = blockIdx.x * 64;
  const int ar = tid >> 2, akq = (tid & 3) << 2;
  const int bc = tid & 63, bkr = tid >> 6;
  float acc[4][4] = {};
  for (int k0 = 0; k0 < K; k0 += 16) {
    const float4 av = *(const float4*)(A + (size_t)(bm + ar) * lda + (k0 + akq));
    As[akq + 0][ar] = av.x; As[akq + 1][ar] = av.y;
    As[akq + 2][ar] = av.z; As[akq + 3][ar] = av.w;
#pragma unroll
    for (int p = 0; p < 4; ++p) {
      const int kk = p * 4 + bkr;
      Bs[kk][bc] = W[(size_t)(k0 + kk) * ldw + (bn + bc)];
    }
    __syncthreads();
#pragma unroll
    for (int kk = 0; kk < 16; ++kk) {
      const float4 a = *(const float4*)&As[kk][ty << 2];
      const float4 b = *(const float4*)&Bs[kk][tx << 2];
      acc[0][0] += a.x * b.x; acc[0][1] += a.x * b.y; acc[0][2] += a.x * b.z; acc[0][3] += a.x * b.w;
      acc[1][0] += a.y * b.x; acc[1][1] += a.y * b.y; acc[1][2] += a.y * b.z; acc[1][3] += a.y * b.w;
      acc[2][0] += a.z * b.x; acc[2][1] += a.z * b.y; acc[2][2] += a.z * b.z; acc[2][3] += a.z * b.w;
      acc[3][0] += a.w * b.x; acc[3][1] += a.w * b.y; acc[3][2] += a.w * b.z; acc[3][3] += a.w * b.w;
    }
    __syncthreads();
  }
  float4 bv = make_float4(0.f, 0.f, 0.f, 0.f);
  if (bias) bv = *(const float4*)(bias + bn + (tx << 2));
#pragma unroll
  for (int i = 0; i < 4; ++i) {
    float* Cp = C + (size_t)(bm + (ty << 2) + i) * ldc + bn + (tx << 2);
    float4 o = make_float4(acc[i][0] + bv.x, acc[i][1] + bv.y,
                           acc[i][2] + bv.z, acc[i][3] + bv.w);
    if (accum) {
      const float4 c = *(const float4*)Cp;
      o.x += c.x; o.y += c.y; o.z += c.z; o.w += c.w;
    }
    *(float4*)Cp = o;
  }
}

// ---------------- batched GEMM-NT: C[b][n,m] = scale * A[b][n,:] . Bt[b][m,:] ----
__global__ __launch_bounds__(256) void gemm_nt(
    const float* __restrict__ A, const float* __restrict__ Bt, float* __restrict__ C,
    int M, int N, int K, int lda, int ldb, int ldc,
    long long sA, long long sB, long long sC, float scale)
{
  A += (size_t)blockIdx.z * sA; Bt += (size_t)blockIdx.z * sB; C += (size_t)blockIdx.z * sC;
  __shared__ __align__(16) float As[16][64];
  __shared__ __align__(16) float Bs[16][64];
  const int tid = threadIdx.x;
  const int tx = tid & 15, ty = tid >> 4;
  const int bm = blockIdx.y * 64, bn = blockIdx.x * 64;
  const int ar = tid >> 2, akq = (tid & 3) << 2;
  float acc[4][4] = {};
  for (int k0 = 0; k0 < K; k0 += 16) {
    const float4 av = *(const float4*)(A + (size_t)(bm + ar) * lda + (k0 + akq));
    As[akq + 0][ar] = av.x; As[akq + 1][ar] = av.y;
    As[akq + 2][ar] = av.z; As[akq + 3][ar] = av.w;
    const float4 bv4 = *(const float4*)(Bt + (size_t)(bn + ar) * ldb + (k0 + akq));
    Bs[akq + 0][ar] = bv4.x; Bs[akq + 1][ar] = bv4.y;
    Bs[akq + 2][ar] = bv4.z; Bs[akq + 3][ar] = bv4.w;
    __syncthreads();
#pragma unroll
    for (int kk = 0; kk < 16; ++kk) {
      const float4 a = *(const float4*)&As[kk][ty << 2];
      const float4 b = *(const float4*)&Bs[kk][tx << 2];
      acc[0][0] += a.x * b.x; acc[0][1] += a.x * b.y; acc[0][2] += a.x * b.z; acc[0][3] += a.x * b.w;
      acc[1][0] += a.y * b.x; acc[1][1] += a.y * b.y; acc[1][2] += a.y * b.z; acc[1][3] += a.y * b.w;
      acc[2][0] += a.z * b.x; acc[2][1] += a.z * b.y; acc[2][2] += a.z * b.z; acc[2][3] += a.z * b.w;
      acc[3][0] += a.w * b.x; acc[3][1] += a.w * b.y; acc[3][2] += a.w * b.z; acc[3][3] += a.w * b.w;
    }
    __syncthreads();
  }
#pragma unroll
  for (int i = 0; i < 4; ++i) {
    float* Cp = C + (size_t)(bm + (ty << 2) + i) * ldc + bn + (tx << 2);
    *(float4*)Cp = make_float4(acc[i][0] * scale, acc[i][1] * scale,
                               acc[i][2] * scale, acc[i][3] * scale);
  }
}

// ---------------- small kernels ----------------
__global__ void zero_k(float* __restrict__ p) {
  p[(size_t)blockIdx.x * 256 + threadIdx.x] = 0.f;
}

__global__ void embed_step(const int* __restrict__ x, const float* __restrict__ emb,
                           const float* __restrict__ pos, float* __restrict__ Xt, int t)
{
  const int i = blockIdx.x * 256 + threadIdx.x;
  const int r = i >> 9, d = i & 511;
  const int b = r >> 10, n = r & (CN - 1);
  const int tok = x[b * CT + n * CP + t];
  Xt[i] = emb[(size_t)tok * CD + d] + pos[t * CD + d];
}

__global__ void gru_point(const float* __restrict__ gi, const float* __restrict__ gh,
                          float* __restrict__ h, float* __restrict__ hs, int t)
{
  const int i = blockIdx.x * 256 + threadIdx.x;
  const int r = i >> 9, d = i & 511;
  const size_t gb = (size_t)r * (3 * CD) + d;
  const float ir = gi[gb], iz = gi[gb + CD], inn = gi[gb + 2 * CD];
  const float hr = gh[gb], hz = gh[gb + CD], hn = gh[gb + 2 * CD];
  const float hp = h[i];
  const float rr = sigm(ir + hr), zz = sigm(iz + hz);
  const float nn = tanhf(inn + rr * hn);
  const float hv = (1.f - zz) * nn + zz * hp;
  h[i] = hv;
  hs[(size_t)r * (CP * CD) + (size_t)t * CD + d] = hv;
}

__global__ __launch_bounds__(256) void ln_rows(const float* __restrict__ in, float* __restrict__ out,
                                               const float* __restrict__ g, const float* __restrict__ b)
{
  const int r = blockIdx.x, t = threadIdx.x;
  __shared__ float red[4];
  const float* ip = in + (size_t)r * CD;
  const float v0 = ip[t], v1 = ip[t + 256];
  const float mu = blk_sum(v0 + v1, red) * (1.f / CD);
  const float d0 = v0 - mu, d1 = v1 - mu;
  const float var = blk_sum(d0 * d0 + d1 * d1, red) * (1.f / CD);
  const float inv = rsqrtf(var + CEPS);
  float* op = out + (size_t)r * CD;
  op[t] = d0 * inv * g[t] + b[t];
  op[t + 256] = d1 * inv * g[t + 256] + b[t + 256];
}

__global__ void mean_pool(const float* __restrict__ local, float* __restrict__ hm)
{
  const int i = blockIdx.x * 256 + threadIdx.x;
  const int r = i >> 9, d = i & 511;
  const float* p = local + (size_t)r * (CP * CD) + d;
  hm[i] = 0.25f * (p[0] + p[CD] + p[2 * CD] + p[3 * CD]);
}

__global__ void msg_gelu(const float* __restrict__ pre, const float* __restrict__ nb,
                         float* __restrict__ G)
{
  const int i = blockIdx.x * 256 + threadIdx.x;
  const int r = i >> 9;
  const int n = r & (CN - 1);
  const float pv = pre[i];
  float acc = 0.f;
#pragma unroll
  for (int w = 0; w <= 4; ++w) {
    const float xv = pv + ((n >= w) ? nb[(size_t)i - (size_t)w * CD] : 0.f);
    acc += geluf(xv);
  }
  G[i] = acc * 0.2f;
}

__global__ void rotary_k(float* __restrict__ t)
{
  const int i = blockIdx.x * 256 + threadIdx.x;
  const int r = i >> 8, j = i & 255;
  const int n = r & (CN - 1);
  const float fr = (float)n * expf(-9.210340371976184f * ((float)j * (1.f / 256.f)));
  float s, c;
  sincosf(fr, &s, &c);
  float* p = t + (size_t)r * CD;
  const float t1 = p[j], t2 = p[j + 256];
  p[j] = t1 * c - t2 * s;
  p[j + 256] = t2 * c + t1 * s;
}

// ---------------- parallel top-K: one block per row ----------------
__global__ __launch_bounds__(256) void topk_softmax2(const float* __restrict__ scores,
                                                     float* __restrict__ probs, int* __restrict__ idxs)
{
  const int rrow = blockIdx.x;                 // ROWS
  const int b = rrow >> 10, n = rrow & (CN - 1);
  const float* row = scores + ((size_t)b * CN + n) * CN;
  __shared__ float sv[CN];
  __shared__ unsigned long long wred[4];
  __shared__ float topv[CK];
  __shared__ int topi[CK];
  const int tid = threadIdx.x;
#pragma unroll
  for (int q = 0; q < 4; ++q) {
    const int m = tid + q * 256;
    sv[m] = (m <= n) ? row[m] : -INFINITY;
  }
  __syncthreads();
  for (int it = 0; it < CK; ++it) {
    unsigned long long best = 0ull;
#pragma unroll
    for (int q = 0; q < 4; ++q) {
      const int m = tid + q * 256;
      unsigned u = __float_as_uint(sv[m]);
      u = (u & 0x80000000u) ? ~u : (u | 0x80000000u);   // order-preserving map
      const unsigned long long key = ((unsigned long long)u << 32) | (unsigned)(CN - 1 - m);
      best = best > key ? best : key;
    }
#pragma unroll
    for (int o = 32; o > 0; o >>= 1) {
      const unsigned long long o2 = __shfl_down(best, o, 64);
      best = best > o2 ? best : o2;
    }
    if ((tid & 63) == 0) wred[tid >> 6] = best;
    __syncthreads();
    if (tid == 0) {
      unsigned long long b0 = wred[0];
      for (int w = 1; w < 4; ++w) b0 = b0 > wred[w] ? b0 : wred[w];
      const int m = CN - 1 - (int)(b0 & 0xFFFFFFFFu);
      unsigned u = (unsigned)(b0 >> 32);
      u = (u & 0x80000000u) ? (u & 0x7FFFFFFFu) : ~u;
      topv[it] = __uint_as_float(u);
      topi[it] = m;
      sv[m] = -INFINITY;
    }
    __syncthreads();
  }
  if (tid < CK) {
    const float mx = topv[0];
    float sum = 0.f;
#pragma unroll
    for (int q = 0; q < CK; ++q)
      sum += (topv[q] == -INFINITY) ? 0.f : expf(topv[q] - mx);
    const float e = (topv[tid] == -INFINITY) ? 0.f : expf(topv[tid] - mx);
    probs[(size_t)rrow * CK + tid] = e / sum;
    idxs[(size_t)rrow * CK + tid] = topi[tid];
  }
}

__global__ __launch_bounds__(128) void topk_gather(const float* __restrict__ probs,
                                                   const int* __restrict__ idxs,
                                                   const float* __restrict__ v,
                                                   float* __restrict__ ctx)
{
  const int r = blockIdx.x;
  const int b = r >> 10;
  __shared__ float p[CK];
  __shared__ int id[CK];
  if (threadIdx.x < CK) {
    p[threadIdx.x] = probs[(size_t)r * CK + threadIdx.x];
    id[threadIdx.x] = idxs[(size_t)r * CK + threadIdx.x];
  }
  __syncthreads();
  for (int d = threadIdx.x; d < CD; d += 128) {
    float a = 0.f;
#pragma unroll
    for (int q = 0; q < CK; ++q)
      a += p[q] * v[((size_t)(b << 10) + id[q]) * CD + d];
    ctx[(size_t)r * CD + d] = a;
  }
}

__global__ __launch_bounds__(256) void gru_ln(const float* __restrict__ gi, const float* __restrict__ gh,
                                              float* __restrict__ h, const float* __restrict__ g,
                                              const float* __restrict__ b)
{
  const int r = blockIdx.x, t = threadIdx.x;
  __shared__ float red[4];
  float u[2];
#pragma unroll
  for (int q = 0; q < 2; ++q) {
    const int d = t + q * 256;
    const size_t gb = (size_t)r * (3 * CD) + d;
    const float ir = gi[gb], iz = gi[gb + CD], inn = gi[gb + 2 * CD];
    const float hr = gh[gb], hz = gh[gb + CD], hn = gh[gb + 2 * CD];
    const float hp = h[(size_t)r * CD + d];
    const float rr = sigm(ir + hr), zz = sigm(iz + hz);
    const float nn = tanhf(inn + rr * hn);
    u[q] = (1.f - zz) * nn + zz * hp;
  }
  const float mu = blk_sum(u[0] + u[1], red) * (1.f / CD);
  const float d0 = u[0] - mu, d1 = u[1] - mu;
  const float var = blk_sum(d0 * d0 + d1 * d1, red) * (1.f / CD);
  const float inv = rsqrtf(var + CEPS);
  h[(size_t)r * CD + t] = d0 * inv * g[t] + b[t];
  h[(size_t)r * CD + t + 256] = d1 * inv * g[t + 256] + b[t + 256];
}

// ---------------- flash-tile causal MHA (hd=64) ----------------
// grid (N/64, H, B), 256 threads; qkv packed (B,N,3D); out (B,N,D)
// LDS tiles XOR-quad-swizzled: quad' = quad ^ (row>>2) keeps reads <=2-way.
__global__ __launch_bounds__(256) void flash_attn(const float* __restrict__ qkv,
                                                  float* __restrict__ out)
{
  __shared__ float Qs[64][64];
  __shared__ float Ks[64][64];
  __shared__ float Vs[64][64];
  __shared__ float Ps[64][64];
  const int qt = blockIdx.x, head = blockIdx.y, b = blockIdx.z;
  const int tid = threadIdx.x;
  const int tx = tid & 15, ty = tid >> 4;
  const size_t base = (size_t)b * CN * (3 * CD) + head * CHD;
  // load Q tile (swizzled)
#pragma unroll
  for (int p = 0; p < 4; ++p) {
    const int r = p * 16 + (tid >> 4);
    const int cq = tid & 15;
    *(float4*)&Qs[r][((cq ^ (r >> 2)) << 2)] =
        *(const float4*)(qkv + base + (size_t)(qt * 64 + r) * (3 * CD) + (cq << 2));
  }
  float m_i[4], l_i[4], O[4][4];
#pragma unroll
  for (int i = 0; i < 4; ++i) {
    m_i[i] = -INFINITY; l_i[i] = 0.f;
#pragma unroll
    for (int d = 0; d < 4; ++d) O[i][d] = 0.f;
  }
  for (int j = 0; j <= qt; ++j) {
    __syncthreads();   // protect K/V/P from still-reading previous iteration
#pragma unroll
    for (int p = 0; p < 4; ++p) {
      const int r = p * 16 + (tid >> 4);
      const int cq = tid & 15;
      const size_t rb = base + (size_t)(j * 64 + r) * (3 * CD);
      *(float4*)&Ks[r][((cq ^ (r >> 2)) << 2)] = *(const float4*)(qkv + rb + CD + (cq << 2));
      *(float4*)&Vs[r][((cq ^ (r >> 2)) << 2)] = *(const float4*)(qkv + rb + 2 * CD + (cq << 2));
    }
    __syncthreads();
    // S = Q . K^T  (4x4 per thread, k-depth 64)
    float S[4][4] = {};
#pragma unroll
    for (int kq = 0; kq < 16; ++kq) {
      float4 qv[4], kv[4];
#pragma unroll
      for (int i = 0; i < 4; ++i) qv[i] = *(const float4*)&Qs[ty * 4 + i][((kq ^ ty) << 2)];
#pragma unroll
      for (int jc = 0; jc < 4; ++jc) kv[jc] = *(const float4*)&Ks[tx * 4 + jc][((kq ^ tx) << 2)];
#pragma unroll
      for (int i = 0; i < 4; ++i)
#pragma unroll
        for (int jc = 0; jc < 4; ++jc)
          S[i][jc] += qv[i].x * kv[jc].x + qv[i].y * kv[jc].y +
                      qv[i].z * kv[jc].z + qv[i].w * kv[jc].w;
    }
    // scale + causal mask (diagonal tile only)
#pragma unroll
    for (int i = 0; i < 4; ++i)
#pragma unroll
      for (int jc = 0; jc < 4; ++jc) {
        S[i][jc] *= 0.125f;
        if (j == qt && (tx * 4 + jc) > (ty * 4 + i)) S[i][jc] = -1e30f;
      }
    // online softmax per row (reduce across the 16 tx lanes)
#pragma unroll
    for (int i = 0; i < 4; ++i) {
      float rm = fmaxf(fmaxf(S[i][0], S[i][1]), fmaxf(S[i][2], S[i][3]));
#pragma unroll
      for (int o = 8; o > 0; o >>= 1) rm = fmaxf(rm, __shfl_xor(rm, o, 64));
      const float newm = fmaxf(m_i[i], rm);
      float p0 = expf(S[i][0] - newm), p1 = expf(S[i][1] - newm);
      float p2 = expf(S[i][2] - newm), p3 = expf(S[i][3] - newm);
      float rs = p0 + p1 + p2 + p3;
#pragma unroll
      for (int o = 8; o > 0; o >>= 1) rs += __shfl_xor(rs, o, 64);
      const float alpha = expf(m_i[i] - newm);
      l_i[i] = l_i[i] * alpha + rs;
      m_i[i] = newm;
#pragma unroll
      for (int d = 0; d < 4; ++d) O[i][d] *= alpha;
      const int r = ty * 4 + i;
      *(float4*)&Ps[r][((tx ^ ty) << 2)] = make_float4(p0, p1, p2, p3);
    }
    __syncthreads();
    // O += P . V  (4 rows x 4 dims per thread, m-depth 64)
#pragma unroll
    for (int mq = 0; mq < 16; ++mq) {
      float4 pv[4], vv[4];
#pragma unroll
      for (int i = 0; i < 4; ++i) pv[i] = *(const float4*)&Ps[ty * 4 + i][((mq ^ ty) << 2)];
#pragma unroll
      for (int mm = 0; mm < 4; ++mm) vv[mm] = *(const float4*)&Vs[mq * 4 + mm][((tx ^ mq) << 2)];
#pragma unroll
      for (int i = 0; i < 4; ++i) {
        O[i][0] += pv[i].x * vv[0].x + pv[i].y * vv[1].x + pv[i].z * vv[2].x + pv[i].w * vv[3].x;
        O[i][1] += pv[i].x * vv[0].y + pv[i].y * vv[1].y + pv[i].z * vv[2].y + pv[i].w * vv[3].y;
        O[i][2] += pv[i].x * vv[0].z + pv[i].y * vv[1].z + pv[i].z * vv[2].z + pv[i].w * vv[3].z;
        O[i][3] += pv[i].x * vv[0].w + pv[i].y * vv[1].w + pv[i].z * vv[2].w + pv[i].w * vv[3].w;
      }
    }
  }
#pragma unroll
  for (int i = 0; i < 4; ++i) {
    const float inv = 1.f / l_i[i];
    float* op = out + ((size_t)b * CN + qt * 64 + ty * 4 + i) * CD + head * CHD + tx * 4;
    *(float4*)op = make_float4(O[i][0] * inv, O[i][1] * inv, O[i][2] * inv, O[i][3] * inv);
  }
}

__global__ __launch_bounds__(256) void final_ln(const float* __restrict__ local,
                                                const float* __restrict__ broad,
                                                const float* __restrict__ g, const float* __restrict__ bb,
                                                float* __restrict__ out)
{
  const int r = blockIdx.x, t = threadIdx.x;
  __shared__ float red[4];
  const size_t lb = (size_t)r * CD;
  const size_t br = (size_t)(r >> 2) * CD;
  const float v0 = local[lb + t] + broad[br + t];
  const float v1 = local[lb + 256 + t] + broad[br + 256 + t];
  const float mu = blk_sum(v0 + v1, red) * (1.f / CD);
  const float d0 = v0 - mu, d1 = v1 - mu;
  const float var = blk_sum(d0 * d0 + d1 * d1, red) * (1.f / CD);
  const float inv = rsqrtf(var + CEPS);
  out[lb + t] = d0 * inv * g[t] + bb[t];
  out[lb + 256 + t] = d1 * inv * g[t + 256] + bb[t + 256];
}

// ---------------- launcher ----------------
extern "C" void kernel_launch(void* const* d_in, const int* in_sizes, int n_in,
                              void* d_out, int out_size, void* d_ws, size_t ws_size,
                              hipStream_t stream)
{
  (void)in_sizes; (void)n_in; (void)out_size; (void)ws_size;
  const int*   x         = (const int*)d_in[0];
  const float* emb       = (const float*)d_in[1];
  const float* pos_emb   = (const float*)d_in[2];
  const float* gru_w_ih  = (const float*)d_in[3];
  const float* gru_w_hh  = (const float*)d_in[4];
  const float* gru_b_ih  = (const float*)d_in[5];
  const float* gru_b_hh  = (const float*)d_in[6];
  const float* patch_g   = (const float*)d_in[7];
  const float* patch_b   = (const float*)d_in[8];
  const float* summ_w    = (const float*)d_in[9];
  const float* summ_b    = (const float*)d_in[10];
  const float* msg_w1    = (const float*)d_in[11];
  const float* msg_b1    = (const float*)d_in[12];
  const float* msg_w2    = (const float*)d_in[13];
  const float* msg_b2    = (const float*)d_in[14];
  const float* msg_ln_g  = (const float*)d_in[15];
  const float* msg_ln_b  = (const float*)d_in[16];
  const float* q_w       = (const float*)d_in[17];
  const float* q_b       = (const float*)d_in[18];
  const float* k_w       = (const float*)d_in[19];
  const float* k_b       = (const float*)d_in[20];
  const float* v_w       = (const float*)d_in[21];
  const float* v_b       = (const float*)d_in[22];
  const float* o_w       = (const float*)d_in[23];
  const float* o_b       = (const float*)d_in[24];
  const float* gc_w_ih   = (const float*)d_in[25];
  const float* gc_w_hh   = (const float*)d_in[26];
  const float* gc_b_ih   = (const float*)d_in[27];
  const float* gc_b_hh   = (const float*)d_in[28];
  const float* ar_ln_g   = (const float*)d_in[29];
  const float* ar_ln_b   = (const float*)d_in[30];
  const float* ar_qkv_w  = (const float*)d_in[31];
  const float* ar_qkv_b  = (const float*)d_in[32];
  const float* ar_out_w  = (const float*)d_in[33];
  const float* ar_out_b  = (const float*)d_in[34];
  const float* broad_w   = (const float*)d_in[35];
  const float* broad_b   = (const float*)d_in[36];
  const float* ln_g      = (const float*)d_in[37];
  const float* ln_b      = (const float*)d_in[38];
  const float* head_w    = (const float*)d_in[39];
  float* out = (float*)d_out;

  float* ws = (float*)d_ws;
  float* Wl    = ws + OFF_LOCAL;
  float* Wh    = ws + OFF_H;
  float* Wgi   = ws + OFF_GI;
  float* Wgh   = ws + OFF_GH;
  float* Wq    = ws + OFF_Q;
  float* Wk    = ws + OFF_K;
  float* Wv    = ws + OFF_V;
  float* Wmsgs = ws + OFF_MSGS;
  float* Wprob = ws + OFF_PROB;
  int*   Widx  = (int*)(ws + OFF_IDX);
  float* Wscores = Wgi;
  float* Wfinal  = Wgi;

  const int EW = ROWS * CD / 256;
  const float inv_sqrt_d = 0.04419417382415922f;   // 1/sqrt(512)

  // ---- patch GRU over P=4 steps ----
  zero_k<<<EW, 256, 0, stream>>>(Wh);
  for (int t = 0; t < CP; ++t) {
    embed_step<<<EW, 256, 0, stream>>>(x, emb, pos_emb, Wq, t);
    gemm_nn<<<dim3(24, 128), 256, 0, stream>>>(
        Wq, gru_w_ih, gru_b_ih, Wgi, ROWS, 1536, 512, 512, 1536, 1536, 0);
    gemm_nn<<<dim3(24, 128), 256, 0, stream>>>(
        Wh, gru_w_hh, gru_b_hh, Wgh, ROWS, 1536, 512, 512, 1536, 1536, 0);
    gru_point<<<EW, 256, 0, stream>>>(Wgi, Wgh, Wh, Wl, t);
  }
  ln_rows<<<TROWS, 256, 0, stream>>>(Wl, Wl, patch_g, patch_b);
  mean_pool<<<EW, 256, 0, stream>>>(Wl, Wk);
  gemm_nn<<<dim3(8, 128), 256, 0, stream>>>(
      Wk, summ_w, summ_b, Wh, ROWS, 512, 512, 512, 512, 512, 0);

  // ---- rounds ----
  for (int rnd = 0; rnd < 6; ++rnd) {
    gemm_nn<<<dim3(8, 128), 256, 0, stream>>>(Wh, msg_w1, msg_b1, Wq,
                                              ROWS, 512, 512, 512, 512, 512, 0);
    gemm_nn<<<dim3(8, 128), 256, 0, stream>>>(Wh, msg_w1 + (size_t)512 * 512, nullptr, Wk,
                                              ROWS, 512, 512, 512, 512, 512, 0);
    msg_gelu<<<EW, 256, 0, stream>>>(Wq, Wk, Wv);
    gemm_nn<<<dim3(8, 128), 256, 0, stream>>>(Wv, msg_w2, msg_b2, Wmsgs,
                                              ROWS, 512, 512, 512, 512, 512, 0);
    gemm_nn<<<dim3(8, 128), 256, 0, stream>>>(Wh, q_w, q_b, Wq, ROWS, 512, 512, 512, 512, 512, 0);
    rotary_k<<<ROWS, 256, 0, stream>>>(Wq);
    gemm_nn<<<dim3(8, 128), 256, 0, stream>>>(Wh, k_w, k_b, Wk, ROWS, 512, 512, 512, 512, 512, 0);
    rotary_k<<<ROWS, 256, 0, stream>>>(Wk);
    gemm_nn<<<dim3(8, 128), 256, 0, stream>>>(Wh, v_w, v_b, Wv, ROWS, 512, 512, 512, 512, 512, 0);
    gemm_nt<<<dim3(16, 16, CB), 256, 0, stream>>>(
        Wq, Wk, Wscores, CN, CN, 512, 512, 512, CN,
        (long long)CN * CD, (long long)CN * CD, (long long)CN * CN, inv_sqrt_d);
    topk_softmax2<<<ROWS, 256, 0, stream>>>(Wscores, Wprob, Widx);
    topk_gather<<<ROWS, 128, 0, stream>>>(Wprob, Widx, Wv, Wq);
    gemm_nn<<<dim3(8, 128), 256, 0, stream>>>(Wq, o_w, o_b, Wk,
                                              ROWS, 512, 512, 512, 512, 512, 0);
    gemm_nn<<<dim3(24, 128), 256, 0, stream>>>(Wmsgs, gc_w_ih, gc_b_ih, Wgi,
                                               ROWS, 1536, 512, 512, 1536, 1536, 0);
    gemm_nn<<<dim3(24, 128), 256, 0, stream>>>(Wk, gc_w_ih + (size_t)512 * 1536, nullptr, Wgi,
                                               ROWS, 1536, 512, 512, 1536, 1536, 1);
    gemm_nn<<<dim3(24, 128), 256, 0, stream>>>(Wh, gc_w_hh, gc_b_hh, Wgh,
                                               ROWS, 1536, 512, 512, 1536, 1536, 0);
    gru_ln<<<ROWS, 256, 0, stream>>>(Wgi, Wgh, Wh, msg_ln_g, msg_ln_b);
    if ((rnd & 1) == 1) {
      ln_rows<<<ROWS, 256, 0, stream>>>(Wh, Wq, ar_ln_g, ar_ln_b);
      gemm_nn<<<dim3(24, 128), 256, 0, stream>>>(Wq, ar_qkv_w, ar_qkv_b, Wgi,
                                                 ROWS, 1536, 512, 512, 1536, 1536, 0);
      flash_attn<<<dim3(16, CH, CB), 256, 0, stream>>>(Wgi, Wk);
      gemm_nn<<<dim3(8, 128), 256, 0, stream>>>(Wk, ar_out_w, ar_out_b, Wh,
                                                ROWS, 512, 512, 512, 512, 512, 1);
    }
  }

  // ---- head ----
  gemm_nn<<<dim3(8, 128), 256, 0, stream>>>(Wh, broad_w, broad_b, Wq,
                                            ROWS, 512, 512, 512, 512, 512, 0);
  final_ln<<<TROWS, 256, 0, stream>>>(Wl, Wq, ln_g, ln_b, Wfinal);
  gemm_nn<<<dim3(CV / 64, TROWS / 64), 256, 0, stream>>>(
      Wfinal, head_w, nullptr, out, TROWS, CV, 512, 512, CV, CV, 0);
}

// Round 3
// 6998.104 us; speedup vs baseline: 2.9633x; 1.8986x over previous
//
#include <hip/hip_runtime.h>
#include <math.h>

// ---------------- problem constants ----------------
constexpr int CB = 8, CT = 4096, CP = 4, CD = 512, CV = 256;
constexpr int CN = 1024, CK = 16, CH = 8, CHD = 64;
constexpr int ROWS = CB * CN;     // 8192
constexpr int TROWS = CB * CT;    // 32768
constexpr float CEPS = 1e-5f;

// ---------------- workspace layout (floats) ----------------
// GI holds: gi (8192x1536) / scores (8x1024x1024) / final[0:12.58M]
// GHN holds: gh n-gate (8192x512) / final tail. GI+GHN = exactly TROWS*CD.
constexpr size_t OFF_LOCAL = 0;                                    // 16,777,216
constexpr size_t OFF_H     = OFF_LOCAL + (size_t)ROWS * CP * CD;   //  4,194,304
constexpr size_t OFF_GI    = OFF_H     + (size_t)ROWS * CD;        // 12,582,912
constexpr size_t OFF_GHN   = OFF_GI    + (size_t)ROWS * 3 * CD;    //  4,194,304
constexpr size_t OFF_Q     = OFF_GHN   + (size_t)ROWS * CD;        //  4,194,304
constexpr size_t OFF_K     = OFF_Q     + (size_t)ROWS * CD;        //  4,194,304
constexpr size_t OFF_V     = OFF_K     + (size_t)ROWS * CD;        //  4,194,304
constexpr size_t OFF_MSGS  = OFF_V     + (size_t)ROWS * CD;        //  4,194,304
constexpr size_t OFF_PROB  = OFF_MSGS  + (size_t)ROWS * CD;        //    131,072
constexpr size_t OFF_IDX   = OFF_PROB  + (size_t)ROWS * CK;        //    131,072
constexpr size_t OFF_WT    = OFF_IDX   + (size_t)ROWS * CK;        //  7,471,104
// total 62,259,200 floats = 237.5 MiB  (< the 241 MiB already proven OK)

// transposed-weight sub-offsets (floats, relative to OFF_WT)
constexpr size_t T_GRU_IH = 0;                    // 1536x512
constexpr size_t T_GRU_HH = T_GRU_IH + 786432;    // 1536x512
constexpr size_t T_SUMM   = T_GRU_HH + 786432;    // 512x512
constexpr size_t T_MSG1A  = T_SUMM   + 262144;
constexpr size_t T_MSG1B  = T_MSG1A  + 262144;
constexpr size_t T_MSG2   = T_MSG1B  + 262144;
constexpr size_t T_QW     = T_MSG2   + 262144;
constexpr size_t T_KW     = T_QW     + 262144;
constexpr size_t T_VW     = T_KW     + 262144;
constexpr size_t T_OW     = T_VW     + 262144;
constexpr size_t T_GC_TOP = T_OW     + 262144;    // 1536x512
constexpr size_t T_GC_BOT = T_GC_TOP + 786432;    // 1536x512
constexpr size_t T_GC_HH  = T_GC_BOT + 786432;    // 1536x512
constexpr size_t T_AR_QKV = T_GC_HH  + 786432;    // 1536x512
constexpr size_t T_AR_OUT = T_AR_QKV + 786432;    // 512x512
constexpr size_t T_BROAD  = T_AR_OUT + 262144;
constexpr size_t T_HEAD   = T_BROAD  + 262144;    // 256x512

// ---------------- device helpers ----------------
typedef __attribute__((ext_vector_type(8))) short short8;
typedef __attribute__((ext_vector_type(4))) float f32x4;

__device__ __forceinline__ float sigm(float x) { return 1.f / (1.f + expf(-x)); }
__device__ __forceinline__ float geluf(float x) {
  return 0.5f * x * (1.f + erff(x * 0.7071067811865475f));
}
__device__ __forceinline__ unsigned short bf_hi(float x) {
  const unsigned u = __float_as_uint(x);
  return (unsigned short)((u + 0x7FFFu + ((u >> 16) & 1u)) >> 16);
}
__device__ __forceinline__ float bf_f(unsigned short h) {
  return __uint_as_float((unsigned)h << 16);
}
__device__ __forceinline__ float blk_sum(float v, float* red) {
#pragma unroll
  for (int o = 32; o > 0; o >>= 1) v += __shfl_down(v, o, 64);
  const int wv = threadIdx.x >> 6, ln = threadIdx.x & 63;
  __syncthreads();
  if (ln == 0) red[wv] = v;
  __syncthreads();
  return red[0] + red[1] + red[2] + red[3];
}

// ---------------- weight transpose: out[n][k] = in[k][n] ----------------
__global__ __launch_bounds__(256) void transpose_k(const float* __restrict__ in,
                                                   float* __restrict__ outp, int K, int N)
{
  __shared__ float tile[32][33];
  const int n0 = blockIdx.x * 32, k0 = blockIdx.y * 32;
  const int tx = threadIdx.x & 31, ty = threadIdx.x >> 5;   // 32 x 8
#pragma unroll
  for (int i = 0; i < 32; i += 8)
    tile[ty + i][tx] = in[(size_t)(k0 + ty + i) * N + n0 + tx];
  __syncthreads();
#pragma unroll
  for (int i = 0; i < 32; i += 8)
    outp[(size_t)(n0 + ty + i) * K + k0 + tx] = tile[tx][ty + i];
}

// ---------------- split-bf16 MFMA GEMM ----------------
// C[M,N] (+)= scale * A[M,K] @ Bt[N,K]^T (+ bias[col]).
// Split x = hi + lo (bf16 each); C = Ah.Bh + Ah.Bl + Al.Bh  (fp32-grade).
// 128x128 tile, BK=32, 4 waves in 2x2, each wave 4x4 grid of 16x16x32 MFMA.
// All of M,N multiples of 128; K multiple of 32; row strides multiples of 4.
__global__ __launch_bounds__(256, 2) void gemm_mfma(
    const float* __restrict__ A, const float* __restrict__ Bt,
    const float* __restrict__ bias, float* __restrict__ C,
    int lda, int ldb, int ldc, int K, int accum, float scale,
    long long sA, long long sB, long long sC)
{
  A  += (size_t)blockIdx.z * sA;
  Bt += (size_t)blockIdx.z * sB;
  C  += (size_t)blockIdx.z * sC;
  // 40-ushort row pitch (80 B): 16B-aligned, frag reads <=2-way conflicted
  __shared__ __align__(16) unsigned short AsH[128][40];
  __shared__ __align__(16) unsigned short AsL[128][40];
  __shared__ __align__(16) unsigned short BsH[128][40];
  __shared__ __align__(16) unsigned short BsL[128][40];
  const int tid = threadIdx.x;
  const int bm = blockIdx.y << 7, bn = blockIdx.x << 7;
  const int lane = tid & 63, wave = tid >> 6;
  const int wm = (wave & 1) << 6, wn = (wave >> 1) << 6;
  const int r16 = lane & 15, quad = lane >> 4;
  const int sr = tid >> 1, sc = (tid & 1) << 4;    // staging: row, 16-float half
  const f32x4 zero = {0.f, 0.f, 0.f, 0.f};
  f32x4 acc[4][4];
#pragma unroll
  for (int i = 0; i < 4; ++i)
#pragma unroll
    for (int j = 0; j < 4; ++j) acc[i][j] = zero;

  for (int k0 = 0; k0 < K; k0 += 32) {
    const float* Ap = A + (size_t)(bm + sr) * lda + k0 + sc;
    const float* Bp = Bt + (size_t)(bn + sr) * ldb + k0 + sc;
#pragma unroll
    for (int q = 0; q < 4; ++q) {
      const float4 av = *(const float4*)(Ap + q * 4);
      ushort4 h, l;
      h.x = bf_hi(av.x); h.y = bf_hi(av.y); h.z = bf_hi(av.z); h.w = bf_hi(av.w);
      l.x = bf_hi(av.x - bf_f(h.x)); l.y = bf_hi(av.y - bf_f(h.y));
      l.z = bf_hi(av.z - bf_f(h.z)); l.w = bf_hi(av.w - bf_f(h.w));
      *(ushort4*)&AsH[sr][sc + q * 4] = h;
      *(ushort4*)&AsL[sr][sc + q * 4] = l;
      const float4 bv = *(const float4*)(Bp + q * 4);
      ushort4 bh4, bl4;
      bh4.x = bf_hi(bv.x); bh4.y = bf_hi(bv.y); bh4.z = bf_hi(bv.z); bh4.w = bf_hi(bv.w);
      bl4.x = bf_hi(bv.x - bf_f(bh4.x)); bl4.y = bf_hi(bv.y - bf_f(bh4.y));
      bl4.z = bf_hi(bv.z - bf_f(bh4.z)); bl4.w = bf_hi(bv.w - bf_f(bh4.w));
      *(ushort4*)&BsH[sr][sc + q * 4] = bh4;
      *(ushort4*)&BsL[sr][sc + q * 4] = bl4;
    }
    __syncthreads();
    short8 bh[4], bl[4];
#pragma unroll
    for (int ni = 0; ni < 4; ++ni) {
      bh[ni] = *(const short8*)&BsH[wn + ni * 16 + r16][quad * 8];
      bl[ni] = *(const short8*)&BsL[wn + ni * 16 + r16][quad * 8];
    }
#pragma unroll
    for (int mi = 0; mi < 4; ++mi) {
      const short8 ah = *(const short8*)&AsH[wm + mi * 16 + r16][quad * 8];
      const short8 al = *(const short8*)&AsL[wm + mi * 16 + r16][quad * 8];
#pragma unroll
      for (int ni = 0; ni < 4; ++ni) {
        acc[mi][ni] = __builtin_amdgcn_mfma_f32_16x16x32_bf16(ah, bh[ni], acc[mi][ni], 0, 0, 0);
        acc[mi][ni] = __builtin_amdgcn_mfma_f32_16x16x32_bf16(ah, bl[ni], acc[mi][ni], 0, 0, 0);
        acc[mi][ni] = __builtin_amdgcn_mfma_f32_16x16x32_bf16(al, bh[ni], acc[mi][ni], 0, 0, 0);
      }
    }
    __syncthreads();
  }
  // epilogue: C/D layout col=lane&15, row=quad*4+reg  [m89-verified]
#pragma unroll
  for (int mi = 0; mi < 4; ++mi) {
    const int row0 = bm + wm + mi * 16 + quad * 4;
#pragma unroll
    for (int ni = 0; ni < 4; ++ni) {
      const int col = bn + wn + ni * 16 + r16;
      const float bv = bias ? bias[col] : 0.f;
#pragma unroll
      for (int rg = 0; rg < 4; ++rg) {
        float* Cp = C + (size_t)(row0 + rg) * ldc + col;
        float o = acc[mi][ni][rg] * scale + bv;
        if (accum) o += *Cp;
        *Cp = o;
      }
    }
  }
}

// ---------------- small kernels ----------------
__global__ void zero_k(float* __restrict__ p) {
  p[(size_t)blockIdx.x * 256 + threadIdx.x] = 0.f;
}

__global__ void embed_step(const int* __restrict__ x, const float* __restrict__ emb,
                           const float* __restrict__ pos, float* __restrict__ Xt, int t)
{
  const int i = blockIdx.x * 256 + threadIdx.x;
  const int r = i >> 9, d = i & 511;
  const int b = r >> 10, n = r & (CN - 1);
  const int tok = x[b * CT + n * CP + t];
  Xt[i] = emb[(size_t)tok * CD + d] + pos[t * CD + d];
}

// GI cols 0..1023 hold summed gate pre-acts (ir+hr, iz+hz); cols 1024..1535 = inn;
// GHN holds hn.
__global__ void gru_point(const float* __restrict__ gi, const float* __restrict__ ghn,
                          float* __restrict__ h, float* __restrict__ hs, int t)
{
  const int i = blockIdx.x * 256 + threadIdx.x;
  const int r = i >> 9, d = i & 511;
  const size_t gb = (size_t)r * (3 * CD) + d;
  const float sr_ = gi[gb], sz = gi[gb + CD], inn = gi[gb + 2 * CD];
  const float hn = ghn[i];
  const float hp = h[i];
  const float rr = sigm(sr_), zz = sigm(sz);
  const float nn = tanhf(inn + rr * hn);
  const float hv = (1.f - zz) * nn + zz * hp;
  h[i] = hv;
  hs[(size_t)r * (CP * CD) + (size_t)t * CD + d] = hv;
}

__global__ __launch_bounds__(256) void ln_rows(const float* __restrict__ in, float* __restrict__ out,
                                               const float* __restrict__ g, const float* __restrict__ b)
{
  const int r = blockIdx.x, t = threadIdx.x;
  __shared__ float red[4];
  const float* ip = in + (size_t)r * CD;
  const float v0 = ip[t], v1 = ip[t + 256];
  const float mu = blk_sum(v0 + v1, red) * (1.f / CD);
  const float d0 = v0 - mu, d1 = v1 - mu;
  const float var = blk_sum(d0 * d0 + d1 * d1, red) * (1.f / CD);
  const float inv = rsqrtf(var + CEPS);
  float* op = out + (size_t)r * CD;
  op[t] = d0 * inv * g[t] + b[t];
  op[t + 256] = d1 * inv * g[t + 256] + b[t + 256];
}

__global__ void mean_pool(const float* __restrict__ local, float* __restrict__ hm)
{
  const int i = blockIdx.x * 256 + threadIdx.x;
  const int r = i >> 9, d = i & 511;
  const float* p = local + (size_t)r * (CP * CD) + d;
  hm[i] = 0.25f * (p[0] + p[CD] + p[2 * CD] + p[3 * CD]);
}

__global__ void msg_gelu(const float* __restrict__ pre, const float* __restrict__ nb,
                         float* __restrict__ G)
{
  const int i = blockIdx.x * 256 + threadIdx.x;
  const int r = i >> 9;
  const int n = r & (CN - 1);
  const float pv = pre[i];
  float acc = 0.f;
#pragma unroll
  for (int w = 0; w <= 4; ++w) {
    const float xv = pv + ((n >= w) ? nb[(size_t)i - (size_t)w * CD] : 0.f);
    acc += geluf(xv);
  }
  G[i] = acc * 0.2f;
}

__global__ void rotary_k(float* __restrict__ t)
{
  const int i = blockIdx.x * 256 + threadIdx.x;
  const int r = i >> 8, j = i & 255;
  const int n = r & (CN - 1);
  const float fr = (float)n * expf(-9.210340371976184f * ((float)j * (1.f / 256.f)));
  float s, c;
  sincosf(fr, &s, &c);
  float* p = t + (size_t)r * CD;
  const float t1 = p[j], t2 = p[j + 256];
  p[j] = t1 * c - t2 * s;
  p[j + 256] = t2 * c + t1 * s;
}

// ---------------- parallel top-K: one block per row ----------------
__global__ __launch_bounds__(256) void topk_softmax2(const float* __restrict__ scores,
                                                     float* __restrict__ probs, int* __restrict__ idxs)
{
  const int rrow = blockIdx.x;
  const int b = rrow >> 10, n = rrow & (CN - 1);
  const float* row = scores + ((size_t)b * CN + n) * CN;
  __shared__ float sv[CN];
  __shared__ unsigned long long wred[4];
  __shared__ float topv[CK];
  __shared__ int topi[CK];
  const int tid = threadIdx.x;
#pragma unroll
  for (int q = 0; q < 4; ++q) {
    const int m = tid + q * 256;
    sv[m] = (m <= n) ? row[m] : -INFINITY;
  }
  __syncthreads();
  for (int it = 0; it < CK; ++it) {
    unsigned long long best = 0ull;
#pragma unroll
    for (int q = 0; q < 4; ++q) {
      const int m = tid + q * 256;
      unsigned u = __float_as_uint(sv[m]);
      u = (u & 0x80000000u) ? ~u : (u | 0x80000000u);
      const unsigned long long key = ((unsigned long long)u << 32) | (unsigned)(CN - 1 - m);
      best = best > key ? best : key;
    }
#pragma unroll
    for (int o = 32; o > 0; o >>= 1) {
      const unsigned long long o2 = __shfl_down(best, o, 64);
      best = best > o2 ? best : o2;
    }
    if ((tid & 63) == 0) wred[tid >> 6] = best;
    __syncthreads();
    if (tid == 0) {
      unsigned long long b0 = wred[0];
      for (int w = 1; w < 4; ++w) b0 = b0 > wred[w] ? b0 : wred[w];
      const int m = CN - 1 - (int)(b0 & 0xFFFFFFFFu);
      unsigned u = (unsigned)(b0 >> 32);
      u = (u & 0x80000000u) ? (u & 0x7FFFFFFFu) : ~u;
      topv[it] = __uint_as_float(u);
      topi[it] = m;
      sv[m] = -INFINITY;
    }
    __syncthreads();
  }
  if (tid < CK) {
    const float mx = topv[0];
    float sum = 0.f;
#pragma unroll
    for (int q = 0; q < CK; ++q)
      sum += (topv[q] == -INFINITY) ? 0.f : expf(topv[q] - mx);
    const float e = (topv[tid] == -INFINITY) ? 0.f : expf(topv[tid] - mx);
    probs[(size_t)rrow * CK + tid] = e / sum;
    idxs[(size_t)rrow * CK + tid] = topi[tid];
  }
}

__global__ __launch_bounds__(128) void topk_gather(const float* __restrict__ probs,
                                                   const int* __restrict__ idxs,
                                                   const float* __restrict__ v,
                                                   float* __restrict__ ctx)
{
  const int r = blockIdx.x;
  const int b = r >> 10;
  __shared__ float p[CK];
  __shared__ int id[CK];
  if (threadIdx.x < CK) {
    p[threadIdx.x] = probs[(size_t)r * CK + threadIdx.x];
    id[threadIdx.x] = idxs[(size_t)r * CK + threadIdx.x];
  }
  __syncthreads();
  for (int d = threadIdx.x; d < CD; d += 128) {
    float a = 0.f;
#pragma unroll
    for (int q = 0; q < CK; ++q)
      a += p[q] * v[((size_t)(b << 10) + id[q]) * CD + d];
    ctx[(size_t)r * CD + d] = a;
  }
}

__global__ __launch_bounds__(256) void gru_ln(const float* __restrict__ gi, const float* __restrict__ ghn,
                                              float* __restrict__ h, const float* __restrict__ g,
                                              const float* __restrict__ b)
{
  const int r = blockIdx.x, t = threadIdx.x;
  __shared__ float red[4];
  float u[2];
#pragma unroll
  for (int q = 0; q < 2; ++q) {
    const int d = t + q * 256;
    const size_t gb = (size_t)r * (3 * CD) + d;
    const float sr_ = gi[gb], sz = gi[gb + CD], inn = gi[gb + 2 * CD];
    const float hn = ghn[(size_t)r * CD + d];
    const float hp = h[(size_t)r * CD + d];
    const float rr = sigm(sr_), zz = sigm(sz);
    const float nn = tanhf(inn + rr * hn);
    u[q] = (1.f - zz) * nn + zz * hp;
  }
  const float mu = blk_sum(u[0] + u[1], red) * (1.f / CD);
  const float d0 = u[0] - mu, d1 = u[1] - mu;
  const float var = blk_sum(d0 * d0 + d1 * d1, red) * (1.f / CD);
  const float inv = rsqrtf(var + CEPS);
  h[(size_t)r * CD + t] = d0 * inv * g[t] + b[t];
  h[(size_t)r * CD + t + 256] = d1 * inv * g[t + 256] + b[t + 256];
}

// ---------------- flash-tile causal MHA (hd=64) ----------------
__global__ __launch_bounds__(256) void flash_attn(const float* __restrict__ qkv,
                                                  float* __restrict__ out)
{
  __shared__ float Qs[64][64];
  __shared__ float Ks[64][64];
  __shared__ float Vs[64][64];
  __shared__ float Ps[64][64];
  const int qt = blockIdx.x, head = blockIdx.y, b = blockIdx.z;
  const int tid = threadIdx.x;
  const int tx = tid & 15, ty = tid >> 4;
  const size_t base = (size_t)b * CN * (3 * CD) + head * CHD;
#pragma unroll
  for (int p = 0; p < 4; ++p) {
    const int r = p * 16 + (tid >> 4);
    const int cq = tid & 15;
    *(float4*)&Qs[r][((cq ^ (r >> 2)) << 2)] =
        *(const float4*)(qkv + base + (size_t)(qt * 64 + r) * (3 * CD) + (cq << 2));
  }
  float m_i[4], l_i[4], O[4][4];
#pragma unroll
  for (int i = 0; i < 4; ++i) {
    m_i[i] = -INFINITY; l_i[i] = 0.f;
#pragma unroll
    for (int d = 0; d < 4; ++d) O[i][d] = 0.f;
  }
  for (int j = 0; j <= qt; ++j) {
    __syncthreads();
#pragma unroll
    for (int p = 0; p < 4; ++p) {
      const int r = p * 16 + (tid >> 4);
      const int cq = tid & 15;
      const size_t rb = base + (size_t)(j * 64 + r) * (3 * CD);
      *(float4*)&Ks[r][((cq ^ (r >> 2)) << 2)] = *(const float4*)(qkv + rb + CD + (cq << 2));
      *(float4*)&Vs[r][((cq ^ (r >> 2)) << 2)] = *(const float4*)(qkv + rb + 2 * CD + (cq << 2));
    }
    __syncthreads();
    float S[4][4] = {};
#pragma unroll
    for (int kq = 0; kq < 16; ++kq) {
      float4 qv[4], kv[4];
#pragma unroll
      for (int i = 0; i < 4; ++i) qv[i] = *(const float4*)&Qs[ty * 4 + i][((kq ^ ty) << 2)];
#pragma unroll
      for (int jc = 0; jc < 4; ++jc) kv[jc] = *(const float4*)&Ks[tx * 4 + jc][((kq ^ tx) << 2)];
#pragma unroll
      for (int i = 0; i < 4; ++i)
#pragma unroll
        for (int jc = 0; jc < 4; ++jc)
          S[i][jc] += qv[i].x * kv[jc].x + qv[i].y * kv[jc].y +
                      qv[i].z * kv[jc].z + qv[i].w * kv[jc].w;
    }
#pragma unroll
    for (int i = 0; i < 4; ++i)
#pragma unroll
      for (int jc = 0; jc < 4; ++jc) {
        S[i][jc] *= 0.125f;
        if (j == qt && (tx * 4 + jc) > (ty * 4 + i)) S[i][jc] = -1e30f;
      }
#pragma unroll
    for (int i = 0; i < 4; ++i) {
      float rm = fmaxf(fmaxf(S[i][0], S[i][1]), fmaxf(S[i][2], S[i][3]));
#pragma unroll
      for (int o = 8; o > 0; o >>= 1) rm = fmaxf(rm, __shfl_xor(rm, o, 64));
      const float newm = fmaxf(m_i[i], rm);
      float p0 = expf(S[i][0] - newm), p1 = expf(S[i][1] - newm);
      float p2 = expf(S[i][2] - newm), p3 = expf(S[i][3] - newm);
      float rs = p0 + p1 + p2 + p3;
#pragma unroll
      for (int o = 8; o > 0; o >>= 1) rs += __shfl_xor(rs, o, 64);
      const float alpha = expf(m_i[i] - newm);
      l_i[i] = l_i[i] * alpha + rs;
      m_i[i] = newm;
#pragma unroll
      for (int d = 0; d < 4; ++d) O[i][d] *= alpha;
      const int r = ty * 4 + i;
      *(float4*)&Ps[r][((tx ^ ty) << 2)] = make_float4(p0, p1, p2, p3);
    }
    __syncthreads();
#pragma unroll
    for (int mq = 0; mq < 16; ++mq) {
      float4 pv[4], vv[4];
#pragma unroll
      for (int i = 0; i < 4; ++i) pv[i] = *(const float4*)&Ps[ty * 4 + i][((mq ^ ty) << 2)];
#pragma unroll
      for (int mm = 0; mm < 4; ++mm) vv[mm] = *(const float4*)&Vs[mq * 4 + mm][((tx ^ mq) << 2)];
#pragma unroll
      for (int i = 0; i < 4; ++i) {
        O[i][0] += pv[i].x * vv[0].x + pv[i].y * vv[1].x + pv[i].z * vv[2].x + pv[i].w * vv[3].x;
        O[i][1] += pv[i].x * vv[0].y + pv[i].y * vv[1].y + pv[i].z * vv[2].y + pv[i].w * vv[3].y;
        O[i][2] += pv[i].x * vv[0].z + pv[i].y * vv[1].z + pv[i].z * vv[2].z + pv[i].w * vv[3].z;
        O[i][3] += pv[i].x * vv[0].w + pv[i].y * vv[1].w + pv[i].z * vv[2].w + pv[i].w * vv[3].w;
      }
    }
  }
#pragma unroll
  for (int i = 0; i < 4; ++i) {
    const float inv = 1.f / l_i[i];
    float* op = out + ((size_t)b * CN + qt * 64 + ty * 4 + i) * CD + head * CHD + tx * 4;
    *(float4*)op = make_float4(O[i][0] * inv, O[i][1] * inv, O[i][2] * inv, O[i][3] * inv);
  }
}

__global__ __launch_bounds__(256) void final_ln(const float* __restrict__ local,
                                                const float* __restrict__ broad,
                                                const float* __restrict__ g, const float* __restrict__ bb,
                                                float* __restrict__ out)
{
  const int r = blockIdx.x, t = threadIdx.x;
  __shared__ float red[4];
  const size_t lb = (size_t)r * CD;
  const size_t br = (size_t)(r >> 2) * CD;
  const float v0 = local[lb + t] + broad[br + t];
  const float v1 = local[lb + 256 + t] + broad[br + 256 + t];
  const float mu = blk_sum(v0 + v1, red) * (1.f / CD);
  const float d0 = v0 - mu, d1 = v1 - mu;
  const float var = blk_sum(d0 * d0 + d1 * d1, red) * (1.f / CD);
  const float inv = rsqrtf(var + CEPS);
  out[lb + t] = d0 * inv * g[t] + bb[t];
  out[lb + 256 + t] = d1 * inv * g[t + 256] + bb[t + 256];
}

// ---------------- launcher ----------------
extern "C" void kernel_launch(void* const* d_in, const int* in_sizes, int n_in,
                              void* d_out, int out_size, void* d_ws, size_t ws_size,
                              hipStream_t stream)
{
  (void)in_sizes; (void)n_in; (void)out_size; (void)ws_size;
  const int*   x         = (const int*)d_in[0];
  const float* emb       = (const float*)d_in[1];
  const float* pos_emb   = (const float*)d_in[2];
  const float* gru_w_ih  = (const float*)d_in[3];
  const float* gru_w_hh  = (const float*)d_in[4];
  const float* gru_b_ih  = (const float*)d_in[5];
  const float* gru_b_hh  = (const float*)d_in[6];
  const float* patch_g   = (const float*)d_in[7];
  const float* patch_b   = (const float*)d_in[8];
  const float* summ_w    = (const float*)d_in[9];
  const float* summ_b    = (const float*)d_in[10];
  const float* msg_w1    = (const float*)d_in[11];
  const float* msg_b1    = (const float*)d_in[12];
  const float* msg_w2    = (const float*)d_in[13];
  const float* msg_b2    = (const float*)d_in[14];
  const float* msg_ln_g  = (const float*)d_in[15];
  const float* msg_ln_b  = (const float*)d_in[16];
  const float* q_w       = (const float*)d_in[17];
  const float* q_b       = (const float*)d_in[18];
  const float* k_w       = (const float*)d_in[19];
  const float* k_b       = (const float*)d_in[20];
  const float* v_w       = (const float*)d_in[21];
  const float* v_b       = (const float*)d_in[22];
  const float* o_w       = (const float*)d_in[23];
  const float* o_b       = (const float*)d_in[24];
  const float* gc_w_ih   = (const float*)d_in[25];
  const float* gc_w_hh   = (const float*)d_in[26];
  const float* gc_b_ih   = (const float*)d_in[27];
  const float* gc_b_hh   = (const float*)d_in[28];
  const float* ar_ln_g   = (const float*)d_in[29];
  const float* ar_ln_b   = (const float*)d_in[30];
  const float* ar_qkv_w  = (const float*)d_in[31];
  const float* ar_qkv_b  = (const float*)d_in[32];
  const float* ar_out_w  = (const float*)d_in[33];
  const float* ar_out_b  = (const float*)d_in[34];
  const float* broad_w   = (const float*)d_in[35];
  const float* broad_b   = (const float*)d_in[36];
  const float* ln_g      = (const float*)d_in[37];
  const float* ln_b      = (const float*)d_in[38];
  const float* head_w    = (const float*)d_in[39];
  float* out = (float*)d_out;

  float* ws = (float*)d_ws;
  float* Wl    = ws + OFF_LOCAL;
  float* Wh    = ws + OFF_H;
  float* Wgi   = ws + OFF_GI;
  float* Wghn  = ws + OFF_GHN;
  float* Wq    = ws + OFF_Q;
  float* Wk    = ws + OFF_K;
  float* Wv    = ws + OFF_V;
  float* Wmsgs = ws + OFF_MSGS;
  float* Wprob = ws + OFF_PROB;
  int*   Widx  = (int*)(ws + OFF_IDX);
  float* WT    = ws + OFF_WT;
  float* Wscores = Wgi;
  float* Wfinal  = Wgi;   // spans GI+GHN = exactly TROWS*CD floats

  const int EW = ROWS * CD / 256;
  const float inv_sqrt_d = 0.04419417382415922f;

  // ---- transpose all weights once (out[n][k] = in[k][n]) ----
  auto TR = [&](const float* in, size_t off, int K, int N) {
    transpose_k<<<dim3(N / 32, K / 32), 256, 0, stream>>>(in, WT + off, K, N);
  };
  TR(gru_w_ih, T_GRU_IH, 512, 1536);
  TR(gru_w_hh, T_GRU_HH, 512, 1536);
  TR(summ_w,   T_SUMM,   512, 512);
  TR(msg_w1,                      T_MSG1A, 512, 512);
  TR(msg_w1 + (size_t)512 * 512,  T_MSG1B, 512, 512);
  TR(msg_w2,   T_MSG2,   512, 512);
  TR(q_w, T_QW, 512, 512);
  TR(k_w, T_KW, 512, 512);
  TR(v_w, T_VW, 512, 512);
  TR(o_w, T_OW, 512, 512);
  TR(gc_w_ih,                       T_GC_TOP, 512, 1536);
  TR(gc_w_ih + (size_t)512 * 1536,  T_GC_BOT, 512, 1536);
  TR(gc_w_hh,  T_GC_HH,  512, 1536);
  TR(ar_qkv_w, T_AR_QKV, 512, 1536);
  TR(ar_out_w, T_AR_OUT, 512, 512);
  TR(broad_w,  T_BROAD,  512, 512);
  TR(head_w,   T_HEAD,   512, 256);

  // GEMM: C[M,N] (+)= A[M,512] @ WT[off]^T + bias
  auto GEMM = [&](const float* A, size_t toff, const float* bias, float* Cc,
                  int M, int N, int ldc, int accum) {
    gemm_mfma<<<dim3(N / 128, M / 128), 256, 0, stream>>>(
        A, WT + toff, bias, Cc, 512, 512, ldc, 512, accum, 1.f, 0, 0, 0);
  };

  // ---- patch GRU over P=4 steps ----
  zero_k<<<EW, 256, 0, stream>>>(Wh);
  for (int t = 0; t < CP; ++t) {
    embed_step<<<EW, 256, 0, stream>>>(x, emb, pos_emb, Wq, t);
    GEMM(Wq, T_GRU_IH, gru_b_ih, Wgi, ROWS, 1536, 1536, 0);
    // hh r,z columns accumulate into GI[:,0:1024]; n column -> GHN
    GEMM(Wh, T_GRU_HH, gru_b_hh, Wgi, ROWS, 1024, 1536, 1);
    gemm_mfma<<<dim3(4, 64), 256, 0, stream>>>(
        Wh, WT + T_GRU_HH + (size_t)1024 * 512, gru_b_hh + 1024, Wghn,
        512, 512, 512, 512, 0, 1.f, 0, 0, 0);
    gru_point<<<EW, 256, 0, stream>>>(Wgi, Wghn, Wh, Wl, t);
  }
  ln_rows<<<TROWS, 256, 0, stream>>>(Wl, Wl, patch_g, patch_b);
  mean_pool<<<EW, 256, 0, stream>>>(Wl, Wk);
  GEMM(Wk, T_SUMM, summ_b, Wh, ROWS, 512, 512, 0);

  // ---- rounds ----
  for (int rnd = 0; rnd < 6; ++rnd) {
    GEMM(Wh, T_MSG1A, msg_b1, Wq, ROWS, 512, 512, 0);
    GEMM(Wh, T_MSG1B, nullptr, Wk, ROWS, 512, 512, 0);
    msg_gelu<<<EW, 256, 0, stream>>>(Wq, Wk, Wv);
    GEMM(Wv, T_MSG2, msg_b2, Wmsgs, ROWS, 512, 512, 0);
    GEMM(Wh, T_QW, q_b, Wq, ROWS, 512, 512, 0);
    rotary_k<<<ROWS, 256, 0, stream>>>(Wq);
    GEMM(Wh, T_KW, k_b, Wk, ROWS, 512, 512, 0);
    rotary_k<<<ROWS, 256, 0, stream>>>(Wk);
    GEMM(Wh, T_VW, v_b, Wv, ROWS, 512, 512, 0);
    // scores = q @ k^T / sqrt(D)  (batched, split-bf16 => fp32-grade)
    gemm_mfma<<<dim3(8, 8, CB), 256, 0, stream>>>(
        Wq, Wk, nullptr, Wscores, 512, 512, CN, 512, 0, inv_sqrt_d,
        (long long)CN * CD, (long long)CN * CD, (long long)CN * CN);
    topk_softmax2<<<ROWS, 256, 0, stream>>>(Wscores, Wprob, Widx);
    topk_gather<<<ROWS, 128, 0, stream>>>(Wprob, Widx, Wv, Wq);
    GEMM(Wq, T_OW, o_b, Wk, ROWS, 512, 512, 0);
    GEMM(Wmsgs, T_GC_TOP, gc_b_ih, Wgi, ROWS, 1536, 1536, 0);
    GEMM(Wk,    T_GC_BOT, nullptr, Wgi, ROWS, 1536, 1536, 1);
    GEMM(Wh, T_GC_HH, gc_b_hh, Wgi, ROWS, 1024, 1536, 1);
    gemm_mfma<<<dim3(4, 64), 256, 0, stream>>>(
        Wh, WT + T_GC_HH + (size_t)1024 * 512, gc_b_hh + 1024, Wghn,
        512, 512, 512, 512, 0, 1.f, 0, 0, 0);
    gru_ln<<<ROWS, 256, 0, stream>>>(Wgi, Wghn, Wh, msg_ln_g, msg_ln_b);
    if ((rnd & 1) == 1) {
      ln_rows<<<ROWS, 256, 0, stream>>>(Wh, Wq, ar_ln_g, ar_ln_b);
      GEMM(Wq, T_AR_QKV, ar_qkv_b, Wgi, ROWS, 1536, 1536, 0);
      flash_attn<<<dim3(16, CH, CB), 256, 0, stream>>>(Wgi, Wk);
      GEMM(Wk, T_AR_OUT, ar_out_b, Wh, ROWS, 512, 512, 1);
    }
  }

  // ---- head ----
  GEMM(Wh, T_BROAD, broad_b, Wq, ROWS, 512, 512, 0);
  final_ln<<<TROWS, 256, 0, stream>>>(Wl, Wq, ln_g, ln_b, Wfinal);
  GEMM(Wfinal, T_HEAD, nullptr, out, TROWS, CV, CV, 0);
}

// Round 4
// 5951.405 us; speedup vs baseline: 3.4845x; 1.1759x over previous
//
#include <hip/hip_runtime.h>
#include <math.h>

// ---------------- problem constants ----------------
constexpr int CB = 8, CT = 4096, CP = 4, CD = 512, CV = 256;
constexpr int CN = 1024, CK = 16, CH = 8, CHD = 64;
constexpr int ROWS = CB * CN;     // 8192
constexpr int TROWS = CB * CT;    // 32768
constexpr float CEPS = 1e-5f;

// ---------------- workspace layout (floats) ----------------
constexpr size_t OFF_LOCAL = 0;                                    // 16,777,216
constexpr size_t OFF_H     = OFF_LOCAL + (size_t)ROWS * CP * CD;   //  4,194,304
constexpr size_t OFF_GI    = OFF_H     + (size_t)ROWS * CD;        // 12,582,912
constexpr size_t OFF_GHN   = OFF_GI    + (size_t)ROWS * 3 * CD;    //  4,194,304
constexpr size_t OFF_Q     = OFF_GHN   + (size_t)ROWS * CD;        //  4,194,304
constexpr size_t OFF_K     = OFF_Q     + (size_t)ROWS * CD;        //  4,194,304
constexpr size_t OFF_V     = OFF_K     + (size_t)ROWS * CD;        //  4,194,304
constexpr size_t OFF_MSGS  = OFF_V     + (size_t)ROWS * CD;        //  4,194,304
constexpr size_t OFF_PROB  = OFF_MSGS  + (size_t)ROWS * CD;        //    131,072
constexpr size_t OFF_IDX   = OFF_PROB  + (size_t)ROWS * CK;        //    131,072
constexpr size_t OFF_WT    = OFF_IDX   + (size_t)ROWS * CK;        //  7,471,104 floats
// WT region holds TWO ushort arrays (hi, lo) of 7,471,104 elements each =
// exactly 7,471,104 floats of bytes. total 237.5 MiB.

constexpr size_t TOT_W    = 7471104;   // total weight elements
// transposed-weight sub-offsets (elements)
constexpr size_t T_GRU_IH = 0;                    // 1536x512
constexpr size_t T_GRU_HH = T_GRU_IH + 786432;    // 1536x512
constexpr size_t T_SUMM   = T_GRU_HH + 786432;    // 512x512
constexpr size_t T_MSG1A  = T_SUMM   + 262144;
constexpr size_t T_MSG1B  = T_MSG1A  + 262144;
constexpr size_t T_MSG2   = T_MSG1B  + 262144;
constexpr size_t T_QW     = T_MSG2   + 262144;
constexpr size_t T_KW     = T_QW     + 262144;
constexpr size_t T_VW     = T_KW     + 262144;
constexpr size_t T_OW     = T_VW     + 262144;
constexpr size_t T_GC_TOP = T_OW     + 262144;    // 1536x512
constexpr size_t T_GC_BOT = T_GC_TOP + 786432;    // 1536x512
constexpr size_t T_GC_HH  = T_GC_BOT + 786432;    // 1536x512
constexpr size_t T_AR_QKV = T_GC_HH  + 786432;    // 1536x512
constexpr size_t T_AR_OUT = T_AR_QKV + 786432;    // 512x512
constexpr size_t T_BROAD  = T_AR_OUT + 262144;
constexpr size_t T_HEAD   = T_BROAD  + 262144;    // 256x512

// ---------------- device helpers ----------------
typedef __attribute__((ext_vector_type(8))) short short8;
typedef __attribute__((ext_vector_type(4))) float f32x4;

__device__ __forceinline__ float sigm(float x) { return 1.f / (1.f + expf(-x)); }
__device__ __forceinline__ float geluf(float x) {
  return 0.5f * x * (1.f + erff(x * 0.7071067811865475f));
}
__device__ __forceinline__ unsigned short bf_hi(float x) {
  const unsigned u = __float_as_uint(x);
  return (unsigned short)((u + 0x7FFFu + ((u >> 16) & 1u)) >> 16);
}
__device__ __forceinline__ float bf_f(unsigned short h) {
  return __uint_as_float((unsigned)h << 16);
}
__device__ __forceinline__ float blk_sum(float v, float* red) {
#pragma unroll
  for (int o = 32; o > 0; o >>= 1) v += __shfl_down(v, o, 64);
  const int wv = threadIdx.x >> 6, ln = threadIdx.x & 63;
  __syncthreads();
  if (ln == 0) red[wv] = v;
  __syncthreads();
  return red[0] + red[1] + red[2] + red[3];
}

// ---------------- transpose + bf16 split: oh/ol[n][k] = split(in[k][n]) ----
__global__ __launch_bounds__(256) void transpose_split(const float* __restrict__ in,
                                                       unsigned short* __restrict__ oh,
                                                       unsigned short* __restrict__ ol,
                                                       int K, int N)
{
  __shared__ float tile[32][33];
  const int n0 = blockIdx.x * 32, k0 = blockIdx.y * 32;
  const int tx = threadIdx.x & 31, ty = threadIdx.x >> 5;   // 32 x 8
#pragma unroll
  for (int i = 0; i < 32; i += 8)
    tile[ty + i][tx] = in[(size_t)(k0 + ty + i) * N + n0 + tx];
  __syncthreads();
#pragma unroll
  for (int i = 0; i < 32; i += 8) {
    const float v = tile[tx][ty + i];
    const unsigned short h = bf_hi(v);
    oh[(size_t)(n0 + ty + i) * K + k0 + tx] = h;
    ol[(size_t)(n0 + ty + i) * K + k0 + tx] = bf_hi(v - bf_f(h));
  }
}

// ---------------- split-bf16 MFMA GEMM (both operands fp32) — scores only ----
__global__ __launch_bounds__(256, 2) void gemm_mfma(
    const float* __restrict__ A, const float* __restrict__ Bt,
    const float* __restrict__ bias, float* __restrict__ C,
    int lda, int ldb, int ldc, int K, int accum, float scale,
    long long sA, long long sB, long long sC)
{
  A  += (size_t)blockIdx.z * sA;
  Bt += (size_t)blockIdx.z * sB;
  C  += (size_t)blockIdx.z * sC;
  __shared__ __align__(16) unsigned short AsH[128][40];
  __shared__ __align__(16) unsigned short AsL[128][40];
  __shared__ __align__(16) unsigned short BsH[128][40];
  __shared__ __align__(16) unsigned short BsL[128][40];
  const int tid = threadIdx.x;
  const int bm = blockIdx.y << 7, bn = blockIdx.x << 7;
  const int lane = tid & 63, wave = tid >> 6;
  const int wm = (wave & 1) << 6, wn = (wave >> 1) << 6;
  const int r16 = lane & 15, quad = lane >> 4;
  const int sr = tid >> 1, sc = (tid & 1) << 4;
  const f32x4 zero = {0.f, 0.f, 0.f, 0.f};
  f32x4 acc[4][4];
#pragma unroll
  for (int i = 0; i < 4; ++i)
#pragma unroll
    for (int j = 0; j < 4; ++j) acc[i][j] = zero;

  for (int k0 = 0; k0 < K; k0 += 32) {
    const float* Ap = A + (size_t)(bm + sr) * lda + k0 + sc;
    const float* Bp = Bt + (size_t)(bn + sr) * ldb + k0 + sc;
#pragma unroll
    for (int q = 0; q < 4; ++q) {
      const float4 av = *(const float4*)(Ap + q * 4);
      ushort4 h, l;
      h.x = bf_hi(av.x); h.y = bf_hi(av.y); h.z = bf_hi(av.z); h.w = bf_hi(av.w);
      l.x = bf_hi(av.x - bf_f(h.x)); l.y = bf_hi(av.y - bf_f(h.y));
      l.z = bf_hi(av.z - bf_f(h.z)); l.w = bf_hi(av.w - bf_f(h.w));
      *(ushort4*)&AsH[sr][sc + q * 4] = h;
      *(ushort4*)&AsL[sr][sc + q * 4] = l;
      const float4 bv = *(const float4*)(Bp + q * 4);
      ushort4 bh4, bl4;
      bh4.x = bf_hi(bv.x); bh4.y = bf_hi(bv.y); bh4.z = bf_hi(bv.z); bh4.w = bf_hi(bv.w);
      bl4.x = bf_hi(bv.x - bf_f(bh4.x)); bl4.y = bf_hi(bv.y - bf_f(bh4.y));
      bl4.z = bf_hi(bv.z - bf_f(bh4.z)); bl4.w = bf_hi(bv.w - bf_f(bh4.w));
      *(ushort4*)&BsH[sr][sc + q * 4] = bh4;
      *(ushort4*)&BsL[sr][sc + q * 4] = bl4;
    }
    __syncthreads();
    short8 bh[4], bl[4];
#pragma unroll
    for (int ni = 0; ni < 4; ++ni) {
      bh[ni] = *(const short8*)&BsH[wn + ni * 16 + r16][quad * 8];
      bl[ni] = *(const short8*)&BsL[wn + ni * 16 + r16][quad * 8];
    }
#pragma unroll
    for (int mi = 0; mi < 4; ++mi) {
      const short8 ah = *(const short8*)&AsH[wm + mi * 16 + r16][quad * 8];
      const short8 al = *(const short8*)&AsL[wm + mi * 16 + r16][quad * 8];
#pragma unroll
      for (int ni = 0; ni < 4; ++ni) {
        acc[mi][ni] = __builtin_amdgcn_mfma_f32_16x16x32_bf16(ah, bh[ni], acc[mi][ni], 0, 0, 0);
        acc[mi][ni] = __builtin_amdgcn_mfma_f32_16x16x32_bf16(ah, bl[ni], acc[mi][ni], 0, 0, 0);
        acc[mi][ni] = __builtin_amdgcn_mfma_f32_16x16x32_bf16(al, bh[ni], acc[mi][ni], 0, 0, 0);
      }
    }
    __syncthreads();
  }
#pragma unroll
  for (int mi = 0; mi < 4; ++mi) {
    const int row0 = bm + wm + mi * 16 + quad * 4;
#pragma unroll
    for (int ni = 0; ni < 4; ++ni) {
      const int col = bn + wn + ni * 16 + r16;
      const float bv = bias ? bias[col] : 0.f;
#pragma unroll
      for (int rg = 0; rg < 4; ++rg) {
        float* Cp = C + (size_t)(row0 + rg) * ldc + col;
        float o = acc[mi][ni][rg] * scale + bv;
        if (accum) o += *Cp;
        *Cp = o;
      }
    }
  }
}

// ---------------- MFMA GEMM with pre-split bf16 weights ----------------
// C[M,N] (+)= A[M,K] @ Bt^T + bias, Bt given as hi/lo ushort [N][K].
__global__ __launch_bounds__(256, 2) void gemm_mfma_w(
    const float* __restrict__ A, const unsigned short* __restrict__ BtH,
    const unsigned short* __restrict__ BtL,
    const float* __restrict__ bias, float* __restrict__ C,
    int lda, int ldb, int ldc, int K, int accum)
{
  __shared__ __align__(16) unsigned short AsH[128][40];
  __shared__ __align__(16) unsigned short AsL[128][40];
  __shared__ __align__(16) unsigned short BsH[128][40];
  __shared__ __align__(16) unsigned short BsL[128][40];
  const int tid = threadIdx.x;
  const int bm = blockIdx.y << 7, bn = blockIdx.x << 7;
  const int lane = tid & 63, wave = tid >> 6;
  const int wm = (wave & 1) << 6, wn = (wave >> 1) << 6;
  const int r16 = lane & 15, quad = lane >> 4;
  const int sr = tid >> 1, sc = (tid & 1) << 4;
  const f32x4 zero = {0.f, 0.f, 0.f, 0.f};
  f32x4 acc[4][4];
#pragma unroll
  for (int i = 0; i < 4; ++i)
#pragma unroll
    for (int j = 0; j < 4; ++j) acc[i][j] = zero;

  for (int k0 = 0; k0 < K; k0 += 32) {
    const float* Ap = A + (size_t)(bm + sr) * lda + k0 + sc;
#pragma unroll
    for (int q = 0; q < 4; ++q) {
      const float4 av = *(const float4*)(Ap + q * 4);
      ushort4 h, l;
      h.x = bf_hi(av.x); h.y = bf_hi(av.y); h.z = bf_hi(av.z); h.w = bf_hi(av.w);
      l.x = bf_hi(av.x - bf_f(h.x)); l.y = bf_hi(av.y - bf_f(h.y));
      l.z = bf_hi(av.z - bf_f(h.z)); l.w = bf_hi(av.w - bf_f(h.w));
      *(ushort4*)&AsH[sr][sc + q * 4] = h;
      *(ushort4*)&AsL[sr][sc + q * 4] = l;
    }
    const unsigned short* BpH = BtH + (size_t)(bn + sr) * ldb + k0 + sc;
    const unsigned short* BpL = BtL + (size_t)(bn + sr) * ldb + k0 + sc;
    *(uint4*)&BsH[sr][sc]     = *(const uint4*)BpH;
    *(uint4*)&BsH[sr][sc + 8] = *(const uint4*)(BpH + 8);
    *(uint4*)&BsL[sr][sc]     = *(const uint4*)BpL;
    *(uint4*)&BsL[sr][sc + 8] = *(const uint4*)(BpL + 8);
    __syncthreads();
    short8 bh[4], bl[4];
#pragma unroll
    for (int ni = 0; ni < 4; ++ni) {
      bh[ni] = *(const short8*)&BsH[wn + ni * 16 + r16][quad * 8];
      bl[ni] = *(const short8*)&BsL[wn + ni * 16 + r16][quad * 8];
    }
#pragma unroll
    for (int mi = 0; mi < 4; ++mi) {
      const short8 ah = *(const short8*)&AsH[wm + mi * 16 + r16][quad * 8];
      const short8 al = *(const short8*)&AsL[wm + mi * 16 + r16][quad * 8];
#pragma unroll
      for (int ni = 0; ni < 4; ++ni) {
        acc[mi][ni] = __builtin_amdgcn_mfma_f32_16x16x32_bf16(ah, bh[ni], acc[mi][ni], 0, 0, 0);
        acc[mi][ni] = __builtin_amdgcn_mfma_f32_16x16x32_bf16(ah, bl[ni], acc[mi][ni], 0, 0, 0);
        acc[mi][ni] = __builtin_amdgcn_mfma_f32_16x16x32_bf16(al, bh[ni], acc[mi][ni], 0, 0, 0);
      }
    }
    __syncthreads();
  }
#pragma unroll
  for (int mi = 0; mi < 4; ++mi) {
    const int row0 = bm + wm + mi * 16 + quad * 4;
#pragma unroll
    for (int ni = 0; ni < 4; ++ni) {
      const int col = bn + wn + ni * 16 + r16;
      const float bv = bias ? bias[col] : 0.f;
#pragma unroll
      for (int rg = 0; rg < 4; ++rg) {
        float* Cp = C + (size_t)(row0 + rg) * ldc + col;
        float o = acc[mi][ni][rg] + bv;
        if (accum) o += *Cp;
        *Cp = o;
      }
    }
  }
}

// ---------------- small kernels ----------------
__global__ void zero_k(float* __restrict__ p) {
  p[(size_t)blockIdx.x * 256 + threadIdx.x] = 0.f;
}

__global__ void embed_step(const int* __restrict__ x, const float* __restrict__ emb,
                           const float* __restrict__ pos, float* __restrict__ Xt, int t)
{
  const int i = blockIdx.x * 256 + threadIdx.x;
  const int r = i >> 9, d = i & 511;
  const int b = r >> 10, n = r & (CN - 1);
  const int tok = x[b * CT + n * CP + t];
  Xt[i] = emb[(size_t)tok * CD + d] + pos[t * CD + d];
}

__global__ void gru_point(const float* __restrict__ gi, const float* __restrict__ ghn,
                          float* __restrict__ h, float* __restrict__ hs, int t)
{
  const int i = blockIdx.x * 256 + threadIdx.x;
  const int r = i >> 9, d = i & 511;
  const size_t gb = (size_t)r * (3 * CD) + d;
  const float sr_ = gi[gb], sz = gi[gb + CD], inn = gi[gb + 2 * CD];
  const float hn = ghn[i];
  const float hp = h[i];
  const float rr = sigm(sr_), zz = sigm(sz);
  const float nn = tanhf(inn + rr * hn);
  const float hv = (1.f - zz) * nn + zz * hp;
  h[i] = hv;
  hs[(size_t)r * (CP * CD) + (size_t)t * CD + d] = hv;
}

__global__ __launch_bounds__(256) void ln_rows(const float* __restrict__ in, float* __restrict__ out,
                                               const float* __restrict__ g, const float* __restrict__ b)
{
  const int r = blockIdx.x, t = threadIdx.x;
  __shared__ float red[4];
  const float* ip = in + (size_t)r * CD;
  const float v0 = ip[t], v1 = ip[t + 256];
  const float mu = blk_sum(v0 + v1, red) * (1.f / CD);
  const float d0 = v0 - mu, d1 = v1 - mu;
  const float var = blk_sum(d0 * d0 + d1 * d1, red) * (1.f / CD);
  const float inv = rsqrtf(var + CEPS);
  float* op = out + (size_t)r * CD;
  op[t] = d0 * inv * g[t] + b[t];
  op[t + 256] = d1 * inv * g[t + 256] + b[t + 256];
}

__global__ void mean_pool(const float* __restrict__ local, float* __restrict__ hm)
{
  const int i = blockIdx.x * 256 + threadIdx.x;
  const int r = i >> 9, d = i & 511;
  const float* p = local + (size_t)r * (CP * CD) + d;
  hm[i] = 0.25f * (p[0] + p[CD] + p[2 * CD] + p[3 * CD]);
}

__global__ void msg_gelu(const float* __restrict__ pre, const float* __restrict__ nb,
                         float* __restrict__ G)
{
  const int i = blockIdx.x * 256 + threadIdx.x;
  const int r = i >> 9;
  const int n = r & (CN - 1);
  const float pv = pre[i];
  float acc = 0.f;
#pragma unroll
  for (int w = 0; w <= 4; ++w) {
    const float xv = pv + ((n >= w) ? nb[(size_t)i - (size_t)w * CD] : 0.f);
    acc += geluf(xv);
  }
  G[i] = acc * 0.2f;
}

__global__ void rotary_k(float* __restrict__ t)
{
  const int i = blockIdx.x * 256 + threadIdx.x;
  const int r = i >> 8, j = i & 255;
  const int n = r & (CN - 1);
  const float fr = (float)n * expf(-9.210340371976184f * ((float)j * (1.f / 256.f)));
  float s, c;
  sincosf(fr, &s, &c);
  float* p = t + (size_t)r * CD;
  const float t1 = p[j], t2 = p[j + 256];
  p[j] = t1 * c - t2 * s;
  p[j + 256] = t2 * c + t1 * s;
}

// ---------------- parallel top-K: one block per row ----------------
__global__ __launch_bounds__(256) void topk_softmax2(const float* __restrict__ scores,
                                                     float* __restrict__ probs, int* __restrict__ idxs)
{
  const int rrow = blockIdx.x;
  const int b = rrow >> 10, n = rrow & (CN - 1);
  const float* row = scores + ((size_t)b * CN + n) * CN;
  __shared__ float sv[CN];
  __shared__ unsigned long long wred[4];
  __shared__ float topv[CK];
  __shared__ int topi[CK];
  const int tid = threadIdx.x;
#pragma unroll
  for (int q = 0; q < 4; ++q) {
    const int m = tid + q * 256;
    sv[m] = (m <= n) ? row[m] : -INFINITY;
  }
  __syncthreads();
  for (int it = 0; it < CK; ++it) {
    unsigned long long best = 0ull;
#pragma unroll
    for (int q = 0; q < 4; ++q) {
      const int m = tid + q * 256;
      unsigned u = __float_as_uint(sv[m]);
      u = (u & 0x80000000u) ? ~u : (u | 0x80000000u);
      const unsigned long long key = ((unsigned long long)u << 32) | (unsigned)(CN - 1 - m);
      best = best > key ? best : key;
    }
#pragma unroll
    for (int o = 32; o > 0; o >>= 1) {
      const unsigned long long o2 = __shfl_down(best, o, 64);
      best = best > o2 ? best : o2;
    }
    if ((tid & 63) == 0) wred[tid >> 6] = best;
    __syncthreads();
    if (tid == 0) {
      unsigned long long b0 = wred[0];
      for (int w = 1; w < 4; ++w) b0 = b0 > wred[w] ? b0 : wred[w];
      const int m = CN - 1 - (int)(b0 & 0xFFFFFFFFu);
      unsigned u = (unsigned)(b0 >> 32);
      u = (u & 0x80000000u) ? (u & 0x7FFFFFFFu) : ~u;
      topv[it] = __uint_as_float(u);
      topi[it] = m;
      sv[m] = -INFINITY;
    }
    __syncthreads();
  }
  if (tid < CK) {
    const float mx = topv[0];
    float sum = 0.f;
#pragma unroll
    for (int q = 0; q < CK; ++q)
      sum += (topv[q] == -INFINITY) ? 0.f : expf(topv[q] - mx);
    const float e = (topv[tid] == -INFINITY) ? 0.f : expf(topv[tid] - mx);
    probs[(size_t)rrow * CK + tid] = e / sum;
    idxs[(size_t)rrow * CK + tid] = topi[tid];
  }
}

__global__ __launch_bounds__(128) void topk_gather(const float* __restrict__ probs,
                                                   const int* __restrict__ idxs,
                                                   const float* __restrict__ v,
                                                   float* __restrict__ ctx)
{
  const int r = blockIdx.x;
  const int b = r >> 10;
  __shared__ float p[CK];
  __shared__ int id[CK];
  if (threadIdx.x < CK) {
    p[threadIdx.x] = probs[(size_t)r * CK + threadIdx.x];
    id[threadIdx.x] = idxs[(size_t)r * CK + threadIdx.x];
  }
  __syncthreads();
  for (int d = threadIdx.x; d < CD; d += 128) {
    float a = 0.f;
#pragma unroll
    for (int q = 0; q < CK; ++q)
      a += p[q] * v[((size_t)(b << 10) + id[q]) * CD + d];
    ctx[(size_t)r * CD + d] = a;
  }
}

__global__ __launch_bounds__(256) void gru_ln(const float* __restrict__ gi, const float* __restrict__ ghn,
                                              float* __restrict__ h, const float* __restrict__ g,
                                              const float* __restrict__ b)
{
  const int r = blockIdx.x, t = threadIdx.x;
  __shared__ float red[4];
  float u[2];
#pragma unroll
  for (int q = 0; q < 2; ++q) {
    const int d = t + q * 256;
    const size_t gb = (size_t)r * (3 * CD) + d;
    const float sr_ = gi[gb], sz = gi[gb + CD], inn = gi[gb + 2 * CD];
    const float hn = ghn[(size_t)r * CD + d];
    const float hp = h[(size_t)r * CD + d];
    const float rr = sigm(sr_), zz = sigm(sz);
    const float nn = tanhf(inn + rr * hn);
    u[q] = (1.f - zz) * nn + zz * hp;
  }
  const float mu = blk_sum(u[0] + u[1], red) * (1.f / CD);
  const float d0 = u[0] - mu, d1 = u[1] - mu;
  const float var = blk_sum(d0 * d0 + d1 * d1, red) * (1.f / CD);
  const float inv = rsqrtf(var + CEPS);
  h[(size_t)r * CD + t] = d0 * inv * g[t] + b[t];
  h[(size_t)r * CD + t + 256] = d1 * inv * g[t + 256] + b[t + 256];
}

// ---------------- MFMA flash attention (hd=64, causal) ----------------
// grid (N/64, H, B), 256 thr (4 waves; wave w owns Q rows [16w,16w+16)).
// QK^T split-bf16 (3 MFMA); PV = Ph*(Vh+Vl) (P-lo term negligible: P in [0,1]).
constexpr int FP = 72;   // LDS pitch in ushorts (144 B, 16B-aligned rows)
__global__ __launch_bounds__(256, 2) void flash_attn_mfma(const float* __restrict__ qkv,
                                                          float* __restrict__ out)
{
  __shared__ __align__(16) unsigned short Qh[64 * FP], Ql[64 * FP];
  __shared__ __align__(16) unsigned short Kh[64 * FP], Kl[64 * FP];
  __shared__ __align__(16) unsigned short Vth[64 * FP], Vtl[64 * FP];
  __shared__ __align__(16) unsigned short Pm[64 * FP];
  const int qt = blockIdx.x, head = blockIdx.y, b = blockIdx.z;
  const int tid = threadIdx.x;
  const int lane = tid & 63, wave = tid >> 6;
  const int r16 = lane & 15, quad = lane >> 4;
  const size_t base = (size_t)b * CN * (3 * CD) + head * CHD;

  // stage Q tile (hi/lo), contiguous layout [row][d]
  {
    const int r = tid >> 2, c0 = (tid & 3) << 4;
    const float* qp = qkv + base + (size_t)(qt * 64 + r) * (3 * CD) + c0;
#pragma unroll
    for (int q = 0; q < 4; ++q) {
      const float4 v = *(const float4*)(qp + q * 4);
      ushort4 h, l;
      h.x = bf_hi(v.x); h.y = bf_hi(v.y); h.z = bf_hi(v.z); h.w = bf_hi(v.w);
      l.x = bf_hi(v.x - bf_f(h.x)); l.y = bf_hi(v.y - bf_f(h.y));
      l.z = bf_hi(v.z - bf_f(h.z)); l.w = bf_hi(v.w - bf_f(h.w));
      *(ushort4*)&Qh[r * FP + c0 + q * 4] = h;
      *(ushort4*)&Ql[r * FP + c0 + q * 4] = l;
    }
  }
  float m_i[4], l_i[4];
  f32x4 O[4];   // [dt]: rows quad*4+reg of wave strip, col dt*16+r16
  const f32x4 zero = {0.f, 0.f, 0.f, 0.f};
#pragma unroll
  for (int r = 0; r < 4; ++r) { m_i[r] = -INFINITY; l_i[r] = 0.f; }
#pragma unroll
  for (int d = 0; d < 4; ++d) O[d] = zero;

  for (int j = 0; j <= qt; ++j) {
    __syncthreads();
    // stage K (contiguous) and V (transposed: Vt[d][key], pair-packed writes)
    {
      const int r = tid >> 2, c0 = (tid & 3) << 4;
      const float* kp = qkv + base + (size_t)(j * 64 + r) * (3 * CD) + CD + c0;
#pragma unroll
      for (int q = 0; q < 4; ++q) {
        const float4 v = *(const float4*)(kp + q * 4);
        ushort4 h, l;
        h.x = bf_hi(v.x); h.y = bf_hi(v.y); h.z = bf_hi(v.z); h.w = bf_hi(v.w);
        l.x = bf_hi(v.x - bf_f(h.x)); l.y = bf_hi(v.y - bf_f(h.y));
        l.z = bf_hi(v.z - bf_f(h.z)); l.w = bf_hi(v.w - bf_f(h.w));
        *(ushort4*)&Kh[r * FP + c0 + q * 4] = h;
        *(ushort4*)&Kl[r * FP + c0 + q * 4] = l;
      }
      const int rp = (tid >> 3) << 1, c0v = (tid & 7) << 3;   // rows rp,rp+1; 8 cols
      const float* vp0 = qkv + base + (size_t)(j * 64 + rp) * (3 * CD) + 2 * CD + c0v;
      const float* vp1 = vp0 + 3 * CD;
      float x[8], y[8];
      *(float4*)&x[0] = *(const float4*)vp0; *(float4*)&x[4] = *(const float4*)(vp0 + 4);
      *(float4*)&y[0] = *(const float4*)vp1; *(float4*)&y[4] = *(const float4*)(vp1 + 4);
#pragma unroll
      for (int c = 0; c < 8; ++c) {
        const unsigned short hx = bf_hi(x[c]), hy = bf_hi(y[c]);
        *(unsigned*)&Vth[(c0v + c) * FP + rp] = (unsigned)hx | ((unsigned)hy << 16);
        const unsigned short lx = bf_hi(x[c] - bf_f(hx)), ly = bf_hi(y[c] - bf_f(hy));
        *(unsigned*)&Vtl[(c0v + c) * FP + rp] = (unsigned)lx | ((unsigned)ly << 16);
      }
    }
    __syncthreads();
    // S = Q K^T for this wave's 16 rows (4 col-tiles of 16)
    f32x4 S[4];
#pragma unroll
    for (int nt = 0; nt < 4; ++nt) S[nt] = zero;
#pragma unroll
    for (int kh = 0; kh < 2; ++kh) {
      const short8 qh = *(const short8*)&Qh[(wave * 16 + r16) * FP + kh * 32 + quad * 8];
      const short8 ql = *(const short8*)&Ql[(wave * 16 + r16) * FP + kh * 32 + quad * 8];
#pragma unroll
      for (int nt = 0; nt < 4; ++nt) {
        const short8 kkh = *(const short8*)&Kh[(nt * 16 + r16) * FP + kh * 32 + quad * 8];
        const short8 kkl = *(const short8*)&Kl[(nt * 16 + r16) * FP + kh * 32 + quad * 8];
        S[nt] = __builtin_amdgcn_mfma_f32_16x16x32_bf16(qh, kkh, S[nt], 0, 0, 0);
        S[nt] = __builtin_amdgcn_mfma_f32_16x16x32_bf16(qh, kkl, S[nt], 0, 0, 0);
        S[nt] = __builtin_amdgcn_mfma_f32_16x16x32_bf16(ql, kkh, S[nt], 0, 0, 0);
      }
    }
    // online softmax (C-layout: row = quad*4+reg, col = nt*16+r16)
#pragma unroll
    for (int r = 0; r < 4; ++r) {
      const int qrow = wave * 16 + quad * 4 + r;
      float s[4];
#pragma unroll
      for (int nt = 0; nt < 4; ++nt) {
        s[nt] = S[nt][r] * 0.125f;
        if (j == qt && (nt * 16 + r16) > qrow) s[nt] = -1e30f;
      }
      float rm = fmaxf(fmaxf(s[0], s[1]), fmaxf(s[2], s[3]));
#pragma unroll
      for (int o = 8; o > 0; o >>= 1) rm = fmaxf(rm, __shfl_xor(rm, o, 64));
      const float newm = fmaxf(m_i[r], rm);
      float p[4], rs = 0.f;
#pragma unroll
      for (int nt = 0; nt < 4; ++nt) { p[nt] = expf(s[nt] - newm); rs += p[nt]; }
#pragma unroll
      for (int o = 8; o > 0; o >>= 1) rs += __shfl_xor(rs, o, 64);
      const float alpha = expf(m_i[r] - newm);
      l_i[r] = l_i[r] * alpha + rs;
      m_i[r] = newm;
#pragma unroll
      for (int dt = 0; dt < 4; ++dt) O[dt][r] *= alpha;
#pragma unroll
      for (int nt = 0; nt < 4; ++nt)
        Pm[qrow * FP + nt * 16 + r16] = bf_hi(p[nt]);
    }
    __syncthreads();
    // O += P @ V  (A = Pm rows of wave strip, B = Vt)
#pragma unroll
    for (int kh = 0; kh < 2; ++kh) {
      const short8 pa = *(const short8*)&Pm[(wave * 16 + r16) * FP + kh * 32 + quad * 8];
#pragma unroll
      for (int dt = 0; dt < 4; ++dt) {
        const short8 vh = *(const short8*)&Vth[(dt * 16 + r16) * FP + kh * 32 + quad * 8];
        const short8 vl = *(const short8*)&Vtl[(dt * 16 + r16) * FP + kh * 32 + quad * 8];
        O[dt] = __builtin_amdgcn_mfma_f32_16x16x32_bf16(pa, vh, O[dt], 0, 0, 0);
        O[dt] = __builtin_amdgcn_mfma_f32_16x16x32_bf16(pa, vl, O[dt], 0, 0, 0);
      }
    }
  }
  // epilogue
#pragma unroll
  for (int r = 0; r < 4; ++r) {
    const float inv = 1.f / l_i[r];
    const size_t row = (size_t)b * CN + qt * 64 + wave * 16 + quad * 4 + r;
#pragma unroll
    for (int dt = 0; dt < 4; ++dt)
      out[row * CD + head * CHD + dt * 16 + r16] = O[dt][r] * inv;
  }
}

__global__ __launch_bounds__(256) void final_ln(const float* __restrict__ local,
                                                const float* __restrict__ broad,
                                                const float* __restrict__ g, const float* __restrict__ bb,
                                                float* __restrict__ out)
{
  const int r = blockIdx.x, t = threadIdx.x;
  __shared__ float red[4];
  const size_t lb = (size_t)r * CD;
  const size_t br = (size_t)(r >> 2) * CD;
  const float v0 = local[lb + t] + broad[br + t];
  const float v1 = local[lb + 256 + t] + broad[br + 256 + t];
  const float mu = blk_sum(v0 + v1, red) * (1.f / CD);
  const float d0 = v0 - mu, d1 = v1 - mu;
  const float var = blk_sum(d0 * d0 + d1 * d1, red) * (1.f / CD);
  const float inv = rsqrtf(var + CEPS);
  out[lb + t] = d0 * inv * g[t] + bb[t];
  out[lb + 256 + t] = d1 * inv * g[t + 256] + bb[t + 256];
}

// ---------------- launcher ----------------
extern "C" void kernel_launch(void* const* d_in, const int* in_sizes, int n_in,
                              void* d_out, int out_size, void* d_ws, size_t ws_size,
                              hipStream_t stream)
{
  (void)in_sizes; (void)n_in; (void)out_size; (void)ws_size;
  const int*   x         = (const int*)d_in[0];
  const float* emb       = (const float*)d_in[1];
  const float* pos_emb   = (const float*)d_in[2];
  const float* gru_w_ih  = (const float*)d_in[3];
  const float* gru_w_hh  = (const float*)d_in[4];
  const float* gru_b_ih  = (const float*)d_in[5];
  const float* gru_b_hh  = (const float*)d_in[6];
  const float* patch_g   = (const float*)d_in[7];
  const float* patch_b   = (const float*)d_in[8];
  const float* summ_w    = (const float*)d_in[9];
  const float* summ_b    = (const float*)d_in[10];
  const float* msg_w1    = (const float*)d_in[11];
  const float* msg_b1    = (const float*)d_in[12];
  const float* msg_w2    = (const float*)d_in[13];
  const float* msg_b2    = (const float*)d_in[14];
  const float* msg_ln_g  = (const float*)d_in[15];
  const float* msg_ln_b  = (const float*)d_in[16];
  const float* q_w       = (const float*)d_in[17];
  const float* q_b       = (const float*)d_in[18];
  const float* k_w       = (const float*)d_in[19];
  const float* k_b       = (const float*)d_in[20];
  const float* v_w       = (const float*)d_in[21];
  const float* v_b       = (const float*)d_in[22];
  const float* o_w       = (const float*)d_in[23];
  const float* o_b       = (const float*)d_in[24];
  const float* gc_w_ih   = (const float*)d_in[25];
  const float* gc_w_hh   = (const float*)d_in[26];
  const float* gc_b_ih   = (const float*)d_in[27];
  const float* gc_b_hh   = (const float*)d_in[28];
  const float* ar_ln_g   = (const float*)d_in[29];
  const float* ar_ln_b   = (const float*)d_in[30];
  const float* ar_qkv_w  = (const float*)d_in[31];
  const float* ar_qkv_b  = (const float*)d_in[32];
  const float* ar_out_w  = (const float*)d_in[33];
  const float* ar_out_b  = (const float*)d_in[34];
  const float* broad_w   = (const float*)d_in[35];
  const float* broad_b   = (const float*)d_in[36];
  const float* ln_g      = (const float*)d_in[37];
  const float* ln_b      = (const float*)d_in[38];
  const float* head_w    = (const float*)d_in[39];
  float* out = (float*)d_out;

  float* ws = (float*)d_ws;
  float* Wl    = ws + OFF_LOCAL;
  float* Wh    = ws + OFF_H;
  float* Wgi   = ws + OFF_GI;
  float* Wghn  = ws + OFF_GHN;
  float* Wq    = ws + OFF_Q;
  float* Wk    = ws + OFF_K;
  float* Wv    = ws + OFF_V;
  float* Wmsgs = ws + OFF_MSGS;
  float* Wprob = ws + OFF_PROB;
  int*   Widx  = (int*)(ws + OFF_IDX);
  unsigned short* WTh = (unsigned short*)(ws + OFF_WT);
  unsigned short* WTl = WTh + TOT_W;
  float* Wscores = Wgi;
  float* Wfinal  = Wgi;

  const int EW = ROWS * CD / 256;
  const float inv_sqrt_d = 0.04419417382415922f;

  // ---- transpose + pre-split all weights once ----
  auto TR = [&](const float* in, size_t off, int K, int N) {
    transpose_split<<<dim3(N / 32, K / 32), 256, 0, stream>>>(in, WTh + off, WTl + off, K, N);
  };
  TR(gru_w_ih, T_GRU_IH, 512, 1536);
  TR(gru_w_hh, T_GRU_HH, 512, 1536);
  TR(summ_w,   T_SUMM,   512, 512);
  TR(msg_w1,                      T_MSG1A, 512, 512);
  TR(msg_w1 + (size_t)512 * 512,  T_MSG1B, 512, 512);
  TR(msg_w2,   T_MSG2,   512, 512);
  TR(q_w, T_QW, 512, 512);
  TR(k_w, T_KW, 512, 512);
  TR(v_w, T_VW, 512, 512);
  TR(o_w, T_OW, 512, 512);
  TR(gc_w_ih,                       T_GC_TOP, 512, 1536);
  TR(gc_w_ih + (size_t)512 * 1536,  T_GC_BOT, 512, 1536);
  TR(gc_w_hh,  T_GC_HH,  512, 1536);
  TR(ar_qkv_w, T_AR_QKV, 512, 1536);
  TR(ar_out_w, T_AR_OUT, 512, 512);
  TR(broad_w,  T_BROAD,  512, 512);
  TR(head_w,   T_HEAD,   512, 256);

  auto GEMM = [&](const float* A, size_t toff, const float* bias, float* Cc,
                  int M, int N, int ldc, int accum) {
    gemm_mfma_w<<<dim3(N / 128, M / 128), 256, 0, stream>>>(
        A, WTh + toff, WTl + toff, bias, Cc, 512, 512, ldc, 512, accum);
  };

  // ---- patch GRU over P=4 steps ----
  zero_k<<<EW, 256, 0, stream>>>(Wh);
  for (int t = 0; t < CP; ++t) {
    embed_step<<<EW, 256, 0, stream>>>(x, emb, pos_emb, Wq, t);
    GEMM(Wq, T_GRU_IH, gru_b_ih, Wgi, ROWS, 1536, 1536, 0);
    GEMM(Wh, T_GRU_HH, gru_b_hh, Wgi, ROWS, 1024, 1536, 1);
    gemm_mfma_w<<<dim3(4, 64), 256, 0, stream>>>(
        Wh, WTh + T_GRU_HH + (size_t)1024 * 512, WTl + T_GRU_HH + (size_t)1024 * 512,
        gru_b_hh + 1024, Wghn, 512, 512, 512, 512, 0);
    gru_point<<<EW, 256, 0, stream>>>(Wgi, Wghn, Wh, Wl, t);
  }
  ln_rows<<<TROWS, 256, 0, stream>>>(Wl, Wl, patch_g, patch_b);
  mean_pool<<<EW, 256, 0, stream>>>(Wl, Wk);
  GEMM(Wk, T_SUMM, summ_b, Wh, ROWS, 512, 512, 0);

  // ---- rounds ----
  for (int rnd = 0; rnd < 6; ++rnd) {
    GEMM(Wh, T_MSG1A, msg_b1, Wq, ROWS, 512, 512, 0);
    GEMM(Wh, T_MSG1B, nullptr, Wk, ROWS, 512, 512, 0);
    msg_gelu<<<EW, 256, 0, stream>>>(Wq, Wk, Wv);
    GEMM(Wv, T_MSG2, msg_b2, Wmsgs, ROWS, 512, 512, 0);
    GEMM(Wh, T_QW, q_b, Wq, ROWS, 512, 512, 0);
    rotary_k<<<ROWS, 256, 0, stream>>>(Wq);
    GEMM(Wh, T_KW, k_b, Wk, ROWS, 512, 512, 0);
    rotary_k<<<ROWS, 256, 0, stream>>>(Wk);
    GEMM(Wh, T_VW, v_b, Wv, ROWS, 512, 512, 0);
    gemm_mfma<<<dim3(8, 8, CB), 256, 0, stream>>>(
        Wq, Wk, nullptr, Wscores, 512, 512, CN, 512, 0, inv_sqrt_d,
        (long long)CN * CD, (long long)CN * CD, (long long)CN * CN);
    topk_softmax2<<<ROWS, 256, 0, stream>>>(Wscores, Wprob, Widx);
    topk_gather<<<ROWS, 128, 0, stream>>>(Wprob, Widx, Wv, Wq);
    GEMM(Wq, T_OW, o_b, Wk, ROWS, 512, 512, 0);
    GEMM(Wmsgs, T_GC_TOP, gc_b_ih, Wgi, ROWS, 1536, 1536, 0);
    GEMM(Wk,    T_GC_BOT, nullptr, Wgi, ROWS, 1536, 1536, 1);
    GEMM(Wh, T_GC_HH, gc_b_hh, Wgi, ROWS, 1024, 1536, 1);
    gemm_mfma_w<<<dim3(4, 64), 256, 0, stream>>>(
        Wh, WTh + T_GC_HH + (size_t)1024 * 512, WTl + T_GC_HH + (size_t)1024 * 512,
        gc_b_hh + 1024, Wghn, 512, 512, 512, 512, 0);
    gru_ln<<<ROWS, 256, 0, stream>>>(Wgi, Wghn, Wh, msg_ln_g, msg_ln_b);
    if ((rnd & 1) == 1) {
      ln_rows<<<ROWS, 256, 0, stream>>>(Wh, Wq, ar_ln_g, ar_ln_b);
      GEMM(Wq, T_AR_QKV, ar_qkv_b, Wgi, ROWS, 1536, 1536, 0);
      flash_attn_mfma<<<dim3(16, CH, CB), 256, 0, stream>>>(Wgi, Wk);
      GEMM(Wk, T_AR_OUT, ar_out_b, Wh, ROWS, 512, 512, 1);
    }
  }

  // ---- head ----
  GEMM(Wh, T_BROAD, broad_b, Wq, ROWS, 512, 512, 0);
  final_ln<<<TROWS, 256, 0, stream>>>(Wl, Wq, ln_g, ln_b, Wfinal);
  GEMM(Wfinal, T_HEAD, nullptr, out, TROWS, CV, CV, 0);
}

// Round 5
// 5532.306 us; speedup vs baseline: 3.7485x; 1.0758x over previous
//
#include <hip/hip_runtime.h>
#include <math.h>

// ---------------- problem constants ----------------
constexpr int CB = 8, CT = 4096, CP = 4, CD = 512, CV = 256;
constexpr int CN = 1024, CK = 16, CH = 8, CHD = 64;
constexpr int ROWS = CB * CN;     // 8192
constexpr int TROWS = CB * CT;    // 32768
constexpr float CEPS = 1e-5f;
constexpr size_t PN = (size_t)ROWS * CD;   // 4,194,304 (one pair-plane)

// ---------------- workspace layout (floats) ----------------
// Pair buffers store hi ushort[PN] followed by lo ushort[PN] = PN floats total.
constexpr size_t OFF_LOCAL = 0;                                    // 16,777,216 fp32 local
constexpr size_t OFF_HP    = OFF_LOCAL + (size_t)ROWS * CP * CD;   //  4,194,304 h pair
constexpr size_t OFF_GI    = OFF_HP    + PN;                       // 12,582,912 gi/scores/qkv-pair/tmp/final
constexpr size_t OFF_GHN   = OFF_GI    + (size_t)ROWS * 3 * CD;    //  4,194,304 ghn / msgs pair / final tail
constexpr size_t OFF_V     = OFF_GHN   + PN;                       //  4,194,304 v fp32 / P1 / broad
constexpr size_t OFF_A     = OFF_V     + PN;                       //  4,194,304 pair A (Xt/Q/ctx/ln/pool)
constexpr size_t OFF_B     = OFF_A     + PN;                       //  4,194,304 pair B (G/K/retr/attn-out)
constexpr size_t OFF_PROB  = OFF_B     + PN;                       //    131,072
constexpr size_t OFF_IDX   = OFF_PROB  + (size_t)ROWS * CK;        //    131,072
constexpr size_t OFF_WT    = OFF_IDX   + (size_t)ROWS * CK;        //  7,471,104
// end = 58,064,896 floats = 221.5 MiB (< 237.5 MiB proven OK)

constexpr size_t TOT_W    = 7471104;
constexpr size_t T_GRU_IH = 0;
constexpr size_t T_GRU_HH = T_GRU_IH + 786432;
constexpr size_t T_SUMM   = T_GRU_HH + 786432;
constexpr size_t T_MSG1A  = T_SUMM   + 262144;
constexpr size_t T_MSG1B  = T_MSG1A  + 262144;
constexpr size_t T_MSG2   = T_MSG1B  + 262144;
constexpr size_t T_QW     = T_MSG2   + 262144;
constexpr size_t T_KW     = T_QW     + 262144;
constexpr size_t T_VW     = T_KW     + 262144;
constexpr size_t T_OW     = T_VW     + 262144;
constexpr size_t T_GC_TOP = T_OW     + 262144;
constexpr size_t T_GC_BOT = T_GC_TOP + 786432;
constexpr size_t T_GC_HH  = T_GC_BOT + 786432;
constexpr size_t T_AR_QKV = T_GC_HH  + 786432;
constexpr size_t T_AR_OUT = T_AR_QKV + 786432;
constexpr size_t T_BROAD  = T_AR_OUT + 262144;
constexpr size_t T_HEAD   = T_BROAD  + 262144;

// GEMM flags
constexpr int F_ACC_F32  = 1;
constexpr int F_ACC_PAIR = 2;
constexpr int F_WR_F32   = 4;
constexpr int F_WR_PAIR  = 8;
constexpr int F_TRI      = 16;

// ---------------- device helpers ----------------
typedef __attribute__((ext_vector_type(8))) short short8;
typedef __attribute__((ext_vector_type(4))) float f32x4;

__device__ __forceinline__ float sigm(float x) { return 1.f / (1.f + expf(-x)); }
__device__ __forceinline__ float geluf(float x) {
  return 0.5f * x * (1.f + erff(x * 0.7071067811865475f));
}
__device__ __forceinline__ unsigned short bf_hi(float x) {
  const unsigned u = __float_as_uint(x);
  return (unsigned short)((u + 0x7FFFu + ((u >> 16) & 1u)) >> 16);
}
__device__ __forceinline__ float bf_f(unsigned short h) {
  return __uint_as_float((unsigned)h << 16);
}
__device__ __forceinline__ void split_store(float v, unsigned short* ph, unsigned short* pl) {
  const unsigned short h = bf_hi(v);
  *ph = h; *pl = bf_hi(v - bf_f(h));
}
__device__ __forceinline__ float blk_sum(float v, float* red) {
#pragma unroll
  for (int o = 32; o > 0; o >>= 1) v += __shfl_down(v, o, 64);
  const int wv = threadIdx.x >> 6, ln = threadIdx.x & 63;
  __syncthreads();
  if (ln == 0) red[wv] = v;
  __syncthreads();
  return red[0] + red[1] + red[2] + red[3];
}

// ---------------- transpose + bf16 split (weights) ----------------
__global__ __launch_bounds__(256) void transpose_split(const float* __restrict__ in,
                                                       unsigned short* __restrict__ oh,
                                                       unsigned short* __restrict__ ol,
                                                       int K, int N)
{
  __shared__ float tile[32][33];
  const int n0 = blockIdx.x * 32, k0 = blockIdx.y * 32;
  const int tx = threadIdx.x & 31, ty = threadIdx.x >> 5;
#pragma unroll
  for (int i = 0; i < 32; i += 8)
    tile[ty + i][tx] = in[(size_t)(k0 + ty + i) * N + n0 + tx];
  __syncthreads();
#pragma unroll
  for (int i = 0; i < 32; i += 8) {
    const float v = tile[tx][ty + i];
    const unsigned short h = bf_hi(v);
    oh[(size_t)(n0 + ty + i) * K + k0 + tx] = h;
    ol[(size_t)(n0 + ty + i) * K + k0 + tx] = bf_hi(v - bf_f(h));
  }
}

// ---------------- unified 3-product bf16 MFMA GEMM, pre-split operands ----
// C[M,N] = scale*(A@Bt^T) + bias (+C);  A,Bt as hi/lo ushort [.,K].
// 128x128 tile, BK=32, 4 waves 2x2, each 4x4 of 16x16x32 MFMA.
__global__ __launch_bounds__(256, 2) void gemm_bf3(
    const unsigned short* __restrict__ AH, const unsigned short* __restrict__ AL, int lda,
    const unsigned short* __restrict__ BH, const unsigned short* __restrict__ BL, int ldb,
    const float* __restrict__ bias, float scale,
    float* __restrict__ Cf, int ldc,
    unsigned short* __restrict__ CHp, unsigned short* __restrict__ CLp, int ldcp,
    int K, int flags, long long sA, long long sB, long long sC)
{
  AH += (size_t)blockIdx.z * sA; AL += (size_t)blockIdx.z * sA;
  BH += (size_t)blockIdx.z * sB; BL += (size_t)blockIdx.z * sB;
  if (Cf) Cf += (size_t)blockIdx.z * sC;
  int bm, bn;
  if (flags & F_TRI) {
    int t = blockIdx.x, i = 0, acc = 0;
    while (acc + i + 1 <= t) { ++i; acc += i; }
    bm = i << 7; bn = (t - acc) << 7;
  } else {
    bm = blockIdx.y << 7; bn = blockIdx.x << 7;
  }
  __shared__ __align__(16) unsigned short AsH[128][40];
  __shared__ __align__(16) unsigned short AsL[128][40];
  __shared__ __align__(16) unsigned short BsH[128][40];
  __shared__ __align__(16) unsigned short BsL[128][40];
  const int tid = threadIdx.x;
  const int lane = tid & 63, wave = tid >> 6;
  const int wm = (wave & 1) << 6, wn = (wave >> 1) << 6;
  const int r16 = lane & 15, quad = lane >> 4;
  const int sr = tid >> 1, sc = (tid & 1) << 4;
  const f32x4 zero = {0.f, 0.f, 0.f, 0.f};
  f32x4 acc[4][4];
#pragma unroll
  for (int i = 0; i < 4; ++i)
#pragma unroll
    for (int j = 0; j < 4; ++j) acc[i][j] = zero;

  for (int k0 = 0; k0 < K; k0 += 32) {
    const unsigned short* pAH = AH + (size_t)(bm + sr) * lda + k0 + sc;
    const unsigned short* pAL = AL + (size_t)(bm + sr) * lda + k0 + sc;
    const unsigned short* pBH = BH + (size_t)(bn + sr) * ldb + k0 + sc;
    const unsigned short* pBL = BL + (size_t)(bn + sr) * ldb + k0 + sc;
    *(uint4*)&AsH[sr][sc]     = *(const uint4*)pAH;
    *(uint4*)&AsH[sr][sc + 8] = *(const uint4*)(pAH + 8);
    *(uint4*)&AsL[sr][sc]     = *(const uint4*)pAL;
    *(uint4*)&AsL[sr][sc + 8] = *(const uint4*)(pAL + 8);
    *(uint4*)&BsH[sr][sc]     = *(const uint4*)pBH;
    *(uint4*)&BsH[sr][sc + 8] = *(const uint4*)(pBH + 8);
    *(uint4*)&BsL[sr][sc]     = *(const uint4*)pBL;
    *(uint4*)&BsL[sr][sc + 8] = *(const uint4*)(pBL + 8);
    __syncthreads();
    short8 bh[4], bl[4];
#pragma unroll
    for (int ni = 0; ni < 4; ++ni) {
      bh[ni] = *(const short8*)&BsH[wn + ni * 16 + r16][quad * 8];
      bl[ni] = *(const short8*)&BsL[wn + ni * 16 + r16][quad * 8];
    }
#pragma unroll
    for (int mi = 0; mi < 4; ++mi) {
      const short8 ah = *(const short8*)&AsH[wm + mi * 16 + r16][quad * 8];
      const short8 al = *(const short8*)&AsL[wm + mi * 16 + r16][quad * 8];
#pragma unroll
      for (int ni = 0; ni < 4; ++ni) {
        acc[mi][ni] = __builtin_amdgcn_mfma_f32_16x16x32_bf16(ah, bh[ni], acc[mi][ni], 0, 0, 0);
        acc[mi][ni] = __builtin_amdgcn_mfma_f32_16x16x32_bf16(ah, bl[ni], acc[mi][ni], 0, 0, 0);
        acc[mi][ni] = __builtin_amdgcn_mfma_f32_16x16x32_bf16(al, bh[ni], acc[mi][ni], 0, 0, 0);
      }
    }
    __syncthreads();
  }
#pragma unroll
  for (int mi = 0; mi < 4; ++mi) {
    const int row0 = bm + wm + mi * 16 + quad * 4;
#pragma unroll
    for (int ni = 0; ni < 4; ++ni) {
      const int col = bn + wn + ni * 16 + r16;
      const float bv = bias ? bias[col] : 0.f;
#pragma unroll
      for (int rg = 0; rg < 4; ++rg) {
        const int row = row0 + rg;
        float o = acc[mi][ni][rg] * scale + bv;
        if (flags & F_ACC_F32) o += Cf[(size_t)row * ldc + col];
        if (flags & F_ACC_PAIR) {
          const size_t ip = (size_t)row * ldcp + col;
          o += bf_f(CHp[ip]) + bf_f(CLp[ip]);
        }
        if (flags & F_WR_F32) Cf[(size_t)row * ldc + col] = o;
        if (flags & F_WR_PAIR) {
          const size_t ip = (size_t)row * ldcp + col;
          split_store(o, &CHp[ip], &CLp[ip]);
        }
      }
    }
  }
}

// ---------------- small kernels ----------------
__global__ void zero_k(float* __restrict__ p) {
  p[(size_t)blockIdx.x * 256 + threadIdx.x] = 0.f;
}

__global__ void embed_p(const int* __restrict__ x, const float* __restrict__ emb,
                        const float* __restrict__ pos,
                        unsigned short* __restrict__ oh, unsigned short* __restrict__ ol, int t)
{
  const int i = blockIdx.x * 256 + threadIdx.x;
  const int r = i >> 9, d = i & 511;
  const int b = r >> 10, n = r & (CN - 1);
  const int tok = x[b * CT + n * CP + t];
  const float v = emb[(size_t)tok * CD + d] + pos[t * CD + d];
  split_store(v, &oh[i], &ol[i]);
}

__global__ void gru_point_p(const float* __restrict__ gi, const float* __restrict__ ghn,
                            unsigned short* __restrict__ hH, unsigned short* __restrict__ hL,
                            float* __restrict__ hs, int t)
{
  const int i = blockIdx.x * 256 + threadIdx.x;
  const int r = i >> 9, d = i & 511;
  const size_t gb = (size_t)r * (3 * CD) + d;
  const float sr_ = gi[gb], sz = gi[gb + CD], inn = gi[gb + 2 * CD];
  const float hn = ghn[i];
  const float hp = bf_f(hH[i]) + bf_f(hL[i]);
  const float rr = sigm(sr_), zz = sigm(sz);
  const float nn = tanhf(inn + rr * hn);
  const float hv = (1.f - zz) * nn + zz * hp;
  split_store(hv, &hH[i], &hL[i]);
  hs[(size_t)r * (CP * CD) + (size_t)t * CD + d] = hv;
}

__global__ __launch_bounds__(256) void ln_rows(const float* __restrict__ in, float* __restrict__ out,
                                               const float* __restrict__ g, const float* __restrict__ b)
{
  const int r = blockIdx.x, t = threadIdx.x;
  __shared__ float red[4];
  const float* ip = in + (size_t)r * CD;
  const float v0 = ip[t], v1 = ip[t + 256];
  const float mu = blk_sum(v0 + v1, red) * (1.f / CD);
  const float d0 = v0 - mu, d1 = v1 - mu;
  const float var = blk_sum(d0 * d0 + d1 * d1, red) * (1.f / CD);
  const float inv = rsqrtf(var + CEPS);
  float* op = out + (size_t)r * CD;
  op[t] = d0 * inv * g[t] + b[t];
  op[t + 256] = d1 * inv * g[t + 256] + b[t + 256];
}

// LN: pair in -> pair out (ar path)
__global__ __launch_bounds__(256) void ln_pp(const unsigned short* __restrict__ inH,
                                             const unsigned short* __restrict__ inL,
                                             unsigned short* __restrict__ oh, unsigned short* __restrict__ ol,
                                             const float* __restrict__ g, const float* __restrict__ b)
{
  const int r = blockIdx.x, t = threadIdx.x;
  __shared__ float red[4];
  const size_t i0 = (size_t)r * CD + t, i1 = i0 + 256;
  const float v0 = bf_f(inH[i0]) + bf_f(inL[i0]);
  const float v1 = bf_f(inH[i1]) + bf_f(inL[i1]);
  const float mu = blk_sum(v0 + v1, red) * (1.f / CD);
  const float d0 = v0 - mu, d1 = v1 - mu;
  const float var = blk_sum(d0 * d0 + d1 * d1, red) * (1.f / CD);
  const float inv = rsqrtf(var + CEPS);
  split_store(d0 * inv * g[t] + b[t], &oh[i0], &ol[i0]);
  split_store(d1 * inv * g[t + 256] + b[t + 256], &oh[i1], &ol[i1]);
}

__global__ void mean_pool_p(const float* __restrict__ local,
                            unsigned short* __restrict__ oh, unsigned short* __restrict__ ol)
{
  const int i = blockIdx.x * 256 + threadIdx.x;
  const int r = i >> 9, d = i & 511;
  const float* p = local + (size_t)r * (CP * CD) + d;
  split_store(0.25f * (p[0] + p[CD] + p[2 * CD] + p[3 * CD]), &oh[i], &ol[i]);
}

__global__ void msg_gelu_p(const float* __restrict__ pre, const float* __restrict__ nb,
                           unsigned short* __restrict__ oh, unsigned short* __restrict__ ol)
{
  const int i = blockIdx.x * 256 + threadIdx.x;
  const int r = i >> 9;
  const int n = r & (CN - 1);
  const float pv = pre[i];
  float acc = 0.f;
#pragma unroll
  for (int w = 0; w <= 4; ++w) {
    const float xv = pv + ((n >= w) ? nb[(size_t)i - (size_t)w * CD] : 0.f);
    acc += geluf(xv);
  }
  split_store(acc * 0.2f, &oh[i], &ol[i]);
}

__global__ void rotary_p(const float* __restrict__ in,
                         unsigned short* __restrict__ oh, unsigned short* __restrict__ ol)
{
  const int i = blockIdx.x * 256 + threadIdx.x;   // ROWS*256
  const int r = i >> 8, j = i & 255;
  const int n = r & (CN - 1);
  const float fr = (float)n * expf(-9.210340371976184f * ((float)j * (1.f / 256.f)));
  float s, c;
  sincosf(fr, &s, &c);
  const float* p = in + (size_t)r * CD;
  const float t1 = p[j], t2 = p[j + 256];
  const size_t o0 = (size_t)r * CD + j, o1 = o0 + 256;
  split_store(t1 * c - t2 * s, &oh[o0], &ol[o0]);
  split_store(t2 * c + t1 * s, &oh[o1], &ol[o1]);
}

// ---------------- top-K ----------------
__global__ __launch_bounds__(256) void topk_softmax2(const float* __restrict__ scores,
                                                     float* __restrict__ probs, int* __restrict__ idxs)
{
  const int rrow = blockIdx.x;
  const int b = rrow >> 10, n = rrow & (CN - 1);
  const float* row = scores + ((size_t)b * CN + n) * CN;
  __shared__ float sv[CN];
  __shared__ unsigned long long wred[4];
  __shared__ float topv[CK];
  __shared__ int topi[CK];
  const int tid = threadIdx.x;
#pragma unroll
  for (int q = 0; q < 4; ++q) {
    const int m = tid + q * 256;
    sv[m] = (m <= n) ? row[m] : -INFINITY;
  }
  __syncthreads();
  for (int it = 0; it < CK; ++it) {
    unsigned long long best = 0ull;
#pragma unroll
    for (int q = 0; q < 4; ++q) {
      const int m = tid + q * 256;
      unsigned u = __float_as_uint(sv[m]);
      u = (u & 0x80000000u) ? ~u : (u | 0x80000000u);
      const unsigned long long key = ((unsigned long long)u << 32) | (unsigned)(CN - 1 - m);
      best = best > key ? best : key;
    }
#pragma unroll
    for (int o = 32; o > 0; o >>= 1) {
      const unsigned long long o2 = __shfl_down(best, o, 64);
      best = best > o2 ? best : o2;
    }
    if ((tid & 63) == 0) wred[tid >> 6] = best;
    __syncthreads();
    if (tid == 0) {
      unsigned long long b0 = wred[0];
      for (int w = 1; w < 4; ++w) b0 = b0 > wred[w] ? b0 : wred[w];
      const int m = CN - 1 - (int)(b0 & 0xFFFFFFFFu);
      unsigned u = (unsigned)(b0 >> 32);
      u = (u & 0x80000000u) ? (u & 0x7FFFFFFFu) : ~u;
      topv[it] = __uint_as_float(u);
      topi[it] = m;
      sv[m] = -INFINITY;
    }
    __syncthreads();
  }
  if (tid < CK) {
    const float mx = topv[0];
    float sum = 0.f;
#pragma unroll
    for (int q = 0; q < CK; ++q)
      sum += (topv[q] == -INFINITY) ? 0.f : expf(topv[q] - mx);
    const float e = (topv[tid] == -INFINITY) ? 0.f : expf(topv[tid] - mx);
    probs[(size_t)rrow * CK + tid] = e / sum;
    idxs[(size_t)rrow * CK + tid] = topi[tid];
  }
}

__global__ __launch_bounds__(128) void topk_gather_p(const float* __restrict__ probs,
                                                     const int* __restrict__ idxs,
                                                     const float* __restrict__ v,
                                                     unsigned short* __restrict__ oh,
                                                     unsigned short* __restrict__ ol)
{
  const int r = blockIdx.x;
  const int b = r >> 10;
  __shared__ float p[CK];
  __shared__ int id[CK];
  if (threadIdx.x < CK) {
    p[threadIdx.x] = probs[(size_t)r * CK + threadIdx.x];
    id[threadIdx.x] = idxs[(size_t)r * CK + threadIdx.x];
  }
  __syncthreads();
  for (int d = threadIdx.x; d < CD; d += 128) {
    float a = 0.f;
#pragma unroll
    for (int q = 0; q < CK; ++q)
      a += p[q] * v[((size_t)(b << 10) + id[q]) * CD + d];
    split_store(a, &oh[(size_t)r * CD + d], &ol[(size_t)r * CD + d]);
  }
}

__global__ __launch_bounds__(256) void gru_ln_p(const float* __restrict__ gi, const float* __restrict__ ghn,
                                                unsigned short* __restrict__ hH, unsigned short* __restrict__ hL,
                                                const float* __restrict__ g, const float* __restrict__ b)
{
  const int r = blockIdx.x, t = threadIdx.x;
  __shared__ float red[4];
  float u[2];
#pragma unroll
  for (int q = 0; q < 2; ++q) {
    const int d = t + q * 256;
    const size_t gb = (size_t)r * (3 * CD) + d;
    const float sr_ = gi[gb], sz = gi[gb + CD], inn = gi[gb + 2 * CD];
    const float hn = ghn[(size_t)r * CD + d];
    const size_t hi = (size_t)r * CD + d;
    const float hp = bf_f(hH[hi]) + bf_f(hL[hi]);
    const float rr = sigm(sr_), zz = sigm(sz);
    const float nn = tanhf(inn + rr * hn);
    u[q] = (1.f - zz) * nn + zz * hp;
  }
  const float mu = blk_sum(u[0] + u[1], red) * (1.f / CD);
  const float d0 = u[0] - mu, d1 = u[1] - mu;
  const float var = blk_sum(d0 * d0 + d1 * d1, red) * (1.f / CD);
  const float inv = rsqrtf(var + CEPS);
  split_store(d0 * inv * g[t] + b[t], &hH[(size_t)r * CD + t], &hL[(size_t)r * CD + t]);
  split_store(d1 * inv * g[t + 256] + b[t + 256],
              &hH[(size_t)r * CD + t + 256], &hL[(size_t)r * CD + t + 256]);
}

// ---------------- MFMA flash attention, pair I/O ----------------
constexpr int FP = 72;
__global__ __launch_bounds__(256, 2) void flash_attn_p(const unsigned short* __restrict__ qkvH,
                                                       const unsigned short* __restrict__ qkvL,
                                                       unsigned short* __restrict__ outH,
                                                       unsigned short* __restrict__ outL)
{
  __shared__ __align__(16) unsigned short Qh[64 * FP], Ql[64 * FP];
  __shared__ __align__(16) unsigned short Kh[64 * FP], Kl[64 * FP];
  __shared__ __align__(16) unsigned short Vth[64 * FP], Vtl[64 * FP];
  __shared__ __align__(16) unsigned short Pm[64 * FP];
  const int qt = blockIdx.x, head = blockIdx.y, b = blockIdx.z;
  const int tid = threadIdx.x;
  const int lane = tid & 63, wave = tid >> 6;
  const int r16 = lane & 15, quad = lane >> 4;
  const size_t base = (size_t)b * CN * (3 * CD) + head * CHD;

  {
    const int r = tid >> 2, c0 = (tid & 3) << 4;
    const unsigned short* qh = qkvH + base + (size_t)(qt * 64 + r) * (3 * CD) + c0;
    const unsigned short* ql = qkvL + base + (size_t)(qt * 64 + r) * (3 * CD) + c0;
    *(uint4*)&Qh[r * FP + c0]     = *(const uint4*)qh;
    *(uint4*)&Qh[r * FP + c0 + 8] = *(const uint4*)(qh + 8);
    *(uint4*)&Ql[r * FP + c0]     = *(const uint4*)ql;
    *(uint4*)&Ql[r * FP + c0 + 8] = *(const uint4*)(ql + 8);
  }
  float m_i[4], l_i[4];
  f32x4 O[4];
  const f32x4 zero = {0.f, 0.f, 0.f, 0.f};
#pragma unroll
  for (int r = 0; r < 4; ++r) { m_i[r] = -INFINITY; l_i[r] = 0.f; }
#pragma unroll
  for (int d = 0; d < 4; ++d) O[d] = zero;

  for (int j = 0; j <= qt; ++j) {
    __syncthreads();
    {
      const int r = tid >> 2, c0 = (tid & 3) << 4;
      const unsigned short* kh = qkvH + base + (size_t)(j * 64 + r) * (3 * CD) + CD + c0;
      const unsigned short* kl = qkvL + base + (size_t)(j * 64 + r) * (3 * CD) + CD + c0;
      *(uint4*)&Kh[r * FP + c0]     = *(const uint4*)kh;
      *(uint4*)&Kh[r * FP + c0 + 8] = *(const uint4*)(kh + 8);
      *(uint4*)&Kl[r * FP + c0]     = *(const uint4*)kl;
      *(uint4*)&Kl[r * FP + c0 + 8] = *(const uint4*)(kl + 8);
      // V transposed, XOR-swizzled (col' = rp ^ ((R>>3)<<3)) -> 2 lanes/bank
      const int rp = (tid >> 3) << 1, c0v = (tid & 7) << 3;
      const unsigned short* v0h = qkvH + base + (size_t)(j * 64 + rp) * (3 * CD) + 2 * CD + c0v;
      const unsigned short* v1h = v0h + 3 * CD;
      const unsigned short* v0l = qkvL + base + (size_t)(j * 64 + rp) * (3 * CD) + 2 * CD + c0v;
      const unsigned short* v1l = v0l + 3 * CD;
      unsigned short xh[8], yh[8], xl[8], yl[8];
      *(uint4*)xh = *(const uint4*)v0h; *(uint4*)yh = *(const uint4*)v1h;
      *(uint4*)xl = *(const uint4*)v0l; *(uint4*)yl = *(const uint4*)v1l;
#pragma unroll
      for (int c = 0; c < 8; ++c) {
        const int R = c0v + c;
        const int col = rp ^ ((R >> 3) << 3);
        *(unsigned*)&Vth[R * FP + col] = (unsigned)xh[c] | ((unsigned)yh[c] << 16);
        *(unsigned*)&Vtl[R * FP + col] = (unsigned)xl[c] | ((unsigned)yl[c] << 16);
      }
    }
    __syncthreads();
    f32x4 S[4];
#pragma unroll
    for (int nt = 0; nt < 4; ++nt) S[nt] = zero;
#pragma unroll
    for (int kh2 = 0; kh2 < 2; ++kh2) {
      const short8 qh = *(const short8*)&Qh[(wave * 16 + r16) * FP + kh2 * 32 + quad * 8];
      const short8 ql = *(const short8*)&Ql[(wave * 16 + r16) * FP + kh2 * 32 + quad * 8];
#pragma unroll
      for (int nt = 0; nt < 4; ++nt) {
        const short8 kkh = *(const short8*)&Kh[(nt * 16 + r16) * FP + kh2 * 32 + quad * 8];
        const short8 kkl = *(const short8*)&Kl[(nt * 16 + r16) * FP + kh2 * 32 + quad * 8];
        S[nt] = __builtin_amdgcn_mfma_f32_16x16x32_bf16(qh, kkh, S[nt], 0, 0, 0);
        S[nt] = __builtin_amdgcn_mfma_f32_16x16x32_bf16(qh, kkl, S[nt], 0, 0, 0);
        S[nt] = __builtin_amdgcn_mfma_f32_16x16x32_bf16(ql, kkh, S[nt], 0, 0, 0);
      }
    }
#pragma unroll
    for (int r = 0; r < 4; ++r) {
      const int qrow = wave * 16 + quad * 4 + r;
      float s[4];
#pragma unroll
      for (int nt = 0; nt < 4; ++nt) {
        s[nt] = S[nt][r] * 0.125f;
        if (j == qt && (nt * 16 + r16) > qrow) s[nt] = -1e30f;
      }
      float rm = fmaxf(fmaxf(s[0], s[1]), fmaxf(s[2], s[3]));
#pragma unroll
      for (int o = 8; o > 0; o >>= 1) rm = fmaxf(rm, __shfl_xor(rm, o, 64));
      const float newm = fmaxf(m_i[r], rm);
      float p[4], rs = 0.f;
#pragma unroll
      for (int nt = 0; nt < 4; ++nt) { p[nt] = expf(s[nt] - newm); rs += p[nt]; }
#pragma unroll
      for (int o = 8; o > 0; o >>= 1) rs += __shfl_xor(rs, o, 64);
      const float alpha = expf(m_i[r] - newm);
      l_i[r] = l_i[r] * alpha + rs;
      m_i[r] = newm;
#pragma unroll
      for (int dt = 0; dt < 4; ++dt) O[dt][r] *= alpha;
#pragma unroll
      for (int nt = 0; nt < 4; ++nt)
        Pm[qrow * FP + nt * 16 + r16] = bf_hi(p[nt]);
    }
    __syncthreads();
#pragma unroll
    for (int kh2 = 0; kh2 < 2; ++kh2) {
      const short8 pa = *(const short8*)&Pm[(wave * 16 + r16) * FP + kh2 * 32 + quad * 8];
#pragma unroll
      for (int dt = 0; dt < 4; ++dt) {
        const int R = dt * 16 + r16;
        const int col = (kh2 * 32 + quad * 8) ^ ((R >> 3) << 3);
        const short8 vh = *(const short8*)&Vth[R * FP + col];
        const short8 vl = *(const short8*)&Vtl[R * FP + col];
        O[dt] = __builtin_amdgcn_mfma_f32_16x16x32_bf16(pa, vh, O[dt], 0, 0, 0);
        O[dt] = __builtin_amdgcn_mfma_f32_16x16x32_bf16(pa, vl, O[dt], 0, 0, 0);
      }
    }
  }
#pragma unroll
  for (int r = 0; r < 4; ++r) {
    const float inv = 1.f / l_i[r];
    const size_t row = (size_t)b * CN + qt * 64 + wave * 16 + quad * 4 + r;
#pragma unroll
    for (int dt = 0; dt < 4; ++dt) {
      const size_t o = row * CD + head * CHD + dt * 16 + r16;
      split_store(O[dt][r] * inv, &outH[o], &outL[o]);
    }
  }
}

__global__ __launch_bounds__(256) void final_ln_p(const float* __restrict__ local,
                                                  const float* __restrict__ broad,
                                                  const float* __restrict__ g, const float* __restrict__ bb,
                                                  unsigned short* __restrict__ oh,
                                                  unsigned short* __restrict__ ol)
{
  const int r = blockIdx.x, t = threadIdx.x;
  __shared__ float red[4];
  const size_t lb = (size_t)r * CD;
  const size_t br = (size_t)(r >> 2) * CD;
  const float v0 = local[lb + t] + broad[br + t];
  const float v1 = local[lb + 256 + t] + broad[br + 256 + t];
  const float mu = blk_sum(v0 + v1, red) * (1.f / CD);
  const float d0 = v0 - mu, d1 = v1 - mu;
  const float var = blk_sum(d0 * d0 + d1 * d1, red) * (1.f / CD);
  const float inv = rsqrtf(var + CEPS);
  split_store(d0 * inv * g[t] + bb[t], &oh[lb + t], &ol[lb + t]);
  split_store(d1 * inv * g[t + 256] + bb[t + 256], &oh[lb + 256 + t], &ol[lb + 256 + t]);
}

// ---------------- launcher ----------------
extern "C" void kernel_launch(void* const* d_in, const int* in_sizes, int n_in,
                              void* d_out, int out_size, void* d_ws, size_t ws_size,
                              hipStream_t stream)
{
  (void)in_sizes; (void)n_in; (void)out_size; (void)ws_size;
  const int*   x         = (const int*)d_in[0];
  const float* emb       = (const float*)d_in[1];
  const float* pos_emb   = (const float*)d_in[2];
  const float* gru_w_ih  = (const float*)d_in[3];
  const float* gru_w_hh  = (const float*)d_in[4];
  const float* gru_b_ih  = (const float*)d_in[5];
  const float* gru_b_hh  = (const float*)d_in[6];
  const float* patch_g   = (const float*)d_in[7];
  const float* patch_b   = (const float*)d_in[8];
  const float* summ_w    = (const float*)d_in[9];
  const float* summ_b    = (const float*)d_in[10];
  const float* msg_w1    = (const float*)d_in[11];
  const float* msg_b1    = (const float*)d_in[12];
  const float* msg_w2    = (const float*)d_in[13];
  const float* msg_b2    = (const float*)d_in[14];
  const float* msg_ln_g  = (const float*)d_in[15];
  const float* msg_ln_b  = (const float*)d_in[16];
  const float* q_w       = (const float*)d_in[17];
  const float* q_b       = (const float*)d_in[18];
  const float* k_w       = (const float*)d_in[19];
  const float* k_b       = (const float*)d_in[20];
  const float* v_w       = (const float*)d_in[21];
  const float* v_b       = (const float*)d_in[22];
  const float* o_w       = (const float*)d_in[23];
  const float* o_b       = (const float*)d_in[24];
  const float* gc_w_ih   = (const float*)d_in[25];
  const float* gc_w_hh   = (const float*)d_in[26];
  const float* gc_b_ih   = (const float*)d_in[27];
  const float* gc_b_hh   = (const float*)d_in[28];
  const float* ar_ln_g   = (const float*)d_in[29];
  const float* ar_ln_b   = (const float*)d_in[30];
  const float* ar_qkv_w  = (const float*)d_in[31];
  const float* ar_qkv_b  = (const float*)d_in[32];
  const float* ar_out_w  = (const float*)d_in[33];
  const float* ar_out_b  = (const float*)d_in[34];
  const float* broad_w   = (const float*)d_in[35];
  const float* broad_b   = (const float*)d_in[36];
  const float* ln_g      = (const float*)d_in[37];
  const float* ln_b      = (const float*)d_in[38];
  const float* head_w    = (const float*)d_in[39];
  float* out = (float*)d_out;

  float* ws = (float*)d_ws;
  float* WL   = ws + OFF_LOCAL;
  float* WGI  = ws + OFF_GI;
  float* WGHN = ws + OFF_GHN;
  float* WV   = ws + OFF_V;
  float* Wprob = ws + OFF_PROB;
  int*   Widx  = (int*)(ws + OFF_IDX);
  unsigned short* WTh = (unsigned short*)(ws + OFF_WT);
  unsigned short* WTl = WTh + TOT_W;
  unsigned short* WhH = (unsigned short*)(ws + OFF_HP);
  unsigned short* WhL = WhH + PN;
  unsigned short* pAH = (unsigned short*)(ws + OFF_A);
  unsigned short* pAL = pAH + PN;
  unsigned short* pBH = (unsigned short*)(ws + OFF_B);
  unsigned short* pBL = pBH + PN;
  unsigned short* MsH = (unsigned short*)WGHN;
  unsigned short* MsL = MsH + PN;
  unsigned short* QkH = (unsigned short*)WGI;
  unsigned short* QkL = QkH + (size_t)ROWS * 1536;
  unsigned short* FnH = (unsigned short*)WGI;
  unsigned short* FnL = FnH + (size_t)TROWS * CD;

  const int EW = ROWS * CD / 256;
  const float inv_sqrt_d = 0.04419417382415922f;   // 1/sqrt(512)

  auto TR = [&](const float* in, size_t off, int K, int N) {
    transpose_split<<<dim3(N / 32, K / 32), 256, 0, stream>>>(in, WTh + off, WTl + off, K, N);
  };
  TR(gru_w_ih, T_GRU_IH, 512, 1536);
  TR(gru_w_hh, T_GRU_HH, 512, 1536);
  TR(summ_w,   T_SUMM,   512, 512);
  TR(msg_w1,                      T_MSG1A, 512, 512);
  TR(msg_w1 + (size_t)512 * 512,  T_MSG1B, 512, 512);
  TR(msg_w2,   T_MSG2,   512, 512);
  TR(q_w, T_QW, 512, 512);
  TR(k_w, T_KW, 512, 512);
  TR(v_w, T_VW, 512, 512);
  TR(o_w, T_OW, 512, 512);
  TR(gc_w_ih,                       T_GC_TOP, 512, 1536);
  TR(gc_w_ih + (size_t)512 * 1536,  T_GC_BOT, 512, 1536);
  TR(gc_w_hh,  T_GC_HH,  512, 1536);
  TR(ar_qkv_w, T_AR_QKV, 512, 1536);
  TR(ar_out_w, T_AR_OUT, 512, 512);
  TR(broad_w,  T_BROAD,  512, 512);
  TR(head_w,   T_HEAD,   512, 256);

  // weight GEMM: A pair x WT[toff], output per flags
  auto G3 = [&](const unsigned short* AH_, const unsigned short* AL_, int lda_,
                size_t toff, const float* bias_, float* Cf_, int ldc_,
                unsigned short* CHp_, unsigned short* CLp_, int ldcp_,
                int flags_, int gx, int gy) {
    gemm_bf3<<<dim3(gx, gy), 256, 0, stream>>>(
        AH_, AL_, lda_, WTh + toff, WTl + toff, 512, bias_, 1.f,
        Cf_, ldc_, CHp_, CLp_, ldcp_, 512, flags_, 0, 0, 0);
  };

  // ---- patch GRU over P=4 steps ----
  zero_k<<<EW, 256, 0, stream>>>(ws + OFF_HP);   // h pair = 0
  for (int t = 0; t < CP; ++t) {
    embed_p<<<EW, 256, 0, stream>>>(x, emb, pos_emb, pAH, pAL, t);
    G3(pAH, pAL, 512, T_GRU_IH, gru_b_ih, WGI, 1536, nullptr, nullptr, 0, F_WR_F32, 12, 64);
    G3(WhH, WhL, 512, T_GRU_HH, gru_b_hh, WGI, 1536, nullptr, nullptr, 0,
       F_ACC_F32 | F_WR_F32, 8, 64);
    G3(WhH, WhL, 512, T_GRU_HH + (size_t)1024 * 512, gru_b_hh + 1024, WGHN, 512,
       nullptr, nullptr, 0, F_WR_F32, 4, 64);
    gru_point_p<<<EW, 256, 0, stream>>>(WGI, WGHN, WhH, WhL, WL, t);
  }
  ln_rows<<<TROWS, 256, 0, stream>>>(WL, WL, patch_g, patch_b);
  mean_pool_p<<<EW, 256, 0, stream>>>(WL, pAH, pAL);
  G3(pAH, pAL, 512, T_SUMM, summ_b, nullptr, 0, WhH, WhL, 512, F_WR_PAIR, 4, 64);

  // ---- rounds ----
  for (int rnd = 0; rnd < 6; ++rnd) {
    G3(WhH, WhL, 512, T_MSG1A, msg_b1, WV, 512, nullptr, nullptr, 0, F_WR_F32, 4, 64);
    G3(WhH, WhL, 512, T_MSG1B, nullptr, WGI, 512, nullptr, nullptr, 0, F_WR_F32, 4, 64);
    msg_gelu_p<<<EW, 256, 0, stream>>>(WV, WGI, pBH, pBL);
    G3(pBH, pBL, 512, T_MSG2, msg_b2, nullptr, 0, MsH, MsL, 512, F_WR_PAIR, 4, 64);
    G3(WhH, WhL, 512, T_QW, q_b, WGI, 512, nullptr, nullptr, 0, F_WR_F32, 4, 64);
    rotary_p<<<ROWS, 256, 0, stream>>>(WGI, pAH, pAL);
    G3(WhH, WhL, 512, T_KW, k_b, WGI, 512, nullptr, nullptr, 0, F_WR_F32, 4, 64);
    rotary_p<<<ROWS, 256, 0, stream>>>(WGI, pBH, pBL);
    G3(WhH, WhL, 512, T_VW, v_b, WV, 512, nullptr, nullptr, 0, F_WR_F32, 4, 64);
    // scores (lower-triangular tiles only)
    gemm_bf3<<<dim3(36, 1, CB), 256, 0, stream>>>(
        pAH, pAL, 512, pBH, pBL, 512, nullptr, inv_sqrt_d,
        WGI, CN, nullptr, nullptr, 0, 512, F_WR_F32 | F_TRI,
        (long long)CN * CD, (long long)CN * CD, (long long)CN * CN);
    topk_softmax2<<<ROWS, 256, 0, stream>>>(WGI, Wprob, Widx);
    topk_gather_p<<<ROWS, 128, 0, stream>>>(Wprob, Widx, WV, pAH, pAL);
    G3(pAH, pAL, 512, T_OW, o_b, nullptr, 0, pBH, pBL, 512, F_WR_PAIR, 4, 64);
    G3(MsH, MsL, 512, T_GC_TOP, gc_b_ih, WGI, 1536, nullptr, nullptr, 0, F_WR_F32, 12, 64);
    G3(pBH, pBL, 512, T_GC_BOT, nullptr, WGI, 1536, nullptr, nullptr, 0,
       F_ACC_F32 | F_WR_F32, 12, 64);
    G3(WhH, WhL, 512, T_GC_HH, gc_b_hh, WGI, 1536, nullptr, nullptr, 0,
       F_ACC_F32 | F_WR_F32, 8, 64);
    G3(WhH, WhL, 512, T_GC_HH + (size_t)1024 * 512, gc_b_hh + 1024, WGHN, 512,
       nullptr, nullptr, 0, F_WR_F32, 4, 64);
    gru_ln_p<<<ROWS, 256, 0, stream>>>(WGI, WGHN, WhH, WhL, msg_ln_g, msg_ln_b);
    if ((rnd & 1) == 1) {
      ln_pp<<<ROWS, 256, 0, stream>>>(WhH, WhL, pAH, pAL, ar_ln_g, ar_ln_b);
      G3(pAH, pAL, 512, T_AR_QKV, ar_qkv_b, nullptr, 0, QkH, QkL, 1536, F_WR_PAIR, 12, 64);
      flash_attn_p<<<dim3(16, CH, CB), 256, 0, stream>>>(QkH, QkL, pBH, pBL);
      G3(pBH, pBL, 512, T_AR_OUT, ar_out_b, nullptr, 0, WhH, WhL, 512,
         F_ACC_PAIR | F_WR_PAIR, 4, 64);
    }
  }

  // ---- head ----
  G3(WhH, WhL, 512, T_BROAD, broad_b, WV, 512, nullptr, nullptr, 0, F_WR_F32, 4, 64);
  final_ln_p<<<TROWS, 256, 0, stream>>>(WL, WV, ln_g, ln_b, FnH, FnL);
  G3(FnH, FnL, 512, T_HEAD, nullptr, out, CV, nullptr, nullptr, 0, F_WR_F32, 2, 256);
}

// Round 6
// 5075.305 us; speedup vs baseline: 4.0860x; 1.0900x over previous
//
#include <hip/hip_runtime.h>
#include <math.h>

// ---------------- problem constants ----------------
constexpr int CB = 8, CT = 4096, CP = 4, CD = 512, CV = 256;
constexpr int CN = 1024, CK = 16, CH = 8, CHD = 64;
constexpr int ROWS = CB * CN;     // 8192
constexpr int TROWS = CB * CT;    // 32768
constexpr float CEPS = 1e-5f;
constexpr size_t PN = (size_t)ROWS * CD;   // 4,194,304 (one pair-plane)

// ---------------- workspace layout (floats) ----------------
constexpr size_t OFF_LOCAL = 0;                                    // 16,777,216 fp32 local
constexpr size_t OFF_HP    = OFF_LOCAL + (size_t)ROWS * CP * CD;   //  4,194,304 h pair
constexpr size_t OFF_X4    = OFF_HP    + PN;                       // 16,777,216 fused4/scores/gi+ghn/arqkv/final
constexpr size_t OFF_V     = OFF_X4    + (size_t)ROWS * 2048;      //  4,194,304 v fp32 / broad
constexpr size_t OFF_MS    = OFF_V     + PN;                       //  4,194,304 msgs pair
constexpr size_t OFF_A     = OFF_MS    + PN;                       //  4,194,304 pair A
constexpr size_t OFF_B     = OFF_A     + PN;                       //  4,194,304 pair B
constexpr size_t OFF_PROB  = OFF_B     + PN;                       //    131,072
constexpr size_t OFF_IDX   = OFF_PROB  + (size_t)ROWS * CK;        //    131,072
constexpr size_t OFF_BIAS  = OFF_IDX   + (size_t)ROWS * CK;        //      4,096
constexpr size_t OFF_WT    = OFF_BIAS  + 4096;                     //  7,471,104
// end = 62,263,296 floats = 237.5 MiB (< 241 MiB proven in R1)

constexpr size_t TOT_W    = 7471104;
constexpr size_t T_GRU_IH = 0;                     // 1536x512
constexpr size_t T_GRU_HH = 786432;                // 1536x512
constexpr size_t T_SUMM   = 1572864;               // 512x512
constexpr size_t T_FUSE   = 1835008;               // 2048x512 (msg1a|msg1b|qw|kw)
constexpr size_t T_MSG2   = 2883584;               // 512x512
constexpr size_t T_VW     = 3145728;               // 512x512
constexpr size_t T_OW     = 3407872;               // 512x512
constexpr size_t T_GCAB   = 3670016;               // 1536x1024 ([gc_top|gc_bot] along K)
constexpr size_t T_GC_HH  = 5242880;               // 1536x512
constexpr size_t T_AR_QKV = 6029312;               // 1536x512
constexpr size_t T_AR_OUT = 6815744;               // 512x512
constexpr size_t T_BROAD  = 7077888;               // 512x512
constexpr size_t T_HEAD   = 7340032;               // 256x512

// GEMM flags
constexpr int F_ACC_F32  = 1;
constexpr int F_ACC_PAIR = 2;
constexpr int F_WR_F32   = 4;
constexpr int F_WR_PAIR  = 8;
constexpr int F_TRI      = 16;

// ---------------- device helpers ----------------
typedef __attribute__((ext_vector_type(8))) short short8;
typedef __attribute__((ext_vector_type(4))) float f32x4;

__device__ __forceinline__ float sigm(float x) { return 1.f / (1.f + expf(-x)); }
__device__ __forceinline__ float geluf(float x) {
  return 0.5f * x * (1.f + erff(x * 0.7071067811865475f));
}
__device__ __forceinline__ unsigned short bf_hi(float x) {
  const unsigned u = __float_as_uint(x);
  return (unsigned short)((u + 0x7FFFu + ((u >> 16) & 1u)) >> 16);
}
__device__ __forceinline__ float bf_f(unsigned short h) {
  return __uint_as_float((unsigned)h << 16);
}
__device__ __forceinline__ void split_store(float v, unsigned short* ph, unsigned short* pl) {
  const unsigned short h = bf_hi(v);
  *ph = h; *pl = bf_hi(v - bf_f(h));
}
__device__ __forceinline__ float blk_sum(float v, float* red) {
#pragma unroll
  for (int o = 32; o > 0; o >>= 1) v += __shfl_down(v, o, 64);
  const int wv = threadIdx.x >> 6, ln = threadIdx.x & 63;
  __syncthreads();
  if (ln == 0) red[wv] = v;
  __syncthreads();
  return red[0] + red[1] + red[2] + red[3];
}

// ---------------- transpose + bf16 split (weights) ----------------
// out[(n)*ldk + ko + k] = in[k][n];  in is [K][N]
__global__ __launch_bounds__(256) void transpose_split(const float* __restrict__ in,
                                                       unsigned short* __restrict__ oh,
                                                       unsigned short* __restrict__ ol,
                                                       int K, int N, int ldk, int ko)
{
  __shared__ float tile[32][33];
  const int n0 = blockIdx.x * 32, k0 = blockIdx.y * 32;
  const int tx = threadIdx.x & 31, ty = threadIdx.x >> 5;
#pragma unroll
  for (int i = 0; i < 32; i += 8)
    tile[ty + i][tx] = in[(size_t)(k0 + ty + i) * N + n0 + tx];
  __syncthreads();
#pragma unroll
  for (int i = 0; i < 32; i += 8) {
    const float v = tile[tx][ty + i];
    const unsigned short h = bf_hi(v);
    const size_t o = (size_t)(n0 + ty + i) * ldk + ko + k0 + tx;
    oh[o] = h;
    ol[o] = bf_hi(v - bf_f(h));
  }
}

__global__ void concat_bias(const float* __restrict__ b1, const float* __restrict__ qb,
                            const float* __restrict__ kb, float* __restrict__ o)
{
  const int i = blockIdx.x * 256 + threadIdx.x;   // 2048
  float v;
  if (i < 512) v = b1[i];
  else if (i < 1024) v = 0.f;
  else if (i < 1536) v = qb[i - 1024];
  else v = kb[i - 1536];
  o[i] = v;
}

// ---------------- unified 3-product bf16 MFMA GEMM, pre-split operands ----
// C[M,N] = scale*([A1|A2]@Bt^T) + bias (+C). A cols <K1 from A1, else A2.
__global__ __launch_bounds__(256, 2) void gemm_bf3(
    const unsigned short* __restrict__ AH, const unsigned short* __restrict__ AL,
    const unsigned short* __restrict__ A2H, const unsigned short* __restrict__ A2L,
    int K1, int lda,
    const unsigned short* __restrict__ BH, const unsigned short* __restrict__ BL, int ldb,
    const float* __restrict__ bias, float scale,
    float* __restrict__ Cf, int ldc,
    unsigned short* __restrict__ CHp, unsigned short* __restrict__ CLp, int ldcp,
    int K, int flags, long long sA, long long sB, long long sC)
{
  AH += (size_t)blockIdx.z * sA; AL += (size_t)blockIdx.z * sA;
  BH += (size_t)blockIdx.z * sB; BL += (size_t)blockIdx.z * sB;
  if (Cf) Cf += (size_t)blockIdx.z * sC;
  int bm, bn;
  if (flags & F_TRI) {
    int t = blockIdx.x, i = 0, acc = 0;
    while (acc + i + 1 <= t) { ++i; acc += i; }
    bm = i << 7; bn = (t - acc) << 7;
  } else {
    bm = blockIdx.y << 7; bn = blockIdx.x << 7;
  }
  __shared__ __align__(16) unsigned short AsH[128][40];
  __shared__ __align__(16) unsigned short AsL[128][40];
  __shared__ __align__(16) unsigned short BsH[128][40];
  __shared__ __align__(16) unsigned short BsL[128][40];
  const int tid = threadIdx.x;
  const int lane = tid & 63, wave = tid >> 6;
  const int wm = (wave & 1) << 6, wn = (wave >> 1) << 6;
  const int r16 = lane & 15, quad = lane >> 4;
  const int sr = tid >> 1, sc = (tid & 1) << 4;
  const f32x4 zero = {0.f, 0.f, 0.f, 0.f};
  f32x4 acc[4][4];
#pragma unroll
  for (int i = 0; i < 4; ++i)
#pragma unroll
    for (int j = 0; j < 4; ++j) acc[i][j] = zero;

  for (int k0 = 0; k0 < K; k0 += 32) {
    const int kc = k0 + sc;
    const unsigned short *pAH, *pAL;
    if (kc < K1) {
      pAH = AH + (size_t)(bm + sr) * lda + kc;
      pAL = AL + (size_t)(bm + sr) * lda + kc;
    } else {
      pAH = A2H + (size_t)(bm + sr) * lda + (kc - K1);
      pAL = A2L + (size_t)(bm + sr) * lda + (kc - K1);
    }
    const unsigned short* pBH = BH + (size_t)(bn + sr) * ldb + kc;
    const unsigned short* pBL = BL + (size_t)(bn + sr) * ldb + kc;
    *(uint4*)&AsH[sr][sc]     = *(const uint4*)pAH;
    *(uint4*)&AsH[sr][sc + 8] = *(const uint4*)(pAH + 8);
    *(uint4*)&AsL[sr][sc]     = *(const uint4*)pAL;
    *(uint4*)&AsL[sr][sc + 8] = *(const uint4*)(pAL + 8);
    *(uint4*)&BsH[sr][sc]     = *(const uint4*)pBH;
    *(uint4*)&BsH[sr][sc + 8] = *(const uint4*)(pBH + 8);
    *(uint4*)&BsL[sr][sc]     = *(const uint4*)pBL;
    *(uint4*)&BsL[sr][sc + 8] = *(const uint4*)(pBL + 8);
    __syncthreads();
    short8 bh[4], bl[4];
#pragma unroll
    for (int ni = 0; ni < 4; ++ni) {
      bh[ni] = *(const short8*)&BsH[wn + ni * 16 + r16][quad * 8];
      bl[ni] = *(const short8*)&BsL[wn + ni * 16 + r16][quad * 8];
    }
#pragma unroll
    for (int mi = 0; mi < 4; ++mi) {
      const short8 ah = *(const short8*)&AsH[wm + mi * 16 + r16][quad * 8];
      const short8 al = *(const short8*)&AsL[wm + mi * 16 + r16][quad * 8];
#pragma unroll
      for (int ni = 0; ni < 4; ++ni) {
        acc[mi][ni] = __builtin_amdgcn_mfma_f32_16x16x32_bf16(ah, bh[ni], acc[mi][ni], 0, 0, 0);
        acc[mi][ni] = __builtin_amdgcn_mfma_f32_16x16x32_bf16(ah, bl[ni], acc[mi][ni], 0, 0, 0);
        acc[mi][ni] = __builtin_amdgcn_mfma_f32_16x16x32_bf16(al, bh[ni], acc[mi][ni], 0, 0, 0);
      }
    }
    __syncthreads();
  }
#pragma unroll
  for (int mi = 0; mi < 4; ++mi) {
    const int row0 = bm + wm + mi * 16 + quad * 4;
#pragma unroll
    for (int ni = 0; ni < 4; ++ni) {
      const int col = bn + wn + ni * 16 + r16;
      const float bv = bias ? bias[col] : 0.f;
#pragma unroll
      for (int rg = 0; rg < 4; ++rg) {
        const int row = row0 + rg;
        float o = acc[mi][ni][rg] * scale + bv;
        if (flags & F_ACC_F32) o += Cf[(size_t)row * ldc + col];
        if (flags & F_ACC_PAIR) {
          const size_t ip = (size_t)row * ldcp + col;
          o += bf_f(CHp[ip]) + bf_f(CLp[ip]);
        }
        if (flags & F_WR_F32) Cf[(size_t)row * ldc + col] = o;
        if (flags & F_WR_PAIR) {
          const size_t ip = (size_t)row * ldcp + col;
          split_store(o, &CHp[ip], &CLp[ip]);
        }
      }
    }
  }
}

// ---------------- small kernels ----------------
__global__ void zero_k(float* __restrict__ p) {
  p[(size_t)blockIdx.x * 256 + threadIdx.x] = 0.f;
}

__global__ void embed_p(const int* __restrict__ x, const float* __restrict__ emb,
                        const float* __restrict__ pos,
                        unsigned short* __restrict__ oh, unsigned short* __restrict__ ol, int t)
{
  const int i = blockIdx.x * 256 + threadIdx.x;
  const int r = i >> 9, d = i & 511;
  const int b = r >> 10, n = r & (CN - 1);
  const int tok = x[b * CT + n * CP + t];
  const float v = emb[(size_t)tok * CD + d] + pos[t * CD + d];
  split_store(v, &oh[i], &ol[i]);
}

__global__ void gru_point_p(const float* __restrict__ gi, const float* __restrict__ ghn,
                            unsigned short* __restrict__ hH, unsigned short* __restrict__ hL,
                            float* __restrict__ hs, int t)
{
  const int i = blockIdx.x * 256 + threadIdx.x;
  const int r = i >> 9, d = i & 511;
  const size_t gb = (size_t)r * (3 * CD) + d;
  const float sr_ = gi[gb], sz = gi[gb + CD], inn = gi[gb + 2 * CD];
  const float hn = ghn[i];
  const float hp = bf_f(hH[i]) + bf_f(hL[i]);
  const float rr = sigm(sr_), zz = sigm(sz);
  const float nn = tanhf(inn + rr * hn);
  const float hv = (1.f - zz) * nn + zz * hp;
  split_store(hv, &hH[i], &hL[i]);
  hs[(size_t)r * (CP * CD) + (size_t)t * CD + d] = hv;
}

__global__ __launch_bounds__(256) void ln_rows(const float* __restrict__ in, float* __restrict__ out,
                                               const float* __restrict__ g, const float* __restrict__ b)
{
  const int r = blockIdx.x, t = threadIdx.x;
  __shared__ float red[4];
  const float* ip = in + (size_t)r * CD;
  const float v0 = ip[t], v1 = ip[t + 256];
  const float mu = blk_sum(v0 + v1, red) * (1.f / CD);
  const float d0 = v0 - mu, d1 = v1 - mu;
  const float var = blk_sum(d0 * d0 + d1 * d1, red) * (1.f / CD);
  const float inv = rsqrtf(var + CEPS);
  float* op = out + (size_t)r * CD;
  op[t] = d0 * inv * g[t] + b[t];
  op[t + 256] = d1 * inv * g[t + 256] + b[t + 256];
}

__global__ __launch_bounds__(256) void ln_pp(const unsigned short* __restrict__ inH,
                                             const unsigned short* __restrict__ inL,
                                             unsigned short* __restrict__ oh, unsigned short* __restrict__ ol,
                                             const float* __restrict__ g, const float* __restrict__ b)
{
  const int r = blockIdx.x, t = threadIdx.x;
  __shared__ float red[4];
  const size_t i0 = (size_t)r * CD + t, i1 = i0 + 256;
  const float v0 = bf_f(inH[i0]) + bf_f(inL[i0]);
  const float v1 = bf_f(inH[i1]) + bf_f(inL[i1]);
  const float mu = blk_sum(v0 + v1, red) * (1.f / CD);
  const float d0 = v0 - mu, d1 = v1 - mu;
  const float var = blk_sum(d0 * d0 + d1 * d1, red) * (1.f / CD);
  const float inv = rsqrtf(var + CEPS);
  split_store(d0 * inv * g[t] + b[t], &oh[i0], &ol[i0]);
  split_store(d1 * inv * g[t + 256] + b[t + 256], &oh[i1], &ol[i1]);
}

__global__ void mean_pool_p(const float* __restrict__ local,
                            unsigned short* __restrict__ oh, unsigned short* __restrict__ ol)
{
  const int i = blockIdx.x * 256 + threadIdx.x;
  const int r = i >> 9, d = i & 511;
  const float* p = local + (size_t)r * (CP * CD) + d;
  split_store(0.25f * (p[0] + p[CD] + p[2 * CD] + p[3 * CD]), &oh[i], &ol[i]);
}

// reads pre/nb from X4 (stride 2048, nb at col offset 512)
__global__ void msg_gelu_p(const float* __restrict__ X4,
                           unsigned short* __restrict__ oh, unsigned short* __restrict__ ol)
{
  const int i = blockIdx.x * 256 + threadIdx.x;
  const int r = i >> 9, d = i & 511;
  const int n = r & (CN - 1);
  const float pv = X4[(size_t)r * 2048 + d];
  float acc = 0.f;
#pragma unroll
  for (int w = 0; w <= 4; ++w) {
    const float xv = pv + ((n >= w) ? X4[(size_t)(r - w) * 2048 + 512 + d] : 0.f);
    acc += geluf(xv);
  }
  split_store(acc * 0.2f, &oh[i], &ol[i]);
}

// rotary from X4 strided input (row stride 2048)
__global__ void rotary_p(const float* __restrict__ in,
                         unsigned short* __restrict__ oh, unsigned short* __restrict__ ol)
{
  const int i = blockIdx.x * 256 + threadIdx.x;   // ROWS*256
  const int r = i >> 8, j = i & 255;
  const int n = r & (CN - 1);
  const float fr = (float)n * expf(-9.210340371976184f * ((float)j * (1.f / 256.f)));
  float s, c;
  sincosf(fr, &s, &c);
  const float* p = in + (size_t)r * 2048;
  const float t1 = p[j], t2 = p[j + 256];
  const size_t o0 = (size_t)r * CD + j, o1 = o0 + 256;
  split_store(t1 * c - t2 * s, &oh[o0], &ol[o0]);
  split_store(t2 * c + t1 * s, &oh[o1], &ol[o1]);
}

// ---------------- top-K ----------------
__global__ __launch_bounds__(256) void topk_softmax2(const float* __restrict__ scores,
                                                     float* __restrict__ probs, int* __restrict__ idxs)
{
  const int rrow = blockIdx.x;
  const int b = rrow >> 10, n = rrow & (CN - 1);
  const float* row = scores + ((size_t)b * CN + n) * CN;
  __shared__ float sv[CN];
  __shared__ unsigned long long wred[4];
  __shared__ float topv[CK];
  __shared__ int topi[CK];
  const int tid = threadIdx.x;
#pragma unroll
  for (int q = 0; q < 4; ++q) {
    const int m = tid + q * 256;
    sv[m] = (m <= n) ? row[m] : -INFINITY;
  }
  __syncthreads();
  for (int it = 0; it < CK; ++it) {
    unsigned long long best = 0ull;
#pragma unroll
    for (int q = 0; q < 4; ++q) {
      const int m = tid + q * 256;
      unsigned u = __float_as_uint(sv[m]);
      u = (u & 0x80000000u) ? ~u : (u | 0x80000000u);
      const unsigned long long key = ((unsigned long long)u << 32) | (unsigned)(CN - 1 - m);
      best = best > key ? best : key;
    }
#pragma unroll
    for (int o = 32; o > 0; o >>= 1) {
      const unsigned long long o2 = __shfl_down(best, o, 64);
      best = best > o2 ? best : o2;
    }
    if ((tid & 63) == 0) wred[tid >> 6] = best;
    __syncthreads();
    if (tid == 0) {
      unsigned long long b0 = wred[0];
      for (int w = 1; w < 4; ++w) b0 = b0 > wred[w] ? b0 : wred[w];
      const int m = CN - 1 - (int)(b0 & 0xFFFFFFFFu);
      unsigned u = (unsigned)(b0 >> 32);
      u = (u & 0x80000000u) ? (u & 0x7FFFFFFFu) : ~u;
      topv[it] = __uint_as_float(u);
      topi[it] = m;
      sv[m] = -INFINITY;
    }
    __syncthreads();
  }
  if (tid < CK) {
    const float mx = topv[0];
    float sum = 0.f;
#pragma unroll
    for (int q = 0; q < CK; ++q)
      sum += (topv[q] == -INFINITY) ? 0.f : expf(topv[q] - mx);
    const float e = (topv[tid] == -INFINITY) ? 0.f : expf(topv[tid] - mx);
    probs[(size_t)rrow * CK + tid] = e / sum;
    idxs[(size_t)rrow * CK + tid] = topi[tid];
  }
}

__global__ __launch_bounds__(128) void topk_gather_p(const float* __restrict__ probs,
                                                     const int* __restrict__ idxs,
                                                     const float* __restrict__ v,
                                                     unsigned short* __restrict__ oh,
                                                     unsigned short* __restrict__ ol)
{
  const int r = blockIdx.x;
  const int b = r >> 10;
  __shared__ float p[CK];
  __shared__ int id[CK];
  if (threadIdx.x < CK) {
    p[threadIdx.x] = probs[(size_t)r * CK + threadIdx.x];
    id[threadIdx.x] = idxs[(size_t)r * CK + threadIdx.x];
  }
  __syncthreads();
  for (int d = threadIdx.x; d < CD; d += 128) {
    float a = 0.f;
#pragma unroll
    for (int q = 0; q < CK; ++q)
      a += p[q] * v[((size_t)(b << 10) + id[q]) * CD + d];
    split_store(a, &oh[(size_t)r * CD + d], &ol[(size_t)r * CD + d]);
  }
}

__global__ __launch_bounds__(256) void gru_ln_p(const float* __restrict__ gi, const float* __restrict__ ghn,
                                                unsigned short* __restrict__ hH, unsigned short* __restrict__ hL,
                                                const float* __restrict__ g, const float* __restrict__ b)
{
  const int r = blockIdx.x, t = threadIdx.x;
  __shared__ float red[4];
  float u[2];
#pragma unroll
  for (int q = 0; q < 2; ++q) {
    const int d = t + q * 256;
    const size_t gb = (size_t)r * (3 * CD) + d;
    const float sr_ = gi[gb], sz = gi[gb + CD], inn = gi[gb + 2 * CD];
    const float hn = ghn[(size_t)r * CD + d];
    const size_t hi = (size_t)r * CD + d;
    const float hp = bf_f(hH[hi]) + bf_f(hL[hi]);
    const float rr = sigm(sr_), zz = sigm(sz);
    const float nn = tanhf(inn + rr * hn);
    u[q] = (1.f - zz) * nn + zz * hp;
  }
  const float mu = blk_sum(u[0] + u[1], red) * (1.f / CD);
  const float d0 = u[0] - mu, d1 = u[1] - mu;
  const float var = blk_sum(d0 * d0 + d1 * d1, red) * (1.f / CD);
  const float inv = rsqrtf(var + CEPS);
  split_store(d0 * inv * g[t] + b[t], &hH[(size_t)r * CD + t], &hL[(size_t)r * CD + t]);
  split_store(d1 * inv * g[t + 256] + b[t + 256],
              &hH[(size_t)r * CD + t + 256], &hL[(size_t)r * CD + t + 256]);
}

// ---------------- MFMA flash attention, pair I/O ----------------
// FP=88 (44 words/row): r*44 mod 32 = 12r -> distinct starts over r=0..7, ~2-way.
constexpr int FP = 88;
__global__ __launch_bounds__(256, 2) void flash_attn_p(const unsigned short* __restrict__ qkvH,
                                                       const unsigned short* __restrict__ qkvL,
                                                       unsigned short* __restrict__ outH,
                                                       unsigned short* __restrict__ outL)
{
  __shared__ __align__(16) unsigned short Qh[64 * FP], Ql[64 * FP];
  __shared__ __align__(16) unsigned short Kh[64 * FP], Kl[64 * FP];
  __shared__ __align__(16) unsigned short Vth[64 * FP], Vtl[64 * FP];
  __shared__ __align__(16) unsigned short Pm[64 * FP];
  const int qt = blockIdx.x, head = blockIdx.y, b = blockIdx.z;
  const int tid = threadIdx.x;
  const int lane = tid & 63, wave = tid >> 6;
  const int r16 = lane & 15, quad = lane >> 4;
  const size_t base = (size_t)b * CN * (3 * CD) + head * CHD;

  {
    const int r = tid >> 2, c0 = (tid & 3) << 4;
    const unsigned short* qh = qkvH + base + (size_t)(qt * 64 + r) * (3 * CD) + c0;
    const unsigned short* ql = qkvL + base + (size_t)(qt * 64 + r) * (3 * CD) + c0;
    *(uint4*)&Qh[r * FP + c0]     = *(const uint4*)qh;
    *(uint4*)&Qh[r * FP + c0 + 8] = *(const uint4*)(qh + 8);
    *(uint4*)&Ql[r * FP + c0]     = *(const uint4*)ql;
    *(uint4*)&Ql[r * FP + c0 + 8] = *(const uint4*)(ql + 8);
  }
  float m_i[4], l_i[4];
  f32x4 O[4];
  const f32x4 zero = {0.f, 0.f, 0.f, 0.f};
#pragma unroll
  for (int r = 0; r < 4; ++r) { m_i[r] = -INFINITY; l_i[r] = 0.f; }
#pragma unroll
  for (int d = 0; d < 4; ++d) O[d] = zero;

  for (int j = 0; j <= qt; ++j) {
    __syncthreads();
    {
      const int r = tid >> 2, c0 = (tid & 3) << 4;
      const unsigned short* kh = qkvH + base + (size_t)(j * 64 + r) * (3 * CD) + CD + c0;
      const unsigned short* kl = qkvL + base + (size_t)(j * 64 + r) * (3 * CD) + CD + c0;
      *(uint4*)&Kh[r * FP + c0]     = *(const uint4*)kh;
      *(uint4*)&Kh[r * FP + c0 + 8] = *(const uint4*)(kh + 8);
      *(uint4*)&Kl[r * FP + c0]     = *(const uint4*)kl;
      *(uint4*)&Kl[r * FP + c0 + 8] = *(const uint4*)(kl + 8);
      const int rp = (tid >> 3) << 1, c0v = (tid & 7) << 3;
      const unsigned short* v0h = qkvH + base + (size_t)(j * 64 + rp) * (3 * CD) + 2 * CD + c0v;
      const unsigned short* v1h = v0h + 3 * CD;
      const unsigned short* v0l = qkvL + base + (size_t)(j * 64 + rp) * (3 * CD) + 2 * CD + c0v;
      const unsigned short* v1l = v0l + 3 * CD;
      unsigned short xh[8], yh[8], xl[8], yl[8];
      *(uint4*)xh = *(const uint4*)v0h; *(uint4*)yh = *(const uint4*)v1h;
      *(uint4*)xl = *(const uint4*)v0l; *(uint4*)yl = *(const uint4*)v1l;
#pragma unroll
      for (int c = 0; c < 8; ++c) {
        const int R = c0v + c;
        const int col = rp ^ ((R >> 3) << 3);
        *(unsigned*)&Vth[R * FP + col] = (unsigned)xh[c] | ((unsigned)yh[c] << 16);
        *(unsigned*)&Vtl[R * FP + col] = (unsigned)xl[c] | ((unsigned)yl[c] << 16);
      }
    }
    __syncthreads();
    f32x4 S[4];
#pragma unroll
    for (int nt = 0; nt < 4; ++nt) S[nt] = zero;
#pragma unroll
    for (int kh2 = 0; kh2 < 2; ++kh2) {
      const short8 qh = *(const short8*)&Qh[(wave * 16 + r16) * FP + kh2 * 32 + quad * 8];
      const short8 ql = *(const short8*)&Ql[(wave * 16 + r16) * FP + kh2 * 32 + quad * 8];
#pragma unroll
      for (int nt = 0; nt < 4; ++nt) {
        const short8 kkh = *(const short8*)&Kh[(nt * 16 + r16) * FP + kh2 * 32 + quad * 8];
        const short8 kkl = *(const short8*)&Kl[(nt * 16 + r16) * FP + kh2 * 32 + quad * 8];
        S[nt] = __builtin_amdgcn_mfma_f32_16x16x32_bf16(qh, kkh, S[nt], 0, 0, 0);
        S[nt] = __builtin_amdgcn_mfma_f32_16x16x32_bf16(qh, kkl, S[nt], 0, 0, 0);
        S[nt] = __builtin_amdgcn_mfma_f32_16x16x32_bf16(ql, kkh, S[nt], 0, 0, 0);
      }
    }
#pragma unroll
    for (int r = 0; r < 4; ++r) {
      const int qrow = wave * 16 + quad * 4 + r;
      float s[4];
#pragma unroll
      for (int nt = 0; nt < 4; ++nt) {
        s[nt] = S[nt][r] * 0.125f;
        if (j == qt && (nt * 16 + r16) > qrow) s[nt] = -1e30f;
      }
      float rm = fmaxf(fmaxf(s[0], s[1]), fmaxf(s[2], s[3]));
#pragma unroll
      for (int o = 8; o > 0; o >>= 1) rm = fmaxf(rm, __shfl_xor(rm, o, 64));
      const float newm = fmaxf(m_i[r], rm);
      float p[4], rs = 0.f;
#pragma unroll
      for (int nt = 0; nt < 4; ++nt) { p[nt] = expf(s[nt] - newm); rs += p[nt]; }
#pragma unroll
      for (int o = 8; o > 0; o >>= 1) rs += __shfl_xor(rs, o, 64);
      const float alpha = expf(m_i[r] - newm);
      l_i[r] = l_i[r] * alpha + rs;
      m_i[r] = newm;
#pragma unroll
      for (int dt = 0; dt < 4; ++dt) O[dt][r] *= alpha;
#pragma unroll
      for (int nt = 0; nt < 4; ++nt)
        Pm[qrow * FP + nt * 16 + r16] = bf_hi(p[nt]);
    }
    __syncthreads();
#pragma unroll
    for (int kh2 = 0; kh2 < 2; ++kh2) {
      const short8 pa = *(const short8*)&Pm[(wave * 16 + r16) * FP + kh2 * 32 + quad * 8];
#pragma unroll
      for (int dt = 0; dt < 4; ++dt) {
        const int R = dt * 16 + r16;
        const int col = (kh2 * 32 + quad * 8) ^ ((R >> 3) << 3);
        const short8 vh = *(const short8*)&Vth[R * FP + col];
        const short8 vl = *(const short8*)&Vtl[R * FP + col];
        O[dt] = __builtin_amdgcn_mfma_f32_16x16x32_bf16(pa, vh, O[dt], 0, 0, 0);
        O[dt] = __builtin_amdgcn_mfma_f32_16x16x32_bf16(pa, vl, O[dt], 0, 0, 0);
      }
    }
  }
#pragma unroll
  for (int r = 0; r < 4; ++r) {
    const float inv = 1.f / l_i[r];
    const size_t row = (size_t)b * CN + qt * 64 + wave * 16 + quad * 4 + r;
#pragma unroll
    for (int dt = 0; dt < 4; ++dt) {
      const size_t o = row * CD + head * CHD + dt * 16 + r16;
      split_store(O[dt][r] * inv, &outH[o], &outL[o]);
    }
  }
}

__global__ __launch_bounds__(256) void final_ln_p(const float* __restrict__ local,
                                                  const float* __restrict__ broad,
                                                  const float* __restrict__ g, const float* __restrict__ bb,
                                                  unsigned short* __restrict__ oh,
                                                  unsigned short* __restrict__ ol)
{
  const int r = blockIdx.x, t = threadIdx.x;
  __shared__ float red[4];
  const size_t lb = (size_t)r * CD;
  const size_t br = (size_t)(r >> 2) * CD;
  const float v0 = local[lb + t] + broad[br + t];
  const float v1 = local[lb + 256 + t] + broad[br + 256 + t];
  const float mu = blk_sum(v0 + v1, red) * (1.f / CD);
  const float d0 = v0 - mu, d1 = v1 - mu;
  const float var = blk_sum(d0 * d0 + d1 * d1, red) * (1.f / CD);
  const float inv = rsqrtf(var + CEPS);
  split_store(d0 * inv * g[t] + bb[t], &oh[lb + t], &ol[lb + t]);
  split_store(d1 * inv * g[t + 256] + bb[t + 256], &oh[lb + 256 + t], &ol[lb + 256 + t]);
}

// ---------------- launcher ----------------
extern "C" void kernel_launch(void* const* d_in, const int* in_sizes, int n_in,
                              void* d_out, int out_size, void* d_ws, size_t ws_size,
                              hipStream_t stream)
{
  (void)in_sizes; (void)n_in; (void)out_size; (void)ws_size;
  const int*   x         = (const int*)d_in[0];
  const float* emb       = (const float*)d_in[1];
  const float* pos_emb   = (const float*)d_in[2];
  const float* gru_w_ih  = (const float*)d_in[3];
  const float* gru_w_hh  = (const float*)d_in[4];
  const float* gru_b_ih  = (const float*)d_in[5];
  const float* gru_b_hh  = (const float*)d_in[6];
  const float* patch_g   = (const float*)d_in[7];
  const float* patch_b   = (const float*)d_in[8];
  const float* summ_w    = (const float*)d_in[9];
  const float* summ_b    = (const float*)d_in[10];
  const float* msg_w1    = (const float*)d_in[11];
  const float* msg_b1    = (const float*)d_in[12];
  const float* msg_w2    = (const float*)d_in[13];
  const float* msg_b2    = (const float*)d_in[14];
  const float* msg_ln_g  = (const float*)d_in[15];
  const float* msg_ln_b  = (const float*)d_in[16];
  const float* q_w       = (const float*)d_in[17];
  const float* q_b       = (const float*)d_in[18];
  const float* k_w       = (const float*)d_in[19];
  const float* k_b       = (const float*)d_in[20];
  const float* v_w       = (const float*)d_in[21];
  const float* v_b       = (const float*)d_in[22];
  const float* o_w       = (const float*)d_in[23];
  const float* o_b       = (const float*)d_in[24];
  const float* gc_w_ih   = (const float*)d_in[25];
  const float* gc_w_hh   = (const float*)d_in[26];
  const float* gc_b_ih   = (const float*)d_in[27];
  const float* gc_b_hh   = (const float*)d_in[28];
  const float* ar_ln_g   = (const float*)d_in[29];
  const float* ar_ln_b   = (const float*)d_in[30];
  const float* ar_qkv_w  = (const float*)d_in[31];
  const float* ar_qkv_b  = (const float*)d_in[32];
  const float* ar_out_w  = (const float*)d_in[33];
  const float* ar_out_b  = (const float*)d_in[34];
  const float* broad_w   = (const float*)d_in[35];
  const float* broad_b   = (const float*)d_in[36];
  const float* ln_g      = (const float*)d_in[37];
  const float* ln_b      = (const float*)d_in[38];
  const float* head_w    = (const float*)d_in[39];
  float* out = (float*)d_out;

  float* ws = (float*)d_ws;
  float* WL    = ws + OFF_LOCAL;
  float* X4    = ws + OFF_X4;
  float* GI    = X4;                               // 8192x1536 fp32
  float* GHN   = X4 + (size_t)ROWS * 1536;         // 8192x512 fp32
  float* WV    = ws + OFF_V;
  float* Wprob = ws + OFF_PROB;
  int*   Widx  = (int*)(ws + OFF_IDX);
  float* Wbias4 = ws + OFF_BIAS;
  unsigned short* WTh = (unsigned short*)(ws + OFF_WT);
  unsigned short* WTl = WTh + TOT_W;
  unsigned short* WhH = (unsigned short*)(ws + OFF_HP);
  unsigned short* WhL = WhH + PN;
  unsigned short* MsH = (unsigned short*)(ws + OFF_MS);
  unsigned short* MsL = MsH + PN;
  unsigned short* pAH = (unsigned short*)(ws + OFF_A);
  unsigned short* pAL = pAH + PN;
  unsigned short* pBH = (unsigned short*)(ws + OFF_B);
  unsigned short* pBL = pBH + PN;
  unsigned short* QkH = (unsigned short*)X4;
  unsigned short* QkL = QkH + (size_t)ROWS * 1536;
  unsigned short* FnH = (unsigned short*)X4;
  unsigned short* FnL = FnH + (size_t)TROWS * CD;

  const int EW = ROWS * CD / 256;
  const float inv_sqrt_d = 0.04419417382415922f;   // 1/sqrt(512)

  auto TR = [&](const float* in, size_t off, int K, int N, int ldk, int ko) {
    transpose_split<<<dim3(N / 32, K / 32), 256, 0, stream>>>(in, WTh + off, WTl + off, K, N, ldk, ko);
  };
  TR(gru_w_ih, T_GRU_IH, 512, 1536, 512, 0);
  TR(gru_w_hh, T_GRU_HH, 512, 1536, 512, 0);
  TR(summ_w,   T_SUMM,   512, 512,  512, 0);
  TR(msg_w1,                      T_FUSE,          512, 512, 512, 0);
  TR(msg_w1 + (size_t)512 * 512,  T_FUSE + 262144, 512, 512, 512, 0);
  TR(q_w,                         T_FUSE + 524288, 512, 512, 512, 0);
  TR(k_w,                         T_FUSE + 786432, 512, 512, 512, 0);
  TR(msg_w2,   T_MSG2,   512, 512,  512, 0);
  TR(v_w, T_VW, 512, 512, 512, 0);
  TR(o_w, T_OW, 512, 512, 512, 0);
  TR(gc_w_ih,                       T_GCAB, 512, 1536, 1024, 0);
  TR(gc_w_ih + (size_t)512 * 1536,  T_GCAB, 512, 1536, 1024, 512);
  TR(gc_w_hh,  T_GC_HH,  512, 1536, 512, 0);
  TR(ar_qkv_w, T_AR_QKV, 512, 1536, 512, 0);
  TR(ar_out_w, T_AR_OUT, 512, 512,  512, 0);
  TR(broad_w,  T_BROAD,  512, 512,  512, 0);
  TR(head_w,   T_HEAD,   512, 256,  512, 0);
  concat_bias<<<8, 256, 0, stream>>>(msg_b1, q_b, k_b, Wbias4);

  // standard weight GEMM (A pair, single operand)
  auto G3 = [&](const unsigned short* AH_, const unsigned short* AL_, int lda_,
                size_t toff, int ldb_, const float* bias_, float* Cf_, int ldc_,
                unsigned short* CHp_, unsigned short* CLp_, int ldcp_,
                int K_, int flags_, int gx, int gy) {
    gemm_bf3<<<dim3(gx, gy), 256, 0, stream>>>(
        AH_, AL_, AH_, AL_, K_, lda_, WTh + toff, WTl + toff, ldb_, bias_, 1.f,
        Cf_, ldc_, CHp_, CLp_, ldcp_, K_, flags_, 0, 0, 0);
  };

  // ---- patch GRU over P=4 steps ----
  zero_k<<<EW, 256, 0, stream>>>(ws + OFF_HP);
  for (int t = 0; t < CP; ++t) {
    embed_p<<<EW, 256, 0, stream>>>(x, emb, pos_emb, pAH, pAL, t);
    G3(pAH, pAL, 512, T_GRU_IH, 512, gru_b_ih, GI, 1536, nullptr, nullptr, 0, 512, F_WR_F32, 12, 64);
    G3(WhH, WhL, 512, T_GRU_HH, 512, gru_b_hh, GI, 1536, nullptr, nullptr, 0, 512,
       F_ACC_F32 | F_WR_F32, 8, 64);
    G3(WhH, WhL, 512, T_GRU_HH + (size_t)1024 * 512, 512, gru_b_hh + 1024, GHN, 512,
       nullptr, nullptr, 0, 512, F_WR_F32, 4, 64);
    gru_point_p<<<EW, 256, 0, stream>>>(GI, GHN, WhH, WhL, WL, t);
  }
  ln_rows<<<TROWS, 256, 0, stream>>>(WL, WL, patch_g, patch_b);
  mean_pool_p<<<EW, 256, 0, stream>>>(WL, pAH, pAL);
  G3(pAH, pAL, 512, T_SUMM, 512, summ_b, nullptr, 0, WhH, WhL, 512, 512, F_WR_PAIR, 4, 64);

  // ---- rounds ----
  for (int rnd = 0; rnd < 6; ++rnd) {
    // fused: [msg_pre | msg_nb | q_pre | k_pre] = h @ W_fuse  -> X4 fp32 (N=2048)
    G3(WhH, WhL, 512, T_FUSE, 512, Wbias4, X4, 2048, nullptr, nullptr, 0, 512, F_WR_F32, 16, 64);
    msg_gelu_p<<<EW, 256, 0, stream>>>(X4, pBH, pBL);
    G3(pBH, pBL, 512, T_MSG2, 512, msg_b2, nullptr, 0, MsH, MsL, 512, 512, F_WR_PAIR, 4, 64);
    rotary_p<<<ROWS, 256, 0, stream>>>(X4 + 1024, pAH, pAL);   // q
    rotary_p<<<ROWS, 256, 0, stream>>>(X4 + 1536, pBH, pBL);   // k
    G3(WhH, WhL, 512, T_VW, 512, v_b, WV, 512, nullptr, nullptr, 0, 512, F_WR_F32, 4, 64);
    // scores (lower-triangular tiles) -> X4 fp32
    gemm_bf3<<<dim3(36, 1, CB), 256, 0, stream>>>(
        pAH, pAL, pAH, pAL, 512, 512, pBH, pBL, 512, nullptr, inv_sqrt_d,
        X4, CN, nullptr, nullptr, 0, 512, F_WR_F32 | F_TRI,
        (long long)CN * CD, (long long)CN * CD, (long long)CN * CN);
    topk_softmax2<<<ROWS, 256, 0, stream>>>(X4, Wprob, Widx);
    topk_gather_p<<<ROWS, 128, 0, stream>>>(Wprob, Widx, WV, pAH, pAL);
    G3(pAH, pAL, 512, T_OW, 512, o_b, nullptr, 0, pBH, pBL, 512, 512, F_WR_PAIR, 4, 64);
    // gi = [msgs|retr] @ [gc_top;gc_bot]  (K=1024, one GEMM)
    gemm_bf3<<<dim3(12, 64), 256, 0, stream>>>(
        MsH, MsL, pBH, pBL, 512, 512, WTh + T_GCAB, WTl + T_GCAB, 1024, gc_b_ih, 1.f,
        GI, 1536, nullptr, nullptr, 0, 1024, F_WR_F32, 0, 0, 0);
    G3(WhH, WhL, 512, T_GC_HH, 512, gc_b_hh, GI, 1536, nullptr, nullptr, 0, 512,
       F_ACC_F32 | F_WR_F32, 8, 64);
    G3(WhH, WhL, 512, T_GC_HH + (size_t)1024 * 512, 512, gc_b_hh + 1024, GHN, 512,
       nullptr, nullptr, 0, 512, F_WR_F32, 4, 64);
    gru_ln_p<<<ROWS, 256, 0, stream>>>(GI, GHN, WhH, WhL, msg_ln_g, msg_ln_b);
    if ((rnd & 1) == 1) {
      ln_pp<<<ROWS, 256, 0, stream>>>(WhH, WhL, pAH, pAL, ar_ln_g, ar_ln_b);
      G3(pAH, pAL, 512, T_AR_QKV, 512, ar_qkv_b, nullptr, 0, QkH, QkL, 1536, 512,
         F_WR_PAIR, 12, 64);
      flash_attn_p<<<dim3(16, CH, CB), 256, 0, stream>>>(QkH, QkL, pBH, pBL);
      G3(pBH, pBL, 512, T_AR_OUT, 512, ar_out_b, nullptr, 0, WhH, WhL, 512, 512,
         F_ACC_PAIR | F_WR_PAIR, 4, 64);
    }
  }

  // ---- head ----
  G3(WhH, WhL, 512, T_BROAD, 512, broad_b, WV, 512, nullptr, nullptr, 0, 512, F_WR_F32, 4, 64);
  final_ln_p<<<TROWS, 256, 0, stream>>>(WL, WV, ln_g, ln_b, FnH, FnL);
  G3(FnH, FnL, 512, T_HEAD, 512, nullptr, out, CV, nullptr, nullptr, 0, 512, F_WR_F32, 2, 256);
}

// Round 7
// 4511.163 us; speedup vs baseline: 4.5970x; 1.1251x over previous
//
#include <hip/hip_runtime.h>
#include <math.h>

// ---------------- problem constants ----------------
constexpr int CB = 8, CT = 4096, CP = 4, CD = 512, CV = 256;
constexpr int CN = 1024, CK = 16, CH = 8, CHD = 64;
constexpr int ROWS = CB * CN;     // 8192
constexpr int TROWS = CB * CT;    // 32768
constexpr float CEPS = 1e-5f;
constexpr size_t PN = (size_t)ROWS * CD;   // 4,194,304 (one pair-plane)

// ---------------- workspace layout (floats) ----------------
constexpr size_t OFF_LOCAL = 0;                                    // 16,777,216 fp32 local
constexpr size_t OFF_HP    = OFF_LOCAL + (size_t)ROWS * CP * CD;   //  4,194,304 h pair
constexpr size_t OFF_X4    = OFF_HP    + PN;                       // 20,971,520 fused5/scores/gi+ghn/arqkv/final
constexpr size_t OFF_MS    = OFF_X4    + (size_t)ROWS * 2560;      //  4,194,304 msgs pair / broad fp32
constexpr size_t OFF_A     = OFF_MS    + PN;                       //  4,194,304 pair A
constexpr size_t OFF_B     = OFF_A     + PN;                       //  4,194,304 pair B
constexpr size_t OFF_BIAS  = OFF_B     + PN;                       //      4,096
constexpr size_t OFF_WT    = OFF_BIAS  + 4096;                     //  7,471,104
// end = 62,011,008 floats = 236.6 MiB (< 241 MiB proven in R1)

constexpr size_t TOT_W    = 7471104;
constexpr size_t T_GRU_IH = 0;                     // 1536x512
constexpr size_t T_GRU_HH = 786432;                // 1536x512
constexpr size_t T_SUMM   = 1572864;               // 512x512
constexpr size_t T_FUSE   = 1835008;               // 2560x512 (msg1a|msg1b|qw|kw|vw)
constexpr size_t T_MSG2   = 3145728;               // 512x512
constexpr size_t T_OW     = 3407872;               // 512x512
constexpr size_t T_GCAB   = 3670016;               // 1536x1024 ([gc_top|gc_bot] along K)
constexpr size_t T_GC_HH  = 5242880;               // 1536x512
constexpr size_t T_AR_QKV = 6029312;               // 1536x512
constexpr size_t T_AR_OUT = 6815744;               // 512x512
constexpr size_t T_BROAD  = 7077888;               // 512x512
constexpr size_t T_HEAD   = 7340032;               // 256x512

// GEMM flags
constexpr int F_ACC_F32  = 1;
constexpr int F_ACC_PAIR = 2;
constexpr int F_WR_F32   = 4;
constexpr int F_WR_PAIR  = 8;
constexpr int F_TRI      = 16;
constexpr int F_SPLIT    = 32;   // col<1024: accumulate into Cf; col>=1024: write Cf2

// ---------------- device helpers ----------------
typedef __attribute__((ext_vector_type(8))) short short8;
typedef __attribute__((ext_vector_type(4))) float f32x4;

__device__ __forceinline__ float sigm(float x) { return 1.f / (1.f + expf(-x)); }
__device__ __forceinline__ float geluf(float x) {
  return 0.5f * x * (1.f + erff(x * 0.7071067811865475f));
}
__device__ __forceinline__ unsigned short bf_hi(float x) {
  const unsigned u = __float_as_uint(x);
  return (unsigned short)((u + 0x7FFFu + ((u >> 16) & 1u)) >> 16);
}
__device__ __forceinline__ float bf_f(unsigned short h) {
  return __uint_as_float((unsigned)h << 16);
}
__device__ __forceinline__ void split_store(float v, unsigned short* ph, unsigned short* pl) {
  const unsigned short h = bf_hi(v);
  *ph = h; *pl = bf_hi(v - bf_f(h));
}
__device__ __forceinline__ float blk_sum(float v, float* red) {
#pragma unroll
  for (int o = 32; o > 0; o >>= 1) v += __shfl_down(v, o, 64);
  const int wv = threadIdx.x >> 6, ln = threadIdx.x & 63;
  __syncthreads();
  if (ln == 0) red[wv] = v;
  __syncthreads();
  return red[0] + red[1] + red[2] + red[3];
}

// ---------------- transpose + bf16 split (weights) ----------------
__global__ __launch_bounds__(256) void transpose_split(const float* __restrict__ in,
                                                       unsigned short* __restrict__ oh,
                                                       unsigned short* __restrict__ ol,
                                                       int K, int N, int ldk, int ko)
{
  __shared__ float tile[32][33];
  const int n0 = blockIdx.x * 32, k0 = blockIdx.y * 32;
  const int tx = threadIdx.x & 31, ty = threadIdx.x >> 5;
#pragma unroll
  for (int i = 0; i < 32; i += 8)
    tile[ty + i][tx] = in[(size_t)(k0 + ty + i) * N + n0 + tx];
  __syncthreads();
#pragma unroll
  for (int i = 0; i < 32; i += 8) {
    const float v = tile[tx][ty + i];
    const unsigned short h = bf_hi(v);
    const size_t o = (size_t)(n0 + ty + i) * ldk + ko + k0 + tx;
    oh[o] = h;
    ol[o] = bf_hi(v - bf_f(h));
  }
}

__global__ void concat_bias5(const float* __restrict__ b1, const float* __restrict__ qb,
                             const float* __restrict__ kb, const float* __restrict__ vb,
                             float* __restrict__ o)
{
  const int i = blockIdx.x * 256 + threadIdx.x;   // 2560
  float v;
  if (i < 512) v = b1[i];
  else if (i < 1024) v = 0.f;
  else if (i < 1536) v = qb[i - 1024];
  else if (i < 2048) v = kb[i - 1536];
  else v = vb[i - 2048];
  o[i] = v;
}

// ---------------- unified 3-product bf16 MFMA GEMM (128x128 tile) ----------
__global__ __launch_bounds__(256, 2) void gemm_bf3(
    const unsigned short* __restrict__ AH, const unsigned short* __restrict__ AL,
    const unsigned short* __restrict__ A2H, const unsigned short* __restrict__ A2L,
    int K1, int lda,
    const unsigned short* __restrict__ BH, const unsigned short* __restrict__ BL, int ldb,
    const float* __restrict__ bias, float scale,
    float* __restrict__ Cf, int ldc, float* __restrict__ Cf2,
    unsigned short* __restrict__ CHp, unsigned short* __restrict__ CLp, int ldcp,
    int K, int flags, long long sA, long long sB, long long sC)
{
  AH += (size_t)blockIdx.z * sA; AL += (size_t)blockIdx.z * sA;
  BH += (size_t)blockIdx.z * sB; BL += (size_t)blockIdx.z * sB;
  if (Cf) Cf += (size_t)blockIdx.z * sC;
  int bm, bn;
  if (flags & F_TRI) {
    int t = blockIdx.x, i = 0, acc = 0;
    while (acc + i + 1 <= t) { ++i; acc += i; }
    bm = i << 7; bn = (t - acc) << 7;
  } else {
    bm = blockIdx.y << 7; bn = blockIdx.x << 7;
  }
  __shared__ __align__(16) unsigned short AsH[128][40];
  __shared__ __align__(16) unsigned short AsL[128][40];
  __shared__ __align__(16) unsigned short BsH[128][40];
  __shared__ __align__(16) unsigned short BsL[128][40];
  const int tid = threadIdx.x;
  const int lane = tid & 63, wave = tid >> 6;
  const int wm = (wave & 1) << 6, wn = (wave >> 1) << 6;
  const int r16 = lane & 15, quad = lane >> 4;
  const int sr = tid >> 1, sc = (tid & 1) << 4;
  const f32x4 zero = {0.f, 0.f, 0.f, 0.f};
  f32x4 acc[4][4];
#pragma unroll
  for (int i = 0; i < 4; ++i)
#pragma unroll
    for (int j = 0; j < 4; ++j) acc[i][j] = zero;

  for (int k0 = 0; k0 < K; k0 += 32) {
    const int kc = k0 + sc;
    const unsigned short *pAH, *pAL;
    if (kc < K1) {
      pAH = AH + (size_t)(bm + sr) * lda + kc;
      pAL = AL + (size_t)(bm + sr) * lda + kc;
    } else {
      pAH = A2H + (size_t)(bm + sr) * lda + (kc - K1);
      pAL = A2L + (size_t)(bm + sr) * lda + (kc - K1);
    }
    const unsigned short* pBH = BH + (size_t)(bn + sr) * ldb + kc;
    const unsigned short* pBL = BL + (size_t)(bn + sr) * ldb + kc;
    *(uint4*)&AsH[sr][sc]     = *(const uint4*)pAH;
    *(uint4*)&AsH[sr][sc + 8] = *(const uint4*)(pAH + 8);
    *(uint4*)&AsL[sr][sc]     = *(const uint4*)pAL;
    *(uint4*)&AsL[sr][sc + 8] = *(const uint4*)(pAL + 8);
    *(uint4*)&BsH[sr][sc]     = *(const uint4*)pBH;
    *(uint4*)&BsH[sr][sc + 8] = *(const uint4*)(pBH + 8);
    *(uint4*)&BsL[sr][sc]     = *(const uint4*)pBL;
    *(uint4*)&BsL[sr][sc + 8] = *(const uint4*)(pBL + 8);
    __syncthreads();
    short8 bh[4], bl[4];
#pragma unroll
    for (int ni = 0; ni < 4; ++ni) {
      bh[ni] = *(const short8*)&BsH[wn + ni * 16 + r16][quad * 8];
      bl[ni] = *(const short8*)&BsL[wn + ni * 16 + r16][quad * 8];
    }
#pragma unroll
    for (int mi = 0; mi < 4; ++mi) {
      const short8 ah = *(const short8*)&AsH[wm + mi * 16 + r16][quad * 8];
      const short8 al = *(const short8*)&AsL[wm + mi * 16 + r16][quad * 8];
#pragma unroll
      for (int ni = 0; ni < 4; ++ni) {
        acc[mi][ni] = __builtin_amdgcn_mfma_f32_16x16x32_bf16(ah, bh[ni], acc[mi][ni], 0, 0, 0);
        acc[mi][ni] = __builtin_amdgcn_mfma_f32_16x16x32_bf16(ah, bl[ni], acc[mi][ni], 0, 0, 0);
        acc[mi][ni] = __builtin_amdgcn_mfma_f32_16x16x32_bf16(al, bh[ni], acc[mi][ni], 0, 0, 0);
      }
    }
    __syncthreads();
  }
#pragma unroll
  for (int mi = 0; mi < 4; ++mi) {
    const int row0 = bm + wm + mi * 16 + quad * 4;
#pragma unroll
    for (int ni = 0; ni < 4; ++ni) {
      const int col = bn + wn + ni * 16 + r16;
      const float bv = bias ? bias[col] : 0.f;
#pragma unroll
      for (int rg = 0; rg < 4; ++rg) {
        const int row = row0 + rg;
        float o = acc[mi][ni][rg] * scale + bv;
        if (flags & F_SPLIT) {
          if (col < 1024) {
            float* p = Cf + (size_t)row * ldc + col;
            *p = o + *p;
          } else {
            Cf2[(size_t)row * 512 + (col - 1024)] = o;
          }
        } else {
          if (flags & F_ACC_F32) o += Cf[(size_t)row * ldc + col];
          if (flags & F_ACC_PAIR) {
            const size_t ip = (size_t)row * ldcp + col;
            o += bf_f(CHp[ip]) + bf_f(CLp[ip]);
          }
          if (flags & F_WR_F32) Cf[(size_t)row * ldc + col] = o;
          if (flags & F_WR_PAIR) {
            const size_t ip = (size_t)row * ldcp + col;
            split_store(o, &CHp[ip], &CLp[ip]);
          }
        }
      }
    }
  }
}

// ---------------- small-tile variant: 64x128, for N<=512 GEMMs ----------
__global__ __launch_bounds__(256, 3) void gemm_bf3s(
    const unsigned short* __restrict__ AH, const unsigned short* __restrict__ AL, int lda,
    const unsigned short* __restrict__ BH, const unsigned short* __restrict__ BL, int ldb,
    const float* __restrict__ bias,
    float* __restrict__ Cf, int ldc,
    unsigned short* __restrict__ CHp, unsigned short* __restrict__ CLp, int ldcp,
    int K, int flags)
{
  const int bm = blockIdx.y << 6, bn = blockIdx.x << 7;
  __shared__ __align__(16) unsigned short AsH[64][40];
  __shared__ __align__(16) unsigned short AsL[64][40];
  __shared__ __align__(16) unsigned short BsH[128][40];
  __shared__ __align__(16) unsigned short BsL[128][40];
  const int tid = threadIdx.x;
  const int lane = tid & 63, wave = tid >> 6;
  const int wm = (wave & 1) << 5, wn = (wave >> 1) << 6;
  const int r16 = lane & 15, quad = lane >> 4;
  const int sar = tid >> 2, sac = (tid & 3) << 3;   // A: 64 rows x 32, one uint4/plane
  const int sbr = tid >> 1, sbc = (tid & 1) << 4;   // B: 128 rows x 32, two uint4/plane
  const f32x4 zero = {0.f, 0.f, 0.f, 0.f};
  f32x4 acc[2][4];
#pragma unroll
  for (int i = 0; i < 2; ++i)
#pragma unroll
    for (int j = 0; j < 4; ++j) acc[i][j] = zero;

  for (int k0 = 0; k0 < K; k0 += 32) {
    const unsigned short* pAH = AH + (size_t)(bm + sar) * lda + k0 + sac;
    const unsigned short* pAL = AL + (size_t)(bm + sar) * lda + k0 + sac;
    const unsigned short* pBH = BH + (size_t)(bn + sbr) * ldb + k0 + sbc;
    const unsigned short* pBL = BL + (size_t)(bn + sbr) * ldb + k0 + sbc;
    *(uint4*)&AsH[sar][sac] = *(const uint4*)pAH;
    *(uint4*)&AsL[sar][sac] = *(const uint4*)pAL;
    *(uint4*)&BsH[sbr][sbc]     = *(const uint4*)pBH;
    *(uint4*)&BsH[sbr][sbc + 8] = *(const uint4*)(pBH + 8);
    *(uint4*)&BsL[sbr][sbc]     = *(const uint4*)pBL;
    *(uint4*)&BsL[sbr][sbc + 8] = *(const uint4*)(pBL + 8);
    __syncthreads();
    short8 bh[4], bl[4];
#pragma unroll
    for (int ni = 0; ni < 4; ++ni) {
      bh[ni] = *(const short8*)&BsH[wn + ni * 16 + r16][quad * 8];
      bl[ni] = *(const short8*)&BsL[wn + ni * 16 + r16][quad * 8];
    }
#pragma unroll
    for (int mi = 0; mi < 2; ++mi) {
      const short8 ah = *(const short8*)&AsH[wm + mi * 16 + r16][quad * 8];
      const short8 al = *(const short8*)&AsL[wm + mi * 16 + r16][quad * 8];
#pragma unroll
      for (int ni = 0; ni < 4; ++ni) {
        acc[mi][ni] = __builtin_amdgcn_mfma_f32_16x16x32_bf16(ah, bh[ni], acc[mi][ni], 0, 0, 0);
        acc[mi][ni] = __builtin_amdgcn_mfma_f32_16x16x32_bf16(ah, bl[ni], acc[mi][ni], 0, 0, 0);
        acc[mi][ni] = __builtin_amdgcn_mfma_f32_16x16x32_bf16(al, bh[ni], acc[mi][ni], 0, 0, 0);
      }
    }
    __syncthreads();
  }
#pragma unroll
  for (int mi = 0; mi < 2; ++mi) {
    const int row0 = bm + wm + mi * 16 + quad * 4;
#pragma unroll
    for (int ni = 0; ni < 4; ++ni) {
      const int col = bn + wn + ni * 16 + r16;
      const float bv = bias ? bias[col] : 0.f;
#pragma unroll
      for (int rg = 0; rg < 4; ++rg) {
        const int row = row0 + rg;
        float o = acc[mi][ni][rg] + bv;
        if (flags & F_ACC_PAIR) {
          const size_t ip = (size_t)row * ldcp + col;
          o += bf_f(CHp[ip]) + bf_f(CLp[ip]);
        }
        if (flags & F_WR_F32) Cf[(size_t)row * ldc + col] = o;
        if (flags & F_WR_PAIR) {
          const size_t ip = (size_t)row * ldcp + col;
          split_store(o, &CHp[ip], &CLp[ip]);
        }
      }
    }
  }
}

// ---------------- small kernels ----------------
__global__ void zero_k(float* __restrict__ p) {
  p[(size_t)blockIdx.x * 256 + threadIdx.x] = 0.f;
}

__global__ void embed_p(const int* __restrict__ x, const float* __restrict__ emb,
                        const float* __restrict__ pos,
                        unsigned short* __restrict__ oh, unsigned short* __restrict__ ol, int t)
{
  const int i = blockIdx.x * 256 + threadIdx.x;
  const int r = i >> 9, d = i & 511;
  const int b = r >> 10, n = r & (CN - 1);
  const int tok = x[b * CT + n * CP + t];
  const float v = emb[(size_t)tok * CD + d] + pos[t * CD + d];
  split_store(v, &oh[i], &ol[i]);
}

__global__ void gru_point_p(const float* __restrict__ gi, const float* __restrict__ ghn,
                            unsigned short* __restrict__ hH, unsigned short* __restrict__ hL,
                            float* __restrict__ hs, int t)
{
  const int i = blockIdx.x * 256 + threadIdx.x;
  const int r = i >> 9, d = i & 511;
  const size_t gb = (size_t)r * (3 * CD) + d;
  const float sr_ = gi[gb], sz = gi[gb + CD], inn = gi[gb + 2 * CD];
  const float hn = ghn[i];
  const float hp = bf_f(hH[i]) + bf_f(hL[i]);
  const float rr = sigm(sr_), zz = sigm(sz);
  const float nn = tanhf(inn + rr * hn);
  const float hv = (1.f - zz) * nn + zz * hp;
  split_store(hv, &hH[i], &hL[i]);
  hs[(size_t)r * (CP * CD) + (size_t)t * CD + d] = hv;
}

__global__ __launch_bounds__(256) void ln_rows(const float* __restrict__ in, float* __restrict__ out,
                                               const float* __restrict__ g, const float* __restrict__ b)
{
  const int r = blockIdx.x, t = threadIdx.x;
  __shared__ float red[4];
  const float* ip = in + (size_t)r * CD;
  const float v0 = ip[t], v1 = ip[t + 256];
  const float mu = blk_sum(v0 + v1, red) * (1.f / CD);
  const float d0 = v0 - mu, d1 = v1 - mu;
  const float var = blk_sum(d0 * d0 + d1 * d1, red) * (1.f / CD);
  const float inv = rsqrtf(var + CEPS);
  float* op = out + (size_t)r * CD;
  op[t] = d0 * inv * g[t] + b[t];
  op[t + 256] = d1 * inv * g[t + 256] + b[t + 256];
}

__global__ __launch_bounds__(256) void ln_pp(const unsigned short* __restrict__ inH,
                                             const unsigned short* __restrict__ inL,
                                             unsigned short* __restrict__ oh, unsigned short* __restrict__ ol,
                                             const float* __restrict__ g, const float* __restrict__ b)
{
  const int r = blockIdx.x, t = threadIdx.x;
  __shared__ float red[4];
  const size_t i0 = (size_t)r * CD + t, i1 = i0 + 256;
  const float v0 = bf_f(inH[i0]) + bf_f(inL[i0]);
  const float v1 = bf_f(inH[i1]) + bf_f(inL[i1]);
  const float mu = blk_sum(v0 + v1, red) * (1.f / CD);
  const float d0 = v0 - mu, d1 = v1 - mu;
  const float var = blk_sum(d0 * d0 + d1 * d1, red) * (1.f / CD);
  const float inv = rsqrtf(var + CEPS);
  split_store(d0 * inv * g[t] + b[t], &oh[i0], &ol[i0]);
  split_store(d1 * inv * g[t + 256] + b[t + 256], &oh[i1], &ol[i1]);
}

__global__ void mean_pool_p(const float* __restrict__ local,
                            unsigned short* __restrict__ oh, unsigned short* __restrict__ ol)
{
  const int i = blockIdx.x * 256 + threadIdx.x;
  const int r = i >> 9, d = i & 511;
  const float* p = local + (size_t)r * (CP * CD) + d;
  split_store(0.25f * (p[0] + p[CD] + p[2 * CD] + p[3 * CD]), &oh[i], &ol[i]);
}

// reads pre/nb from X4 (stride 2560, nb at col offset 512)
__global__ void msg_gelu_p(const float* __restrict__ X4,
                           unsigned short* __restrict__ oh, unsigned short* __restrict__ ol)
{
  const int i = blockIdx.x * 256 + threadIdx.x;
  const int r = i >> 9, d = i & 511;
  const int n = r & (CN - 1);
  const float pv = X4[(size_t)r * 2560 + d];
  float acc = 0.f;
#pragma unroll
  for (int w = 0; w <= 4; ++w) {
    const float xv = pv + ((n >= w) ? X4[(size_t)(r - w) * 2560 + 512 + d] : 0.f);
    acc += geluf(xv);
  }
  split_store(acc * 0.2f, &oh[i], &ol[i]);
}

// rotary for q (cols 1024..2047) and k (cols 1536..2047? no: q at 1024, k at 1536)
__global__ void rotary2_p(const float* __restrict__ X4,
                          unsigned short* __restrict__ qh, unsigned short* __restrict__ ql,
                          unsigned short* __restrict__ kh, unsigned short* __restrict__ kl)
{
  const int i = blockIdx.x * 256 + threadIdx.x;   // ROWS*256
  const int r = i >> 8, j = i & 255;
  const int n = r & (CN - 1);
  const float fr = (float)n * expf(-9.210340371976184f * ((float)j * (1.f / 256.f)));
  float s, c;
  sincosf(fr, &s, &c);
  const float* p = X4 + (size_t)r * 2560;
  const size_t o0 = (size_t)r * CD + j, o1 = o0 + 256;
  const float q1 = p[1024 + j], q2 = p[1024 + 256 + j];
  split_store(q1 * c - q2 * s, &qh[o0], &ql[o0]);
  split_store(q2 * c + q1 * s, &qh[o1], &ql[o1]);
  const float k1 = p[1536 + j], k2 = p[1536 + 256 + j];
  split_store(k1 * c - k2 * s, &kh[o0], &kl[o0]);
  split_store(k2 * c + k1 * s, &kh[o1], &kl[o1]);
}

// ---------------- fused top-K + softmax + gather ----------------
// scores at X4[r*2560 + m] (m<=n valid); v at X4[row*2560 + 2048 + d].
__global__ __launch_bounds__(256) void topk_attn(const float* __restrict__ X4,
                                                 unsigned short* __restrict__ ctxH,
                                                 unsigned short* __restrict__ ctxL)
{
  const int r = blockIdx.x;
  const int b = r >> 10, n = r & (CN - 1);
  const float* row = X4 + (size_t)r * 2560;
  const int tid = threadIdx.x, lane = tid & 63, wave = tid >> 6;
  __shared__ unsigned long long cands[64];
  __shared__ float p16[CK];
  __shared__ int i16[CK];
  unsigned long long key[4];
#pragma unroll
  for (int q = 0; q < 4; ++q) {
    const int m = tid + q * 256;
    const float v = (m <= n) ? row[m] : -INFINITY;
    unsigned u = __float_as_uint(v);
    u = (u & 0x80000000u) ? ~u : (u | 0x80000000u);
    key[q] = ((unsigned long long)u << 32) | (unsigned)(CN - 1 - m);
  }
  // per-wave top-16 (no block syncs)
  unsigned long long mycand = 0ull;
#pragma unroll
  for (int it = 0; it < CK; ++it) {
    unsigned long long best = key[0];
#pragma unroll
    for (int q = 1; q < 4; ++q) best = best > key[q] ? best : key[q];
#pragma unroll
    for (int o = 32; o > 0; o >>= 1) {
      const unsigned long long o2 = __shfl_xor(best, o, 64);
      best = best > o2 ? best : o2;
    }
    if (lane == it) mycand = best;
#pragma unroll
    for (int q = 0; q < 4; ++q)
      if (key[q] == best) key[q] = 0ull;
  }
  if (lane < CK) cands[wave * CK + lane] = mycand;
  __syncthreads();
  if (wave == 0) {
    unsigned long long k2 = cands[lane];
    unsigned long long mine = 0ull;
#pragma unroll
    for (int it = 0; it < CK; ++it) {
      unsigned long long best = k2;
#pragma unroll
      for (int o = 32; o > 0; o >>= 1) {
        const unsigned long long o2 = __shfl_xor(best, o, 64);
        best = best > o2 ? best : o2;
      }
      if (lane == it) mine = best;
      if (k2 == best) k2 = 0ull;
    }
    unsigned u = (unsigned)(mine >> 32);
    u = (u & 0x80000000u) ? (u & 0x7FFFFFFFu) : ~u;
    const float val = __uint_as_float(u);
    const int idx = CN - 1 - (int)(mine & 0xFFFFFFFFu);
    const float mx = __shfl(val, 0, 64);   // lane 0 = max (descending extraction)
    float e = 0.f;
    if (lane < CK && val != -INFINITY) e = expf(val - mx);
    float sum = e;
#pragma unroll
    for (int o = 32; o > 0; o >>= 1) sum += __shfl_xor(sum, o, 64);
    if (lane < CK) {
      p16[lane] = e / sum;
      i16[lane] = idx;
    }
  }
  __syncthreads();
  const size_t vb = ((size_t)b << 10);
#pragma unroll
  for (int pass = 0; pass < 2; ++pass) {
    const int d = tid + pass * 256;
    float a = 0.f;
#pragma unroll
    for (int q = 0; q < CK; ++q)
      a += p16[q] * X4[(vb + i16[q]) * 2560 + 2048 + d];
    split_store(a, &ctxH[(size_t)r * CD + d], &ctxL[(size_t)r * CD + d]);
  }
}

__global__ __launch_bounds__(256) void gru_ln_p(const float* __restrict__ gi, const float* __restrict__ ghn,
                                                unsigned short* __restrict__ hH, unsigned short* __restrict__ hL,
                                                const float* __restrict__ g, const float* __restrict__ b)
{
  const int r = blockIdx.x, t = threadIdx.x;
  __shared__ float red[4];
  float u[2];
#pragma unroll
  for (int q = 0; q < 2; ++q) {
    const int d = t + q * 256;
    const size_t gb = (size_t)r * (3 * CD) + d;
    const float sr_ = gi[gb], sz = gi[gb + CD], inn = gi[gb + 2 * CD];
    const float hn = ghn[(size_t)r * CD + d];
    const size_t hi = (size_t)r * CD + d;
    const float hp = bf_f(hH[hi]) + bf_f(hL[hi]);
    const float rr = sigm(sr_), zz = sigm(sz);
    const float nn = tanhf(inn + rr * hn);
    u[q] = (1.f - zz) * nn + zz * hp;
  }
  const float mu = blk_sum(u[0] + u[1], red) * (1.f / CD);
  const float d0 = u[0] - mu, d1 = u[1] - mu;
  const float var = blk_sum(d0 * d0 + d1 * d1, red) * (1.f / CD);
  const float inv = rsqrtf(var + CEPS);
  split_store(d0 * inv * g[t] + b[t], &hH[(size_t)r * CD + t], &hL[(size_t)r * CD + t]);
  split_store(d1 * inv * g[t + 256] + b[t + 256],
              &hH[(size_t)r * CD + t + 256], &hL[(size_t)r * CD + t + 256]);
}

// ---------------- MFMA flash attention, pair I/O ----------------
constexpr int FP = 72;
__global__ __launch_bounds__(256, 2) void flash_attn_p(const unsigned short* __restrict__ qkvH,
                                                       const unsigned short* __restrict__ qkvL,
                                                       unsigned short* __restrict__ outH,
                                                       unsigned short* __restrict__ outL)
{
  __shared__ __align__(16) unsigned short Qh[64 * FP], Ql[64 * FP];
  __shared__ __align__(16) unsigned short Kh[64 * FP], Kl[64 * FP];
  __shared__ __align__(16) unsigned short Vth[64 * FP], Vtl[64 * FP];
  __shared__ __align__(16) unsigned short Pm[64 * FP];
  const int qt = blockIdx.x, head = blockIdx.y, b = blockIdx.z;
  const int tid = threadIdx.x;
  const int lane = tid & 63, wave = tid >> 6;
  const int r16 = lane & 15, quad = lane >> 4;
  const size_t base = (size_t)b * CN * (3 * CD) + head * CHD;

  {
    const int r = tid >> 2, c0 = (tid & 3) << 4;
    const unsigned short* qh = qkvH + base + (size_t)(qt * 64 + r) * (3 * CD) + c0;
    const unsigned short* ql = qkvL + base + (size_t)(qt * 64 + r) * (3 * CD) + c0;
    *(uint4*)&Qh[r * FP + c0]     = *(const uint4*)qh;
    *(uint4*)&Qh[r * FP + c0 + 8] = *(const uint4*)(qh + 8);
    *(uint4*)&Ql[r * FP + c0]     = *(const uint4*)ql;
    *(uint4*)&Ql[r * FP + c0 + 8] = *(const uint4*)(ql + 8);
  }
  float m_i[4], l_i[4];
  f32x4 O[4];
  const f32x4 zero = {0.f, 0.f, 0.f, 0.f};
#pragma unroll
  for (int r = 0; r < 4; ++r) { m_i[r] = -INFINITY; l_i[r] = 0.f; }
#pragma unroll
  for (int d = 0; d < 4; ++d) O[d] = zero;

  for (int j = 0; j <= qt; ++j) {
    __syncthreads();
    {
      const int r = tid >> 2, c0 = (tid & 3) << 4;
      const unsigned short* kh = qkvH + base + (size_t)(j * 64 + r) * (3 * CD) + CD + c0;
      const unsigned short* kl = qkvL + base + (size_t)(j * 64 + r) * (3 * CD) + CD + c0;
      *(uint4*)&Kh[r * FP + c0]     = *(const uint4*)kh;
      *(uint4*)&Kh[r * FP + c0 + 8] = *(const uint4*)(kh + 8);
      *(uint4*)&Kl[r * FP + c0]     = *(const uint4*)kl;
      *(uint4*)&Kl[r * FP + c0 + 8] = *(const uint4*)(kl + 8);
      const int rp = (tid >> 3) << 1, c0v = (tid & 7) << 3;
      const unsigned short* v0h = qkvH + base + (size_t)(j * 64 + rp) * (3 * CD) + 2 * CD + c0v;
      const unsigned short* v1h = v0h + 3 * CD;
      const unsigned short* v0l = qkvL + base + (size_t)(j * 64 + rp) * (3 * CD) + 2 * CD + c0v;
      const unsigned short* v1l = v0l + 3 * CD;
      unsigned short xh[8], yh[8], xl[8], yl[8];
      *(uint4*)xh = *(const uint4*)v0h; *(uint4*)yh = *(const uint4*)v1h;
      *(uint4*)xl = *(const uint4*)v0l; *(uint4*)yl = *(const uint4*)v1l;
#pragma unroll
      for (int c = 0; c < 8; ++c) {
        const int R = c0v + c;
        const int col = rp ^ ((R >> 3) << 3);
        *(unsigned*)&Vth[R * FP + col] = (unsigned)xh[c] | ((unsigned)yh[c] << 16);
        *(unsigned*)&Vtl[R * FP + col] = (unsigned)xl[c] | ((unsigned)yl[c] << 16);
      }
    }
    __syncthreads();
    f32x4 S[4];
#pragma unroll
    for (int nt = 0; nt < 4; ++nt) S[nt] = zero;
#pragma unroll
    for (int kh2 = 0; kh2 < 2; ++kh2) {
      const short8 qh = *(const short8*)&Qh[(wave * 16 + r16) * FP + kh2 * 32 + quad * 8];
      const short8 ql = *(const short8*)&Ql[(wave * 16 + r16) * FP + kh2 * 32 + quad * 8];
#pragma unroll
      for (int nt = 0; nt < 4; ++nt) {
        const short8 kkh = *(const short8*)&Kh[(nt * 16 + r16) * FP + kh2 * 32 + quad * 8];
        const short8 kkl = *(const short8*)&Kl[(nt * 16 + r16) * FP + kh2 * 32 + quad * 8];
        S[nt] = __builtin_amdgcn_mfma_f32_16x16x32_bf16(qh, kkh, S[nt], 0, 0, 0);
        S[nt] = __builtin_amdgcn_mfma_f32_16x16x32_bf16(qh, kkl, S[nt], 0, 0, 0);
        S[nt] = __builtin_amdgcn_mfma_f32_16x16x32_bf16(ql, kkh, S[nt], 0, 0, 0);
      }
    }
#pragma unroll
    for (int r = 0; r < 4; ++r) {
      const int qrow = wave * 16 + quad * 4 + r;
      float s[4];
#pragma unroll
      for (int nt = 0; nt < 4; ++nt) {
        s[nt] = S[nt][r] * 0.125f;
        if (j == qt && (nt * 16 + r16) > qrow) s[nt] = -1e30f;
      }
      float rm = fmaxf(fmaxf(s[0], s[1]), fmaxf(s[2], s[3]));
#pragma unroll
      for (int o = 8; o > 0; o >>= 1) rm = fmaxf(rm, __shfl_xor(rm, o, 64));
      const float newm = fmaxf(m_i[r], rm);
      float p[4], rs = 0.f;
#pragma unroll
      for (int nt = 0; nt < 4; ++nt) { p[nt] = expf(s[nt] - newm); rs += p[nt]; }
#pragma unroll
      for (int o = 8; o > 0; o >>= 1) rs += __shfl_xor(rs, o, 64);
      const float alpha = expf(m_i[r] - newm);
      l_i[r] = l_i[r] * alpha + rs;
      m_i[r] = newm;
#pragma unroll
      for (int dt = 0; dt < 4; ++dt) O[dt][r] *= alpha;
#pragma unroll
      for (int nt = 0; nt < 4; ++nt)
        Pm[qrow * FP + nt * 16 + r16] = bf_hi(p[nt]);
    }
    __syncthreads();
#pragma unroll
    for (int kh2 = 0; kh2 < 2; ++kh2) {
      const short8 pa = *(const short8*)&Pm[(wave * 16 + r16) * FP + kh2 * 32 + quad * 8];
#pragma unroll
      for (int dt = 0; dt < 4; ++dt) {
        const int R = dt * 16 + r16;
        const int col = (kh2 * 32 + quad * 8) ^ ((R >> 3) << 3);
        const short8 vh = *(const short8*)&Vth[R * FP + col];
        const short8 vl = *(const short8*)&Vtl[R * FP + col];
        O[dt] = __builtin_amdgcn_mfma_f32_16x16x32_bf16(pa, vh, O[dt], 0, 0, 0);
        O[dt] = __builtin_amdgcn_mfma_f32_16x16x32_bf16(pa, vl, O[dt], 0, 0, 0);
      }
    }
  }
#pragma unroll
  for (int r = 0; r < 4; ++r) {
    const float inv = 1.f / l_i[r];
    const size_t row = (size_t)b * CN + qt * 64 + wave * 16 + quad * 4 + r;
#pragma unroll
    for (int dt = 0; dt < 4; ++dt) {
      const size_t o = row * CD + head * CHD + dt * 16 + r16;
      split_store(O[dt][r] * inv, &outH[o], &outL[o]);
    }
  }
}

__global__ __launch_bounds__(256) void final_ln_p(const float* __restrict__ local,
                                                  const float* __restrict__ broad,
                                                  const float* __restrict__ g, const float* __restrict__ bb,
                                                  unsigned short* __restrict__ oh,
                                                  unsigned short* __restrict__ ol)
{
  const int r = blockIdx.x, t = threadIdx.x;
  __shared__ float red[4];
  const size_t lb = (size_t)r * CD;
  const size_t br = (size_t)(r >> 2) * CD;
  const float v0 = local[lb + t] + broad[br + t];
  const float v1 = local[lb + 256 + t] + broad[br + 256 + t];
  const float mu = blk_sum(v0 + v1, red) * (1.f / CD);
  const float d0 = v0 - mu, d1 = v1 - mu;
  const float var = blk_sum(d0 * d0 + d1 * d1, red) * (1.f / CD);
  const float inv = rsqrtf(var + CEPS);
  split_store(d0 * inv * g[t] + bb[t], &oh[lb + t], &ol[lb + t]);
  split_store(d1 * inv * g[t + 256] + bb[t + 256], &oh[lb + 256 + t], &ol[lb + 256 + t]);
}

// ---------------- launcher ----------------
extern "C" void kernel_launch(void* const* d_in, const int* in_sizes, int n_in,
                              void* d_out, int out_size, void* d_ws, size_t ws_size,
                              hipStream_t stream)
{
  (void)in_sizes; (void)n_in; (void)out_size; (void)ws_size;
  const int*   x         = (const int*)d_in[0];
  const float* emb       = (const float*)d_in[1];
  const float* pos_emb   = (const float*)d_in[2];
  const float* gru_w_ih  = (const float*)d_in[3];
  const float* gru_w_hh  = (const float*)d_in[4];
  const float* gru_b_ih  = (const float*)d_in[5];
  const float* gru_b_hh  = (const float*)d_in[6];
  const float* patch_g   = (const float*)d_in[7];
  const float* patch_b   = (const float*)d_in[8];
  const float* summ_w    = (const float*)d_in[9];
  const float* summ_b    = (const float*)d_in[10];
  const float* msg_w1    = (const float*)d_in[11];
  const float* msg_b1    = (const float*)d_in[12];
  const float* msg_w2    = (const float*)d_in[13];
  const float* msg_b2    = (const float*)d_in[14];
  const float* msg_ln_g  = (const float*)d_in[15];
  const float* msg_ln_b  = (const float*)d_in[16];
  const float* q_w       = (const float*)d_in[17];
  const float* q_b       = (const float*)d_in[18];
  const float* k_w       = (const float*)d_in[19];
  const float* k_b       = (const float*)d_in[20];
  const float* v_w       = (const float*)d_in[21];
  const float* v_b       = (const float*)d_in[22];
  const float* o_w       = (const float*)d_in[23];
  const float* o_b       = (const float*)d_in[24];
  const float* gc_w_ih   = (const float*)d_in[25];
  const float* gc_w_hh   = (const float*)d_in[26];
  const float* gc_b_ih   = (const float*)d_in[27];
  const float* gc_b_hh   = (const float*)d_in[28];
  const float* ar_ln_g   = (const float*)d_in[29];
  const float* ar_ln_b   = (const float*)d_in[30];
  const float* ar_qkv_w  = (const float*)d_in[31];
  const float* ar_qkv_b  = (const float*)d_in[32];
  const float* ar_out_w  = (const float*)d_in[33];
  const float* ar_out_b  = (const float*)d_in[34];
  const float* broad_w   = (const float*)d_in[35];
  const float* broad_b   = (const float*)d_in[36];
  const float* ln_g      = (const float*)d_in[37];
  const float* ln_b      = (const float*)d_in[38];
  const float* head_w    = (const float*)d_in[39];
  float* out = (float*)d_out;

  float* ws = (float*)d_ws;
  float* WL    = ws + OFF_LOCAL;
  float* X4    = ws + OFF_X4;
  float* GI    = X4;                               // 8192x1536 fp32 (flat)
  float* GHN   = X4 + (size_t)ROWS * 1536;         // 8192x512 fp32
  float* WBR   = ws + OFF_MS;                      // broad fp32 (after msgs dead)
  float* Wbias5 = ws + OFF_BIAS;
  unsigned short* WTh = (unsigned short*)(ws + OFF_WT);
  unsigned short* WTl = WTh + TOT_W;
  unsigned short* WhH = (unsigned short*)(ws + OFF_HP);
  unsigned short* WhL = WhH + PN;
  unsigned short* MsH = (unsigned short*)(ws + OFF_MS);
  unsigned short* MsL = MsH + PN;
  unsigned short* pAH = (unsigned short*)(ws + OFF_A);
  unsigned short* pAL = pAH + PN;
  unsigned short* pBH = (unsigned short*)(ws + OFF_B);
  unsigned short* pBL = pBH + PN;
  unsigned short* QkH = (unsigned short*)X4;
  unsigned short* QkL = QkH + (size_t)ROWS * 1536;
  unsigned short* FnH = (unsigned short*)X4;
  unsigned short* FnL = FnH + (size_t)TROWS * CD;

  const int EW = ROWS * CD / 256;
  const float inv_sqrt_d = 0.04419417382415922f;   // 1/sqrt(512)

  auto TR = [&](const float* in, size_t off, int K, int N, int ldk, int ko) {
    transpose_split<<<dim3(N / 32, K / 32), 256, 0, stream>>>(in, WTh + off, WTl + off, K, N, ldk, ko);
  };
  TR(gru_w_ih, T_GRU_IH, 512, 1536, 512, 0);
  TR(gru_w_hh, T_GRU_HH, 512, 1536, 512, 0);
  TR(summ_w,   T_SUMM,   512, 512,  512, 0);
  TR(msg_w1,                      T_FUSE,           512, 512, 512, 0);
  TR(msg_w1 + (size_t)512 * 512,  T_FUSE + 262144,  512, 512, 512, 0);
  TR(q_w,                         T_FUSE + 524288,  512, 512, 512, 0);
  TR(k_w,                         T_FUSE + 786432,  512, 512, 512, 0);
  TR(v_w,                         T_FUSE + 1048576, 512, 512, 512, 0);
  TR(msg_w2,   T_MSG2,   512, 512,  512, 0);
  TR(o_w, T_OW, 512, 512, 512, 0);
  TR(gc_w_ih,                       T_GCAB, 512, 1536, 1024, 0);
  TR(gc_w_ih + (size_t)512 * 1536,  T_GCAB, 512, 1536, 1024, 512);
  TR(gc_w_hh,  T_GC_HH,  512, 1536, 512, 0);
  TR(ar_qkv_w, T_AR_QKV, 512, 1536, 512, 0);
  TR(ar_out_w, T_AR_OUT, 512, 512,  512, 0);
  TR(broad_w,  T_BROAD,  512, 512,  512, 0);
  TR(head_w,   T_HEAD,   512, 256,  512, 0);
  concat_bias5<<<10, 256, 0, stream>>>(msg_b1, q_b, k_b, v_b, Wbias5);

  // big GEMM wrapper (128x128 tiles)
  auto G3 = [&](const unsigned short* AH_, const unsigned short* AL_, int lda_,
                size_t toff, int ldb_, const float* bias_, float* Cf_, int ldc_, float* Cf2_,
                unsigned short* CHp_, unsigned short* CLp_, int ldcp_,
                int K_, int flags_, int gx, int gy) {
    gemm_bf3<<<dim3(gx, gy), 256, 0, stream>>>(
        AH_, AL_, AH_, AL_, K_, lda_, WTh + toff, WTl + toff, ldb_, bias_, 1.f,
        Cf_, ldc_, Cf2_, CHp_, CLp_, ldcp_, K_, flags_, 0, 0, 0);
  };
  // small GEMM wrapper (64x128 tiles), N=512 -> grid (4,128)
  auto G3S = [&](const unsigned short* AH_, const unsigned short* AL_, int lda_,
                 size_t toff, const float* bias_, float* Cf_, int ldc_,
                 unsigned short* CHp_, unsigned short* CLp_, int ldcp_,
                 int flags_, int gx, int gy) {
    gemm_bf3s<<<dim3(gx, gy), 256, 0, stream>>>(
        AH_, AL_, lda_, WTh + toff, WTl + toff, 512, bias_,
        Cf_, ldc_, CHp_, CLp_, ldcp_, 512, flags_);
  };

  // ---- patch GRU over P=4 steps ----
  zero_k<<<EW, 256, 0, stream>>>(ws + OFF_HP);
  for (int t = 0; t < CP; ++t) {
    embed_p<<<EW, 256, 0, stream>>>(x, emb, pos_emb, pAH, pAL, t);
    G3(pAH, pAL, 512, T_GRU_IH, 512, gru_b_ih, GI, 1536, nullptr,
       nullptr, nullptr, 0, 512, F_WR_F32, 12, 64);
    G3(WhH, WhL, 512, T_GRU_HH, 512, gru_b_hh, GI, 1536, GHN,
       nullptr, nullptr, 0, 512, F_SPLIT, 12, 64);
    gru_point_p<<<EW, 256, 0, stream>>>(GI, GHN, WhH, WhL, WL, t);
  }
  ln_rows<<<TROWS, 256, 0, stream>>>(WL, WL, patch_g, patch_b);
  mean_pool_p<<<EW, 256, 0, stream>>>(WL, pAH, pAL);
  G3S(pAH, pAL, 512, T_SUMM, summ_b, nullptr, 0, WhH, WhL, 512, F_WR_PAIR, 4, 128);

  // ---- rounds ----
  for (int rnd = 0; rnd < 6; ++rnd) {
    // fused: [msg_pre | msg_nb | q | k | v] = h @ W_fuse -> X4 fp32 (N=2560)
    G3(WhH, WhL, 512, T_FUSE, 512, Wbias5, X4, 2560, nullptr,
       nullptr, nullptr, 0, 512, F_WR_F32, 20, 64);
    msg_gelu_p<<<EW, 256, 0, stream>>>(X4, pBH, pBL);
    G3S(pBH, pBL, 512, T_MSG2, msg_b2, nullptr, 0, MsH, MsL, 512, F_WR_PAIR, 4, 128);
    rotary2_p<<<ROWS, 256, 0, stream>>>(X4, pAH, pAL, pBH, pBL);
    // scores (lower-triangular 128-tiles) -> X4 cols 0..1023 (stride 2560)
    gemm_bf3<<<dim3(36, 1, CB), 256, 0, stream>>>(
        pAH, pAL, pAH, pAL, 512, 512, pBH, pBL, 512, nullptr, inv_sqrt_d,
        X4, 2560, nullptr, nullptr, nullptr, 0, 512, F_WR_F32 | F_TRI,
        (long long)CN * CD, (long long)CN * CD, (long long)CN * 2560);
    topk_attn<<<ROWS, 256, 0, stream>>>(X4, pAH, pAL);        // ctx pair -> pA
    G3S(pAH, pAL, 512, T_OW, o_b, nullptr, 0, pBH, pBL, 512, F_WR_PAIR, 4, 128);
    // gi = [msgs|retr] @ [gc_top;gc_bot]  (K=1024)
    gemm_bf3<<<dim3(12, 64), 256, 0, stream>>>(
        MsH, MsL, pBH, pBL, 512, 512, WTh + T_GCAB, WTl + T_GCAB, 1024, gc_b_ih, 1.f,
        GI, 1536, nullptr, nullptr, nullptr, 0, 1024, F_WR_F32, 0, 0, 0);
    G3(WhH, WhL, 512, T_GC_HH, 512, gc_b_hh, GI, 1536, GHN,
       nullptr, nullptr, 0, 512, F_SPLIT, 12, 64);
    gru_ln_p<<<ROWS, 256, 0, stream>>>(GI, GHN, WhH, WhL, msg_ln_g, msg_ln_b);
    if ((rnd & 1) == 1) {
      ln_pp<<<ROWS, 256, 0, stream>>>(WhH, WhL, pAH, pAL, ar_ln_g, ar_ln_b);
      G3(pAH, pAL, 512, T_AR_QKV, 512, ar_qkv_b, nullptr, 0, nullptr,
         QkH, QkL, 1536, 512, F_WR_PAIR, 12, 64);
      flash_attn_p<<<dim3(16, CH, CB), 256, 0, stream>>>(QkH, QkL, pBH, pBL);
      G3S(pBH, pBL, 512, T_AR_OUT, ar_out_b, nullptr, 0, WhH, WhL, 512,
          F_ACC_PAIR | F_WR_PAIR, 4, 128);
    }
  }

  // ---- head ----
  G3S(WhH, WhL, 512, T_BROAD, broad_b, WBR, 512, nullptr, nullptr, 0, F_WR_F32, 4, 128);
  final_ln_p<<<TROWS, 256, 0, stream>>>(WL, WBR, ln_g, ln_b, FnH, FnL);
  G3S(FnH, FnL, 512, T_HEAD, nullptr, out, CV, nullptr, nullptr, 0, F_WR_F32, 2, 512);
}

// Round 8
// 4051.961 us; speedup vs baseline: 5.1179x; 1.1133x over previous
//
#include <hip/hip_runtime.h>
#include <math.h>

// ---------------- problem constants ----------------
constexpr int CB = 8, CT = 4096, CP = 4, CD = 512, CV = 256;
constexpr int CN = 1024, CK = 16, CH = 8, CHD = 64;
constexpr int ROWS = CB * CN;     // 8192
constexpr int TROWS = CB * CT;    // 32768
constexpr float CEPS = 1e-5f;
constexpr size_t PN = (size_t)ROWS * CD;   // 4,194,304 (one pair-plane)

// ---------------- workspace layout (floats) ----------------
constexpr size_t OFF_LOCAL = 0;                                    // 16,777,216 fp32 local
constexpr size_t OFF_HP    = OFF_LOCAL + (size_t)ROWS * CP * CD;   //  4,194,304 h pair
constexpr size_t OFF_X4    = OFF_HP    + PN;                       // 20,971,520 fused5/scores/gi+ghn/arqkv/final
constexpr size_t OFF_MS    = OFF_X4    + (size_t)ROWS * 2560;      //  4,194,304 msgs pair / broad fp32
constexpr size_t OFF_A     = OFF_MS    + PN;                       //  4,194,304 pair A
constexpr size_t OFF_B     = OFF_A     + PN;                       //  4,194,304 pair B
constexpr size_t OFF_BIAS  = OFF_B     + PN;                       //      4,096
constexpr size_t OFF_WT    = OFF_BIAS  + 4096;                     //  7,471,104
// end = 62,011,008 floats = 236.6 MiB

constexpr size_t TOT_W    = 7471104;
constexpr size_t T_GRU_IH = 0;                     // 1536x512
constexpr size_t T_GRU_HH = 786432;                // 1536x512
constexpr size_t T_SUMM   = 1572864;               // 512x512
constexpr size_t T_FUSE   = 1835008;               // 2560x512 (msg1a|msg1b|qw|kw|vw)
constexpr size_t T_MSG2   = 3145728;               // 512x512
constexpr size_t T_OW     = 3407872;               // 512x512
constexpr size_t T_GCAB   = 3670016;               // 1536x1024 ([gc_top|gc_bot] along K)
constexpr size_t T_GC_HH  = 5242880;               // 1536x512
constexpr size_t T_AR_QKV = 6029312;               // 1536x512
constexpr size_t T_AR_OUT = 6815744;               // 512x512
constexpr size_t T_BROAD  = 7077888;               // 512x512
constexpr size_t T_HEAD   = 7340032;               // 256x512

// GEMM flags
constexpr int F_ACC_F32  = 1;
constexpr int F_ACC_PAIR = 2;
constexpr int F_WR_F32   = 4;
constexpr int F_WR_PAIR  = 8;
constexpr int F_TRI      = 16;
constexpr int F_SPLIT    = 32;   // col<1024: accumulate into Cf; col>=1024: write Cf2

// ---------------- device helpers ----------------
typedef __attribute__((ext_vector_type(8))) short short8;
typedef __attribute__((ext_vector_type(4))) float f32x4;

__device__ __forceinline__ float sigm(float x) { return 1.f / (1.f + expf(-x)); }
__device__ __forceinline__ float geluf(float x) {
  return 0.5f * x * (1.f + erff(x * 0.7071067811865475f));
}
__device__ __forceinline__ unsigned short bf_hi(float x) {
  const unsigned u = __float_as_uint(x);
  return (unsigned short)((u + 0x7FFFu + ((u >> 16) & 1u)) >> 16);
}
__device__ __forceinline__ float bf_f(unsigned short h) {
  return __uint_as_float((unsigned)h << 16);
}
__device__ __forceinline__ void split_store(float v, unsigned short* ph, unsigned short* pl) {
  const unsigned short h = bf_hi(v);
  *ph = h; *pl = bf_hi(v - bf_f(h));
}
__device__ __forceinline__ float blk_sum(float v, float* red) {
#pragma unroll
  for (int o = 32; o > 0; o >>= 1) v += __shfl_down(v, o, 64);
  const int wv = threadIdx.x >> 6, ln = threadIdx.x & 63;
  __syncthreads();
  if (ln == 0) red[wv] = v;
  __syncthreads();
  return red[0] + red[1] + red[2] + red[3];
}

// ---------------- transpose + bf16 split (weights) ----------------
__global__ __launch_bounds__(256) void transpose_split(const float* __restrict__ in,
                                                       unsigned short* __restrict__ oh,
                                                       unsigned short* __restrict__ ol,
                                                       int K, int N, int ldk, int ko)
{
  __shared__ float tile[32][33];
  const int n0 = blockIdx.x * 32, k0 = blockIdx.y * 32;
  const int tx = threadIdx.x & 31, ty = threadIdx.x >> 5;
#pragma unroll
  for (int i = 0; i < 32; i += 8)
    tile[ty + i][tx] = in[(size_t)(k0 + ty + i) * N + n0 + tx];
  __syncthreads();
#pragma unroll
  for (int i = 0; i < 32; i += 8) {
    const float v = tile[tx][ty + i];
    const unsigned short h = bf_hi(v);
    const size_t o = (size_t)(n0 + ty + i) * ldk + ko + k0 + tx;
    oh[o] = h;
    ol[o] = bf_hi(v - bf_f(h));
  }
}

__global__ void concat_bias5(const float* __restrict__ b1, const float* __restrict__ qb,
                             const float* __restrict__ kb, const float* __restrict__ vb,
                             float* __restrict__ o)
{
  const int i = blockIdx.x * 256 + threadIdx.x;   // 2560
  float v;
  if (i < 512) v = b1[i];
  else if (i < 1024) v = 0.f;
  else if (i < 1536) v = qb[i - 1024];
  else if (i < 2048) v = kb[i - 1536];
  else v = vb[i - 2048];
  o[i] = v;
}

// ---------------- bf16 MFMA GEMM (128x128 tile) ----------
// P3=true : 3-product (ah*bh + ah*bl + al*bh) — fp32-grade both sides (scores).
// P3=false: 2-product (ah*bh + al*bh) — A fp32-grade, B truncated to bf16 (weights).
template <bool P3>
__global__ __launch_bounds__(256, 2) void gemm_bf3(
    const unsigned short* __restrict__ AH, const unsigned short* __restrict__ AL,
    const unsigned short* __restrict__ A2H, const unsigned short* __restrict__ A2L,
    int K1, int lda,
    const unsigned short* __restrict__ BH, const unsigned short* __restrict__ BL, int ldb,
    const float* __restrict__ bias, float scale,
    float* __restrict__ Cf, int ldc, float* __restrict__ Cf2,
    unsigned short* __restrict__ CHp, unsigned short* __restrict__ CLp, int ldcp,
    int K, int flags, long long sA, long long sB, long long sC)
{
  AH += (size_t)blockIdx.z * sA; AL += (size_t)blockIdx.z * sA;
  BH += (size_t)blockIdx.z * sB; BL += (size_t)blockIdx.z * sB;
  if (Cf) Cf += (size_t)blockIdx.z * sC;
  int bm, bn;
  if (flags & F_TRI) {
    int t = blockIdx.x, i = 0, acc = 0;
    while (acc + i + 1 <= t) { ++i; acc += i; }
    bm = i << 7; bn = (t - acc) << 7;
  } else {
    bm = blockIdx.y << 7; bn = blockIdx.x << 7;
  }
  __shared__ __align__(16) unsigned short AsH[128][40];
  __shared__ __align__(16) unsigned short AsL[128][40];
  __shared__ __align__(16) unsigned short BsH[128][40];
  __shared__ __align__(16) unsigned short BsL[P3 ? 128 : 1][40];
  const int tid = threadIdx.x;
  const int lane = tid & 63, wave = tid >> 6;
  const int wm = (wave & 1) << 6, wn = (wave >> 1) << 6;
  const int r16 = lane & 15, quad = lane >> 4;
  const int sr = tid >> 1, sc = (tid & 1) << 4;
  const f32x4 zero = {0.f, 0.f, 0.f, 0.f};
  f32x4 acc[4][4];
#pragma unroll
  for (int i = 0; i < 4; ++i)
#pragma unroll
    for (int j = 0; j < 4; ++j) acc[i][j] = zero;

  for (int k0 = 0; k0 < K; k0 += 32) {
    const int kc = k0 + sc;
    const unsigned short *pAH, *pAL;
    if (kc < K1) {
      pAH = AH + (size_t)(bm + sr) * lda + kc;
      pAL = AL + (size_t)(bm + sr) * lda + kc;
    } else {
      pAH = A2H + (size_t)(bm + sr) * lda + (kc - K1);
      pAL = A2L + (size_t)(bm + sr) * lda + (kc - K1);
    }
    const unsigned short* pBH = BH + (size_t)(bn + sr) * ldb + kc;
    *(uint4*)&AsH[sr][sc]     = *(const uint4*)pAH;
    *(uint4*)&AsH[sr][sc + 8] = *(const uint4*)(pAH + 8);
    *(uint4*)&AsL[sr][sc]     = *(const uint4*)pAL;
    *(uint4*)&AsL[sr][sc + 8] = *(const uint4*)(pAL + 8);
    *(uint4*)&BsH[sr][sc]     = *(const uint4*)pBH;
    *(uint4*)&BsH[sr][sc + 8] = *(const uint4*)(pBH + 8);
    if (P3) {
      const unsigned short* pBL = BL + (size_t)(bn + sr) * ldb + kc;
      *(uint4*)&BsL[sr][sc]     = *(const uint4*)pBL;
      *(uint4*)&BsL[sr][sc + 8] = *(const uint4*)(pBL + 8);
    }
    __syncthreads();
    short8 bh[4], bl[4];
#pragma unroll
    for (int ni = 0; ni < 4; ++ni) {
      bh[ni] = *(const short8*)&BsH[wn + ni * 16 + r16][quad * 8];
      if (P3) bl[ni] = *(const short8*)&BsL[wn + ni * 16 + r16][quad * 8];
    }
#pragma unroll
    for (int mi = 0; mi < 4; ++mi) {
      const short8 ah = *(const short8*)&AsH[wm + mi * 16 + r16][quad * 8];
      const short8 al = *(const short8*)&AsL[wm + mi * 16 + r16][quad * 8];
#pragma unroll
      for (int ni = 0; ni < 4; ++ni) {
        acc[mi][ni] = __builtin_amdgcn_mfma_f32_16x16x32_bf16(ah, bh[ni], acc[mi][ni], 0, 0, 0);
        acc[mi][ni] = __builtin_amdgcn_mfma_f32_16x16x32_bf16(al, bh[ni], acc[mi][ni], 0, 0, 0);
        if (P3)
          acc[mi][ni] = __builtin_amdgcn_mfma_f32_16x16x32_bf16(ah, bl[ni], acc[mi][ni], 0, 0, 0);
      }
    }
    __syncthreads();
  }
#pragma unroll
  for (int mi = 0; mi < 4; ++mi) {
    const int row0 = bm + wm + mi * 16 + quad * 4;
#pragma unroll
    for (int ni = 0; ni < 4; ++ni) {
      const int col = bn + wn + ni * 16 + r16;
      const float bv = bias ? bias[col] : 0.f;
#pragma unroll
      for (int rg = 0; rg < 4; ++rg) {
        const int row = row0 + rg;
        float o = acc[mi][ni][rg] * scale + bv;
        if (flags & F_SPLIT) {
          if (col < 1024) {
            float* p = Cf + (size_t)row * ldc + col;
            *p = o + *p;
          } else {
            Cf2[(size_t)row * 512 + (col - 1024)] = o;
          }
        } else {
          if (flags & F_ACC_F32) o += Cf[(size_t)row * ldc + col];
          if (flags & F_ACC_PAIR) {
            const size_t ip = (size_t)row * ldcp + col;
            o += bf_f(CHp[ip]) + bf_f(CLp[ip]);
          }
          if (flags & F_WR_F32) Cf[(size_t)row * ldc + col] = o;
          if (flags & F_WR_PAIR) {
            const size_t ip = (size_t)row * ldcp + col;
            split_store(o, &CHp[ip], &CLp[ip]);
          }
        }
      }
    }
  }
}

// ---------------- small-tile variant: 64x128, 2-product ----------
__global__ __launch_bounds__(256, 3) void gemm_bf3s(
    const unsigned short* __restrict__ AH, const unsigned short* __restrict__ AL, int lda,
    const unsigned short* __restrict__ BH, int ldb,
    const float* __restrict__ bias,
    float* __restrict__ Cf, int ldc,
    unsigned short* __restrict__ CHp, unsigned short* __restrict__ CLp, int ldcp,
    int K, int flags)
{
  const int bm = blockIdx.y << 6, bn = blockIdx.x << 7;
  __shared__ __align__(16) unsigned short AsH[64][40];
  __shared__ __align__(16) unsigned short AsL[64][40];
  __shared__ __align__(16) unsigned short BsH[128][40];
  const int tid = threadIdx.x;
  const int lane = tid & 63, wave = tid >> 6;
  const int wm = (wave & 1) << 5, wn = (wave >> 1) << 6;
  const int r16 = lane & 15, quad = lane >> 4;
  const int sar = tid >> 2, sac = (tid & 3) << 3;
  const int sbr = tid >> 1, sbc = (tid & 1) << 4;
  const f32x4 zero = {0.f, 0.f, 0.f, 0.f};
  f32x4 acc[2][4];
#pragma unroll
  for (int i = 0; i < 2; ++i)
#pragma unroll
    for (int j = 0; j < 4; ++j) acc[i][j] = zero;

  for (int k0 = 0; k0 < K; k0 += 32) {
    const unsigned short* pAH = AH + (size_t)(bm + sar) * lda + k0 + sac;
    const unsigned short* pAL = AL + (size_t)(bm + sar) * lda + k0 + sac;
    const unsigned short* pBH = BH + (size_t)(bn + sbr) * ldb + k0 + sbc;
    *(uint4*)&AsH[sar][sac] = *(const uint4*)pAH;
    *(uint4*)&AsL[sar][sac] = *(const uint4*)pAL;
    *(uint4*)&BsH[sbr][sbc]     = *(const uint4*)pBH;
    *(uint4*)&BsH[sbr][sbc + 8] = *(const uint4*)(pBH + 8);
    __syncthreads();
    short8 bh[4];
#pragma unroll
    for (int ni = 0; ni < 4; ++ni)
      bh[ni] = *(const short8*)&BsH[wn + ni * 16 + r16][quad * 8];
#pragma unroll
    for (int mi = 0; mi < 2; ++mi) {
      const short8 ah = *(const short8*)&AsH[wm + mi * 16 + r16][quad * 8];
      const short8 al = *(const short8*)&AsL[wm + mi * 16 + r16][quad * 8];
#pragma unroll
      for (int ni = 0; ni < 4; ++ni) {
        acc[mi][ni] = __builtin_amdgcn_mfma_f32_16x16x32_bf16(ah, bh[ni], acc[mi][ni], 0, 0, 0);
        acc[mi][ni] = __builtin_amdgcn_mfma_f32_16x16x32_bf16(al, bh[ni], acc[mi][ni], 0, 0, 0);
      }
    }
    __syncthreads();
  }
#pragma unroll
  for (int mi = 0; mi < 2; ++mi) {
    const int row0 = bm + wm + mi * 16 + quad * 4;
#pragma unroll
    for (int ni = 0; ni < 4; ++ni) {
      const int col = bn + wn + ni * 16 + r16;
      const float bv = bias ? bias[col] : 0.f;
#pragma unroll
      for (int rg = 0; rg < 4; ++rg) {
        const int row = row0 + rg;
        float o = acc[mi][ni][rg] + bv;
        if (flags & F_ACC_PAIR) {
          const size_t ip = (size_t)row * ldcp + col;
          o += bf_f(CHp[ip]) + bf_f(CLp[ip]);
        }
        if (flags & F_WR_F32) Cf[(size_t)row * ldc + col] = o;
        if (flags & F_WR_PAIR) {
          const size_t ip = (size_t)row * ldcp + col;
          split_store(o, &CHp[ip], &CLp[ip]);
        }
      }
    }
  }
}

// ---------------- small kernels ----------------
__global__ void zero_k(float* __restrict__ p) {
  p[(size_t)blockIdx.x * 256 + threadIdx.x] = 0.f;
}

__global__ void embed_p(const int* __restrict__ x, const float* __restrict__ emb,
                        const float* __restrict__ pos,
                        unsigned short* __restrict__ oh, unsigned short* __restrict__ ol, int t)
{
  const int i = blockIdx.x * 256 + threadIdx.x;
  const int r = i >> 9, d = i & 511;
  const int b = r >> 10, n = r & (CN - 1);
  const int tok = x[b * CT + n * CP + t];
  const float v = emb[(size_t)tok * CD + d] + pos[t * CD + d];
  split_store(v, &oh[i], &ol[i]);
}

__global__ void gru_point_p(const float* __restrict__ gi, const float* __restrict__ ghn,
                            unsigned short* __restrict__ hH, unsigned short* __restrict__ hL,
                            float* __restrict__ hs, int t)
{
  const int i = blockIdx.x * 256 + threadIdx.x;
  const int r = i >> 9, d = i & 511;
  const size_t gb = (size_t)r * (3 * CD) + d;
  const float sr_ = gi[gb], sz = gi[gb + CD], inn = gi[gb + 2 * CD];
  const float hn = ghn[i];
  const float hp = bf_f(hH[i]) + bf_f(hL[i]);
  const float rr = sigm(sr_), zz = sigm(sz);
  const float nn = tanhf(inn + rr * hn);
  const float hv = (1.f - zz) * nn + zz * hp;
  split_store(hv, &hH[i], &hL[i]);
  hs[(size_t)r * (CP * CD) + (size_t)t * CD + d] = hv;
}

__global__ __launch_bounds__(256) void ln_rows(const float* __restrict__ in, float* __restrict__ out,
                                               const float* __restrict__ g, const float* __restrict__ b)
{
  const int r = blockIdx.x, t = threadIdx.x;
  __shared__ float red[4];
  const float* ip = in + (size_t)r * CD;
  const float v0 = ip[t], v1 = ip[t + 256];
  const float mu = blk_sum(v0 + v1, red) * (1.f / CD);
  const float d0 = v0 - mu, d1 = v1 - mu;
  const float var = blk_sum(d0 * d0 + d1 * d1, red) * (1.f / CD);
  const float inv = rsqrtf(var + CEPS);
  float* op = out + (size_t)r * CD;
  op[t] = d0 * inv * g[t] + b[t];
  op[t + 256] = d1 * inv * g[t + 256] + b[t + 256];
}

__global__ void mean_pool_p(const float* __restrict__ local,
                            unsigned short* __restrict__ oh, unsigned short* __restrict__ ol)
{
  const int i = blockIdx.x * 256 + threadIdx.x;
  const int r = i >> 9, d = i & 511;
  const float* p = local + (size_t)r * (CP * CD) + d;
  split_store(0.25f * (p[0] + p[CD] + p[2 * CD] + p[3 * CD]), &oh[i], &ol[i]);
}

__global__ void msg_gelu_p(const float* __restrict__ X4,
                           unsigned short* __restrict__ oh, unsigned short* __restrict__ ol)
{
  const int i = blockIdx.x * 256 + threadIdx.x;
  const int r = i >> 9, d = i & 511;
  const int n = r & (CN - 1);
  const float pv = X4[(size_t)r * 2560 + d];
  float acc = 0.f;
#pragma unroll
  for (int w = 0; w <= 4; ++w) {
    const float xv = pv + ((n >= w) ? X4[(size_t)(r - w) * 2560 + 512 + d] : 0.f);
    acc += geluf(xv);
  }
  split_store(acc * 0.2f, &oh[i], &ol[i]);
}

__global__ void rotary2_p(const float* __restrict__ X4,
                          unsigned short* __restrict__ qh, unsigned short* __restrict__ ql,
                          unsigned short* __restrict__ kh, unsigned short* __restrict__ kl)
{
  const int i = blockIdx.x * 256 + threadIdx.x;   // ROWS*256
  const int r = i >> 8, j = i & 255;
  const int n = r & (CN - 1);
  const float fr = (float)n * expf(-9.210340371976184f * ((float)j * (1.f / 256.f)));
  float s, c;
  sincosf(fr, &s, &c);
  const float* p = X4 + (size_t)r * 2560;
  const size_t o0 = (size_t)r * CD + j, o1 = o0 + 256;
  const float q1 = p[1024 + j], q2 = p[1024 + 256 + j];
  split_store(q1 * c - q2 * s, &qh[o0], &ql[o0]);
  split_store(q2 * c + q1 * s, &qh[o1], &ql[o1]);
  const float k1 = p[1536 + j], k2 = p[1536 + 256 + j];
  split_store(k1 * c - k2 * s, &kh[o0], &kl[o0]);
  split_store(k2 * c + k1 * s, &kh[o1], &kl[o1]);
}

// ---------------- fused top-K + softmax + gather ----------------
__global__ __launch_bounds__(256) void topk_attn(const float* __restrict__ X4,
                                                 unsigned short* __restrict__ ctxH,
                                                 unsigned short* __restrict__ ctxL)
{
  const int r = blockIdx.x;
  const int b = r >> 10, n = r & (CN - 1);
  const float* row = X4 + (size_t)r * 2560;
  const int tid = threadIdx.x, lane = tid & 63, wave = tid >> 6;
  __shared__ unsigned long long cands[64];
  __shared__ float p16[CK];
  __shared__ int i16[CK];
  unsigned long long key[4];
#pragma unroll
  for (int q = 0; q < 4; ++q) {
    const int m = tid + q * 256;
    const float v = (m <= n) ? row[m] : -INFINITY;
    unsigned u = __float_as_uint(v);
    u = (u & 0x80000000u) ? ~u : (u | 0x80000000u);
    key[q] = ((unsigned long long)u << 32) | (unsigned)(CN - 1 - m);
  }
  unsigned long long mycand = 0ull;
#pragma unroll
  for (int it = 0; it < CK; ++it) {
    unsigned long long best = key[0];
#pragma unroll
    for (int q = 1; q < 4; ++q) best = best > key[q] ? best : key[q];
#pragma unroll
    for (int o = 32; o > 0; o >>= 1) {
      const unsigned long long o2 = __shfl_xor(best, o, 64);
      best = best > o2 ? best : o2;
    }
    if (lane == it) mycand = best;
#pragma unroll
    for (int q = 0; q < 4; ++q)
      if (key[q] == best) key[q] = 0ull;
  }
  if (lane < CK) cands[wave * CK + lane] = mycand;
  __syncthreads();
  if (wave == 0) {
    unsigned long long k2 = cands[lane];
    unsigned long long mine = 0ull;
#pragma unroll
    for (int it = 0; it < CK; ++it) {
      unsigned long long best = k2;
#pragma unroll
      for (int o = 32; o > 0; o >>= 1) {
        const unsigned long long o2 = __shfl_xor(best, o, 64);
        best = best > o2 ? best : o2;
      }
      if (lane == it) mine = best;
      if (k2 == best) k2 = 0ull;
    }
    unsigned u = (unsigned)(mine >> 32);
    u = (u & 0x80000000u) ? (u & 0x7FFFFFFFu) : ~u;
    const float val = __uint_as_float(u);
    const int idx = CN - 1 - (int)(mine & 0xFFFFFFFFu);
    const float mx = __shfl(val, 0, 64);
    float e = 0.f;
    if (lane < CK && val != -INFINITY) e = expf(val - mx);
    float sum = e;
#pragma unroll
    for (int o = 32; o > 0; o >>= 1) sum += __shfl_xor(sum, o, 64);
    if (lane < CK) {
      p16[lane] = e / sum;
      i16[lane] = idx;
    }
  }
  __syncthreads();
  const size_t vb = ((size_t)b << 10);
#pragma unroll
  for (int pass = 0; pass < 2; ++pass) {
    const int d = tid + pass * 256;
    float a = 0.f;
#pragma unroll
    for (int q = 0; q < CK; ++q)
      a += p16[q] * X4[(vb + i16[q]) * 2560 + 2048 + d];
    split_store(a, &ctxH[(size_t)r * CD + d], &ctxL[(size_t)r * CD + d]);
  }
}

// gru + msg-LN; optionally also ar-LN of the new h -> (aH,aL)
__global__ __launch_bounds__(256) void gru_ln_p(const float* __restrict__ gi, const float* __restrict__ ghn,
                                                unsigned short* __restrict__ hH, unsigned short* __restrict__ hL,
                                                const float* __restrict__ g, const float* __restrict__ b,
                                                unsigned short* __restrict__ aH, unsigned short* __restrict__ aL,
                                                const float* __restrict__ g2, const float* __restrict__ b2)
{
  const int r = blockIdx.x, t = threadIdx.x;
  __shared__ float red[4];
  float u[2];
#pragma unroll
  for (int q = 0; q < 2; ++q) {
    const int d = t + q * 256;
    const size_t gb = (size_t)r * (3 * CD) + d;
    const float sr_ = gi[gb], sz = gi[gb + CD], inn = gi[gb + 2 * CD];
    const float hn = ghn[(size_t)r * CD + d];
    const size_t hi = (size_t)r * CD + d;
    const float hp = bf_f(hH[hi]) + bf_f(hL[hi]);
    const float rr = sigm(sr_), zz = sigm(sz);
    const float nn = tanhf(inn + rr * hn);
    u[q] = (1.f - zz) * nn + zz * hp;
  }
  const float mu = blk_sum(u[0] + u[1], red) * (1.f / CD);
  const float d0 = u[0] - mu, d1 = u[1] - mu;
  const float var = blk_sum(d0 * d0 + d1 * d1, red) * (1.f / CD);
  const float inv = rsqrtf(var + CEPS);
  const float h0 = d0 * inv * g[t] + b[t];
  const float h1 = d1 * inv * g[t + 256] + b[t + 256];
  split_store(h0, &hH[(size_t)r * CD + t], &hL[(size_t)r * CD + t]);
  split_store(h1, &hH[(size_t)r * CD + t + 256], &hL[(size_t)r * CD + t + 256]);
  if (aH) {
    const float mu2 = blk_sum(h0 + h1, red) * (1.f / CD);
    const float e0 = h0 - mu2, e1 = h1 - mu2;
    const float var2 = blk_sum(e0 * e0 + e1 * e1, red) * (1.f / CD);
    const float inv2 = rsqrtf(var2 + CEPS);
    split_store(e0 * inv2 * g2[t] + b2[t], &aH[(size_t)r * CD + t], &aL[(size_t)r * CD + t]);
    split_store(e1 * inv2 * g2[t + 256] + b2[t + 256],
                &aH[(size_t)r * CD + t + 256], &aL[(size_t)r * CD + t + 256]);
  }
}

// ---------------- MFMA flash attention, pair I/O ----------------
constexpr int FP = 72;
__global__ __launch_bounds__(256, 2) void flash_attn_p(const unsigned short* __restrict__ qkvH,
                                                       const unsigned short* __restrict__ qkvL,
                                                       unsigned short* __restrict__ outH,
                                                       unsigned short* __restrict__ outL)
{
  __shared__ __align__(16) unsigned short Qh[64 * FP], Ql[64 * FP];
  __shared__ __align__(16) unsigned short Kh[64 * FP], Kl[64 * FP];
  __shared__ __align__(16) unsigned short Vth[64 * FP], Vtl[64 * FP];
  __shared__ __align__(16) unsigned short Pm[64 * FP];
  const int qt = blockIdx.x, head = blockIdx.y, b = blockIdx.z;
  const int tid = threadIdx.x;
  const int lane = tid & 63, wave = tid >> 6;
  const int r16 = lane & 15, quad = lane >> 4;
  const size_t base = (size_t)b * CN * (3 * CD) + head * CHD;

  {
    const int r = tid >> 2, c0 = (tid & 3) << 4;
    const unsigned short* qh = qkvH + base + (size_t)(qt * 64 + r) * (3 * CD) + c0;
    const unsigned short* ql = qkvL + base + (size_t)(qt * 64 + r) * (3 * CD) + c0;
    *(uint4*)&Qh[r * FP + c0]     = *(const uint4*)qh;
    *(uint4*)&Qh[r * FP + c0 + 8] = *(const uint4*)(qh + 8);
    *(uint4*)&Ql[r * FP + c0]     = *(const uint4*)ql;
    *(uint4*)&Ql[r * FP + c0 + 8] = *(const uint4*)(ql + 8);
  }
  float m_i[4], l_i[4];
  f32x4 O[4];
  const f32x4 zero = {0.f, 0.f, 0.f, 0.f};
#pragma unroll
  for (int r = 0; r < 4; ++r) { m_i[r] = -INFINITY; l_i[r] = 0.f; }
#pragma unroll
  for (int d = 0; d < 4; ++d) O[d] = zero;

  for (int j = 0; j <= qt; ++j) {
    __syncthreads();
    {
      const int r = tid >> 2, c0 = (tid & 3) << 4;
      const unsigned short* kh = qkvH + base + (size_t)(j * 64 + r) * (3 * CD) + CD + c0;
      const unsigned short* kl = qkvL + base + (size_t)(j * 64 + r) * (3 * CD) + CD + c0;
      *(uint4*)&Kh[r * FP + c0]     = *(const uint4*)kh;
      *(uint4*)&Kh[r * FP + c0 + 8] = *(const uint4*)(kh + 8);
      *(uint4*)&Kl[r * FP + c0]     = *(const uint4*)kl;
      *(uint4*)&Kl[r * FP + c0 + 8] = *(const uint4*)(kl + 8);
      const int rp = (tid >> 3) << 1, c0v = (tid & 7) << 3;
      const unsigned short* v0h = qkvH + base + (size_t)(j * 64 + rp) * (3 * CD) + 2 * CD + c0v;
      const unsigned short* v1h = v0h + 3 * CD;
      const unsigned short* v0l = qkvL + base + (size_t)(j * 64 + rp) * (3 * CD) + 2 * CD + c0v;
      const unsigned short* v1l = v0l + 3 * CD;
      unsigned short xh[8], yh[8], xl[8], yl[8];
      *(uint4*)xh = *(const uint4*)v0h; *(uint4*)yh = *(const uint4*)v1h;
      *(uint4*)xl = *(const uint4*)v0l; *(uint4*)yl = *(const uint4*)v1l;
#pragma unroll
      for (int c = 0; c < 8; ++c) {
        const int R = c0v + c;
        const int col = rp ^ ((R >> 3) << 3);
        *(unsigned*)&Vth[R * FP + col] = (unsigned)xh[c] | ((unsigned)yh[c] << 16);
        *(unsigned*)&Vtl[R * FP + col] = (unsigned)xl[c] | ((unsigned)yl[c] << 16);
      }
    }
    __syncthreads();
    f32x4 S[4];
#pragma unroll
    for (int nt = 0; nt < 4; ++nt) S[nt] = zero;
#pragma unroll
    for (int kh2 = 0; kh2 < 2; ++kh2) {
      const short8 qh = *(const short8*)&Qh[(wave * 16 + r16) * FP + kh2 * 32 + quad * 8];
      const short8 ql = *(const short8*)&Ql[(wave * 16 + r16) * FP + kh2 * 32 + quad * 8];
#pragma unroll
      for (int nt = 0; nt < 4; ++nt) {
        const short8 kkh = *(const short8*)&Kh[(nt * 16 + r16) * FP + kh2 * 32 + quad * 8];
        const short8 kkl = *(const short8*)&Kl[(nt * 16 + r16) * FP + kh2 * 32 + quad * 8];
        S[nt] = __builtin_amdgcn_mfma_f32_16x16x32_bf16(qh, kkh, S[nt], 0, 0, 0);
        S[nt] = __builtin_amdgcn_mfma_f32_16x16x32_bf16(qh, kkl, S[nt], 0, 0, 0);
        S[nt] = __builtin_amdgcn_mfma_f32_16x16x32_bf16(ql, kkh, S[nt], 0, 0, 0);
      }
    }
#pragma unroll
    for (int r = 0; r < 4; ++r) {
      const int qrow = wave * 16 + quad * 4 + r;
      float s[4];
#pragma unroll
      for (int nt = 0; nt < 4; ++nt) {
        s[nt] = S[nt][r] * 0.125f;
        if (j == qt && (nt * 16 + r16) > qrow) s[nt] = -1e30f;
      }
      float rm = fmaxf(fmaxf(s[0], s[1]), fmaxf(s[2], s[3]));
#pragma unroll
      for (int o = 8; o > 0; o >>= 1) rm = fmaxf(rm, __shfl_xor(rm, o, 64));
      const float newm = fmaxf(m_i[r], rm);
      float p[4], rs = 0.f;
#pragma unroll
      for (int nt = 0; nt < 4; ++nt) { p[nt] = expf(s[nt] - newm); rs += p[nt]; }
#pragma unroll
      for (int o = 8; o > 0; o >>= 1) rs += __shfl_xor(rs, o, 64);
      const float alpha = expf(m_i[r] - newm);
      l_i[r] = l_i[r] * alpha + rs;
      m_i[r] = newm;
#pragma unroll
      for (int dt = 0; dt < 4; ++dt) O[dt][r] *= alpha;
#pragma unroll
      for (int nt = 0; nt < 4; ++nt)
        Pm[qrow * FP + nt * 16 + r16] = bf_hi(p[nt]);
    }
    __syncthreads();
#pragma unroll
    for (int kh2 = 0; kh2 < 2; ++kh2) {
      const short8 pa = *(const short8*)&Pm[(wave * 16 + r16) * FP + kh2 * 32 + quad * 8];
#pragma unroll
      for (int dt = 0; dt < 4; ++dt) {
        const int R = dt * 16 + r16;
        const int col = (kh2 * 32 + quad * 8) ^ ((R >> 3) << 3);
        const short8 vh = *(const short8*)&Vth[R * FP + col];
        const short8 vl = *(const short8*)&Vtl[R * FP + col];
        O[dt] = __builtin_amdgcn_mfma_f32_16x16x32_bf16(pa, vh, O[dt], 0, 0, 0);
        O[dt] = __builtin_amdgcn_mfma_f32_16x16x32_bf16(pa, vl, O[dt], 0, 0, 0);
      }
    }
  }
#pragma unroll
  for (int r = 0; r < 4; ++r) {
    const float inv = 1.f / l_i[r];
    const size_t row = (size_t)b * CN + qt * 64 + wave * 16 + quad * 4 + r;
#pragma unroll
    for (int dt = 0; dt < 4; ++dt) {
      const size_t o = row * CD + head * CHD + dt * 16 + r16;
      split_store(O[dt][r] * inv, &outH[o], &outL[o]);
    }
  }
}

__global__ __launch_bounds__(256) void final_ln_p(const float* __restrict__ local,
                                                  const float* __restrict__ broad,
                                                  const float* __restrict__ g, const float* __restrict__ bb,
                                                  unsigned short* __restrict__ oh,
                                                  unsigned short* __restrict__ ol)
{
  const int r = blockIdx.x, t = threadIdx.x;
  __shared__ float red[4];
  const size_t lb = (size_t)r * CD;
  const size_t br = (size_t)(r >> 2) * CD;
  const float v0 = local[lb + t] + broad[br + t];
  const float v1 = local[lb + 256 + t] + broad[br + 256 + t];
  const float mu = blk_sum(v0 + v1, red) * (1.f / CD);
  const float d0 = v0 - mu, d1 = v1 - mu;
  const float var = blk_sum(d0 * d0 + d1 * d1, red) * (1.f / CD);
  const float inv = rsqrtf(var + CEPS);
  split_store(d0 * inv * g[t] + bb[t], &oh[lb + t], &ol[lb + t]);
  split_store(d1 * inv * g[t + 256] + bb[t + 256], &oh[lb + 256 + t], &ol[lb + 256 + t]);
}

// ---------------- launcher ----------------
extern "C" void kernel_launch(void* const* d_in, const int* in_sizes, int n_in,
                              void* d_out, int out_size, void* d_ws, size_t ws_size,
                              hipStream_t stream)
{
  (void)in_sizes; (void)n_in; (void)out_size; (void)ws_size;
  const int*   x         = (const int*)d_in[0];
  const float* emb       = (const float*)d_in[1];
  const float* pos_emb   = (const float*)d_in[2];
  const float* gru_w_ih  = (const float*)d_in[3];
  const float* gru_w_hh  = (const float*)d_in[4];
  const float* gru_b_ih  = (const float*)d_in[5];
  const float* gru_b_hh  = (const float*)d_in[6];
  const float* patch_g   = (const float*)d_in[7];
  const float* patch_b   = (const float*)d_in[8];
  const float* summ_w    = (const float*)d_in[9];
  const float* summ_b    = (const float*)d_in[10];
  const float* msg_w1    = (const float*)d_in[11];
  const float* msg_b1    = (const float*)d_in[12];
  const float* msg_w2    = (const float*)d_in[13];
  const float* msg_b2    = (const float*)d_in[14];
  const float* msg_ln_g  = (const float*)d_in[15];
  const float* msg_ln_b  = (const float*)d_in[16];
  const float* q_w       = (const float*)d_in[17];
  const float* q_b       = (const float*)d_in[18];
  const float* k_w       = (const float*)d_in[19];
  const float* k_b       = (const float*)d_in[20];
  const float* v_w       = (const float*)d_in[21];
  const float* v_b       = (const float*)d_in[22];
  const float* o_w       = (const float*)d_in[23];
  const float* o_b       = (const float*)d_in[24];
  const float* gc_w_ih   = (const float*)d_in[25];
  const float* gc_w_hh   = (const float*)d_in[26];
  const float* gc_b_ih   = (const float*)d_in[27];
  const float* gc_b_hh   = (const float*)d_in[28];
  const float* ar_ln_g   = (const float*)d_in[29];
  const float* ar_ln_b   = (const float*)d_in[30];
  const float* ar_qkv_w  = (const float*)d_in[31];
  const float* ar_qkv_b  = (const float*)d_in[32];
  const float* ar_out_w  = (const float*)d_in[33];
  const float* ar_out_b  = (const float*)d_in[34];
  const float* broad_w   = (const float*)d_in[35];
  const float* broad_b   = (const float*)d_in[36];
  const float* ln_g      = (const float*)d_in[37];
  const float* ln_b      = (const float*)d_in[38];
  const float* head_w    = (const float*)d_in[39];
  float* out = (float*)d_out;

  float* ws = (float*)d_ws;
  float* WL    = ws + OFF_LOCAL;
  float* X4    = ws + OFF_X4;
  float* GI    = X4;
  float* GHN   = X4 + (size_t)ROWS * 1536;
  float* WBR   = ws + OFF_MS;
  float* Wbias5 = ws + OFF_BIAS;
  unsigned short* WTh = (unsigned short*)(ws + OFF_WT);
  unsigned short* WTl = WTh + TOT_W;
  unsigned short* WhH = (unsigned short*)(ws + OFF_HP);
  unsigned short* WhL = WhH + PN;
  unsigned short* MsH = (unsigned short*)(ws + OFF_MS);
  unsigned short* MsL = MsH + PN;
  unsigned short* pAH = (unsigned short*)(ws + OFF_A);
  unsigned short* pAL = pAH + PN;
  unsigned short* pBH = (unsigned short*)(ws + OFF_B);
  unsigned short* pBL = pBH + PN;
  unsigned short* QkH = (unsigned short*)X4;
  unsigned short* QkL = QkH + (size_t)ROWS * 1536;
  unsigned short* FnH = (unsigned short*)X4;
  unsigned short* FnL = FnH + (size_t)TROWS * CD;

  const int EW = ROWS * CD / 256;
  const float inv_sqrt_d = 0.04419417382415922f;

  auto TR = [&](const float* in, size_t off, int K, int N, int ldk, int ko) {
    transpose_split<<<dim3(N / 32, K / 32), 256, 0, stream>>>(in, WTh + off, WTl + off, K, N, ldk, ko);
  };
  TR(gru_w_ih, T_GRU_IH, 512, 1536, 512, 0);
  TR(gru_w_hh, T_GRU_HH, 512, 1536, 512, 0);
  TR(summ_w,   T_SUMM,   512, 512,  512, 0);
  TR(msg_w1,                      T_FUSE,           512, 512, 512, 0);
  TR(msg_w1 + (size_t)512 * 512,  T_FUSE + 262144,  512, 512, 512, 0);
  TR(q_w,                         T_FUSE + 524288,  512, 512, 512, 0);
  TR(k_w,                         T_FUSE + 786432,  512, 512, 512, 0);
  TR(v_w,                         T_FUSE + 1048576, 512, 512, 512, 0);
  TR(msg_w2,   T_MSG2,   512, 512,  512, 0);
  TR(o_w, T_OW, 512, 512, 512, 0);
  TR(gc_w_ih,                       T_GCAB, 512, 1536, 1024, 0);
  TR(gc_w_ih + (size_t)512 * 1536,  T_GCAB, 512, 1536, 1024, 512);
  TR(gc_w_hh,  T_GC_HH,  512, 1536, 512, 0);
  TR(ar_qkv_w, T_AR_QKV, 512, 1536, 512, 0);
  TR(ar_out_w, T_AR_OUT, 512, 512,  512, 0);
  TR(broad_w,  T_BROAD,  512, 512,  512, 0);
  TR(head_w,   T_HEAD,   512, 256,  512, 0);
  concat_bias5<<<10, 256, 0, stream>>>(msg_b1, q_b, k_b, v_b, Wbias5);

  // big weight GEMM (2-product)
  auto G3 = [&](const unsigned short* AH_, const unsigned short* AL_, int lda_,
                size_t toff, int ldb_, const float* bias_, float* Cf_, int ldc_, float* Cf2_,
                unsigned short* CHp_, unsigned short* CLp_, int ldcp_,
                int K_, int flags_, int gx, int gy) {
    gemm_bf3<false><<<dim3(gx, gy), 256, 0, stream>>>(
        AH_, AL_, AH_, AL_, K_, lda_, WTh + toff, WTl + toff, ldb_, bias_, 1.f,
        Cf_, ldc_, Cf2_, CHp_, CLp_, ldcp_, K_, flags_, 0, 0, 0);
  };
  // small weight GEMM (64x128, 2-product)
  auto G3S = [&](const unsigned short* AH_, const unsigned short* AL_, int lda_,
                 size_t toff, const float* bias_, float* Cf_, int ldc_,
                 unsigned short* CHp_, unsigned short* CLp_, int ldcp_,
                 int flags_, int gx, int gy) {
    gemm_bf3s<<<dim3(gx, gy), 256, 0, stream>>>(
        AH_, AL_, lda_, WTh + toff, 512, bias_,
        Cf_, ldc_, CHp_, CLp_, ldcp_, 512, flags_);
  };

  // ---- patch GRU over P=4 steps ----
  zero_k<<<EW, 256, 0, stream>>>(ws + OFF_HP);
  for (int t = 0; t < CP; ++t) {
    embed_p<<<EW, 256, 0, stream>>>(x, emb, pos_emb, pAH, pAL, t);
    G3(pAH, pAL, 512, T_GRU_IH, 512, gru_b_ih, GI, 1536, nullptr,
       nullptr, nullptr, 0, 512, F_WR_F32, 12, 64);
    G3(WhH, WhL, 512, T_GRU_HH, 512, gru_b_hh, GI, 1536, GHN,
       nullptr, nullptr, 0, 512, F_SPLIT, 12, 64);
    gru_point_p<<<EW, 256, 0, stream>>>(GI, GHN, WhH, WhL, WL, t);
  }
  ln_rows<<<TROWS, 256, 0, stream>>>(WL, WL, patch_g, patch_b);
  mean_pool_p<<<EW, 256, 0, stream>>>(WL, pAH, pAL);
  G3S(pAH, pAL, 512, T_SUMM, summ_b, nullptr, 0, WhH, WhL, 512, F_WR_PAIR, 4, 128);

  // ---- rounds ----
  for (int rnd = 0; rnd < 6; ++rnd) {
    G3(WhH, WhL, 512, T_FUSE, 512, Wbias5, X4, 2560, nullptr,
       nullptr, nullptr, 0, 512, F_WR_F32, 20, 64);
    msg_gelu_p<<<EW, 256, 0, stream>>>(X4, pBH, pBL);
    G3S(pBH, pBL, 512, T_MSG2, msg_b2, nullptr, 0, MsH, MsL, 512, F_WR_PAIR, 4, 128);
    rotary2_p<<<ROWS, 256, 0, stream>>>(X4, pAH, pAL, pBH, pBL);
    // scores (3-product, lower-triangular 128-tiles) -> X4 cols 0..1023
    gemm_bf3<true><<<dim3(36, 1, CB), 256, 0, stream>>>(
        pAH, pAL, pAH, pAL, 512, 512, pBH, pBL, 512, nullptr, inv_sqrt_d,
        X4, 2560, nullptr, nullptr, nullptr, 0, 512, F_WR_F32 | F_TRI,
        (long long)CN * CD, (long long)CN * CD, (long long)CN * 2560);
    topk_attn<<<ROWS, 256, 0, stream>>>(X4, pAH, pAL);
    G3S(pAH, pAL, 512, T_OW, o_b, nullptr, 0, pBH, pBL, 512, F_WR_PAIR, 4, 128);
    gemm_bf3<false><<<dim3(12, 64), 256, 0, stream>>>(
        MsH, MsL, pBH, pBL, 512, 512, WTh + T_GCAB, WTl + T_GCAB, 1024, gc_b_ih, 1.f,
        GI, 1536, nullptr, nullptr, nullptr, 0, 1024, F_WR_F32, 0, 0, 0);
    G3(WhH, WhL, 512, T_GC_HH, 512, gc_b_hh, GI, 1536, GHN,
       nullptr, nullptr, 0, 512, F_SPLIT, 12, 64);
    if ((rnd & 1) == 1) {
      gru_ln_p<<<ROWS, 256, 0, stream>>>(GI, GHN, WhH, WhL, msg_ln_g, msg_ln_b,
                                         pAH, pAL, ar_ln_g, ar_ln_b);
      G3(pAH, pAL, 512, T_AR_QKV, 512, ar_qkv_b, nullptr, 0, nullptr,
         QkH, QkL, 1536, 512, F_WR_PAIR, 12, 64);
      flash_attn_p<<<dim3(16, CH, CB), 256, 0, stream>>>(QkH, QkL, pBH, pBL);
      G3S(pBH, pBL, 512, T_AR_OUT, ar_out_b, nullptr, 0, WhH, WhL, 512,
          F_ACC_PAIR | F_WR_PAIR, 4, 128);
    } else {
      gru_ln_p<<<ROWS, 256, 0, stream>>>(GI, GHN, WhH, WhL, msg_ln_g, msg_ln_b,
                                         nullptr, nullptr, nullptr, nullptr);
    }
  }

  // ---- head ----
  G3S(WhH, WhL, 512, T_BROAD, broad_b, WBR, 512, nullptr, nullptr, 0, F_WR_F32, 4, 128);
  final_ln_p<<<TROWS, 256, 0, stream>>>(WL, WBR, ln_g, ln_b, FnH, FnL);
  G3S(FnH, FnL, 512, T_HEAD, nullptr, out, CV, nullptr, nullptr, 0, F_WR_F32, 2, 512);
}